// Round 6
// baseline (2135.063 us; speedup 1.0000x reference)
//
#include <hip/hip_runtime.h>

// ---------------- constants ----------------
#define NE 60000
#define NA 30000
#define E_EE 150000
#define E_EA 75000
#define E_AE 75000
#define SCALE 0.17677669529663689f   // 1/sqrt(32)

__device__ __forceinline__ float bf2f(unsigned short u) {
  return __uint_as_float(((unsigned)u) << 16);
}
__device__ __forceinline__ unsigned short f2bf(float f) {
  unsigned u = __float_as_uint(f);
  u = u + 0x7FFFu + ((u >> 16) & 1u);   // RNE
  return (unsigned short)(u >> 16);
}
__device__ __forceinline__ float ldc(const float* p) { return *p; }
__device__ __forceinline__ float ldc(const unsigned short* p) { return bf2f(*p); }
__device__ __forceinline__ float gelu_f(float x) {
  return 0.5f * x * (1.0f + erff(x * 0.7071067811865476f));
}

// ---------------- fused relation weights (all f32) ----------------
__global__ __launch_bounds__(256) void wrel_k(
    const float* __restrict__ Wk_e, const float* __restrict__ Wk_a,
    const float* __restrict__ bk_e, const float* __restrict__ bk_a,
    const float* __restrict__ a_rel, const float* __restrict__ m_rel,
    float* __restrict__ Wkt, float* __restrict__ Wvt,
    float* __restrict__ bkt, float* __restrict__ bvt) {
  int t = blockIdx.x;        // relation 0..2
  int part = blockIdx.y;     // 0: key (a_rel, cols 0..127), 1: value (m_rel, cols 256..)
  const float* W = (t < 2) ? Wk_e : Wk_a;
  const float* bb = (t < 2) ? bk_e : bk_a;
  const float* A = (part ? m_rel : a_rel) + t * 4096;
  int coff = part ? 256 : 0;
  float* Wo = (part ? Wvt : Wkt) + t * 16384;
  float* bo = (part ? bvt : bkt) + t * 128;
  __shared__ float As[4096];
  for (int u = threadIdx.x; u < 4096; u += 256) As[u] = A[u];
  __syncthreads();
  for (int u = threadIdx.x; u < 16384; u += 256) {
    int i = u >> 7, c = u & 127;
    int hh = c >> 5, e = c & 31;
    const float* wr = W + i * 384 + coff + hh * 32;
    const float* ar = As + hh * 1024 + e;
    float acc = 0.f;
#pragma unroll
    for (int d = 0; d < 32; ++d) acc = fmaf(wr[d], ar[d * 32], acc);
    Wo[u] = acc;
  }
  if (threadIdx.x < 128) {
    int c = threadIdx.x, hh = c >> 5, e = c & 31;
    const float* br = bb + coff + hh * 32;
    const float* ar = As + hh * 1024 + e;
    float acc = 0.f;
#pragma unroll
    for (int d = 0; d < 32; ++d) acc = fmaf(br[d], ar[d * 32], acc);
    bo[c] = acc;
  }
}

// ---------------- tiled GEMM v5: 128 rows x 128 cols per block, 256 threads ---------
// 8x8 per-thread tile -> 2 FLOP/LDS-byte. K staged in 4 steps of 32. LDS 32KB.
// ACT: 0 none, 1 gelu(X).
// EPI: 0 f32 store; 1 relu f32; 2 bf16 store (+ atomic ssq if ssq!=null);
//      3 blend: fout = gelu(g*acc + (1-g)*fout), g = sigmoid(*skipp)
template <int ACT, int EPI>
__global__ __launch_bounds__(256) void gemm128_k(
    const float* __restrict__ X, int ldx,
    const float* __restrict__ W, int ldw,
    const float* __restrict__ bias, int N,
    float* __restrict__ fout, unsigned short* __restrict__ bout, int ldo,
    const float* __restrict__ skipp, float* __restrict__ ssq) {
  __shared__ float Xs[128 * 32];
  __shared__ float Ws[32 * 128];
  const int tid = threadIdx.x;
  const int ti = tid >> 4;             // 0..15 -> rows ti*8..+7
  const int tj = tid & 15;             // cols {tj*4..+3} and {64+tj*4..+3}
  const int row0 = blockIdx.x * 128;
  const int cb = blockIdx.y * 128;
  const int c0 = cb + tj * 4;
  const int c1 = cb + 64 + tj * 4;

  float acc[8][8];
  {
    float bc[8] = {0.f, 0.f, 0.f, 0.f, 0.f, 0.f, 0.f, 0.f};
    if (bias) {
#pragma unroll
      for (int j = 0; j < 4; ++j) { bc[j] = bias[c0 + j]; bc[4 + j] = bias[c1 + j]; }
    }
#pragma unroll
    for (int i = 0; i < 8; ++i)
#pragma unroll
      for (int j = 0; j < 8; ++j) acc[i][j] = bc[j];
  }

  for (int ks = 0; ks < 128; ks += 32) {
    __syncthreads();   // previous step's compute done before overwriting LDS
    for (int v = tid; v < 1024; v += 256) {
      int kq = v & 7, r = v >> 3;
      int rg = row0 + r; if (rg >= N) rg = N - 1;
      float4 x4 = *reinterpret_cast<const float4*>(X + (size_t)rg * ldx + ks + kq * 4);
      if (ACT == 1) {
        x4.x = gelu_f(x4.x); x4.y = gelu_f(x4.y);
        x4.z = gelu_f(x4.z); x4.w = gelu_f(x4.w);
      }
      *reinterpret_cast<float4*>(&Xs[r * 32 + ((kq ^ ((r >> 3) & 7)) << 2)]) = x4;
    }
    for (int v = tid; v < 1024; v += 256) {
      int cq = v & 31, k = v >> 5;
      *reinterpret_cast<float4*>(&Ws[k * 128 + cq * 4]) =
          *reinterpret_cast<const float4*>(W + (size_t)(ks + k) * ldw + cb + cq * 4);
    }
    __syncthreads();
#pragma unroll
    for (int k = 0; k < 32; k += 4) {
      float xr[8][4];
#pragma unroll
      for (int i = 0; i < 8; ++i)
        *reinterpret_cast<float4*>(xr[i]) = *reinterpret_cast<const float4*>(
            &Xs[(ti * 8 + i) * 32 + ((((k >> 2)) ^ (ti & 7)) << 2)]);
      float wr[4][8];
#pragma unroll
      for (int dk = 0; dk < 4; ++dk) {
        *reinterpret_cast<float4*>(&wr[dk][0]) =
            *reinterpret_cast<const float4*>(&Ws[(k + dk) * 128 + tj * 4]);
        *reinterpret_cast<float4*>(&wr[dk][4]) =
            *reinterpret_cast<const float4*>(&Ws[(k + dk) * 128 + 64 + tj * 4]);
      }
#pragma unroll
      for (int i = 0; i < 8; ++i)
#pragma unroll
        for (int dk = 0; dk < 4; ++dk)
#pragma unroll
          for (int j = 0; j < 8; ++j)
            acc[i][j] = fmaf(xr[i][dk], wr[dk][j], acc[i][j]);
    }
  }

  if (EPI == 0 || EPI == 1) {
#pragma unroll
    for (int i = 0; i < 8; ++i) {
      int rg = row0 + ti * 8 + i;
      if (rg < N) {
        float4 a = make_float4(acc[i][0], acc[i][1], acc[i][2], acc[i][3]);
        float4 b = make_float4(acc[i][4], acc[i][5], acc[i][6], acc[i][7]);
        if (EPI == 1) {
          a.x = fmaxf(a.x, 0.f); a.y = fmaxf(a.y, 0.f);
          a.z = fmaxf(a.z, 0.f); a.w = fmaxf(a.w, 0.f);
          b.x = fmaxf(b.x, 0.f); b.y = fmaxf(b.y, 0.f);
          b.z = fmaxf(b.z, 0.f); b.w = fmaxf(b.w, 0.f);
        }
        *reinterpret_cast<float4*>(fout + (size_t)rg * ldo + c0) = a;
        *reinterpret_cast<float4*>(fout + (size_t)rg * ldo + c1) = b;
      }
    }
  } else if (EPI == 2) {
    float loc = 0.f;
#pragma unroll
    for (int i = 0; i < 8; ++i) {
      int rg = row0 + ti * 8 + i;
      if (rg < N) {
        ushort4 s0, s1;
        s0.x = f2bf(acc[i][0]); s0.y = f2bf(acc[i][1]);
        s0.z = f2bf(acc[i][2]); s0.w = f2bf(acc[i][3]);
        s1.x = f2bf(acc[i][4]); s1.y = f2bf(acc[i][5]);
        s1.z = f2bf(acc[i][6]); s1.w = f2bf(acc[i][7]);
        *reinterpret_cast<ushort4*>(bout + (size_t)rg * ldo + c0) = s0;
        *reinterpret_cast<ushort4*>(bout + (size_t)rg * ldo + c1) = s1;
#pragma unroll
        for (int j = 0; j < 8; ++j) loc += acc[i][j] * acc[i][j];
      }
    }
    if (ssq) {
      __syncthreads();
      Xs[tid] = loc;
      __syncthreads();
      if (tid < 128) Xs[tid] += Xs[tid + 128];
      __syncthreads();
      if (tid < 64) {
        float v = Xs[tid] + Xs[tid + 64];
#pragma unroll
        for (int m = 32; m > 0; m >>= 1) v += __shfl_down(v, m, 64);
        if (tid == 0) atomicAdd(ssq, v);
      }
    }
  } else {  // EPI == 3
    float g = 1.f / (1.f + expf(-*skipp));
    float g1 = 1.f - g;
#pragma unroll
    for (int i = 0; i < 8; ++i) {
      int rg = row0 + ti * 8 + i;
      if (rg < N) {
        float4 o0 = *reinterpret_cast<const float4*>(fout + (size_t)rg * ldo + c0);
        float4 o1 = *reinterpret_cast<const float4*>(fout + (size_t)rg * ldo + c1);
        float4 a, b;
        a.x = gelu_f(g * acc[i][0] + g1 * o0.x);
        a.y = gelu_f(g * acc[i][1] + g1 * o0.y);
        a.z = gelu_f(g * acc[i][2] + g1 * o0.z);
        a.w = gelu_f(g * acc[i][3] + g1 * o0.w);
        b.x = gelu_f(g * acc[i][4] + g1 * o1.x);
        b.y = gelu_f(g * acc[i][5] + g1 * o1.y);
        b.z = gelu_f(g * acc[i][6] + g1 * o1.z);
        b.w = gelu_f(g * acc[i][7] + g1 * o1.w);
        *reinterpret_cast<float4*>(fout + (size_t)rg * ldo + c0) = a;
        *reinterpret_cast<float4*>(fout + (size_t)rg * ldo + c1) = b;
      }
    }
  }
}

// ---------------- CSR build ----------------
__global__ __launch_bounds__(256) void deg_k(const int* __restrict__ ei, int E,
                                             int* __restrict__ deg) {
  int i = blockIdx.x * 256 + threadIdx.x;
  if (i < E) atomicAdd(&deg[ei[E + i]], 1);
}

// exclusive scan over deg_cursor[0..n), writing rowptr[0..n] and exclusive back
// into deg_cursor (becomes the fill cursor). Single block, 1024 threads.
__global__ __launch_bounds__(1024) void scan_k(int* __restrict__ deg_cursor,
                                               int* __restrict__ rowptr, int n) {
  __shared__ int sd[1024];
  __shared__ int carry;
  int tid = threadIdx.x;
  if (tid == 0) carry = 0;
  __syncthreads();
  for (int base = 0; base < n; base += 1024) {
    int v = (base + tid < n) ? deg_cursor[base + tid] : 0;
    sd[tid] = v;
    __syncthreads();
    for (int off = 1; off < 1024; off <<= 1) {
      int t = (tid >= off) ? sd[tid - off] : 0;
      __syncthreads();
      sd[tid] += t;
      __syncthreads();
    }
    int c0 = carry;
    if (base + tid < n) {
      int excl = c0 + sd[tid] - v;
      rowptr[base + tid] = excl;
      deg_cursor[base + tid] = excl;
    }
    __syncthreads();
    if (tid == 0) carry = c0 + sd[1023];
    __syncthreads();
  }
  if (tid == 0) rowptr[n] = carry;
}

__global__ __launch_bounds__(256) void fill_k(const int* __restrict__ ei, int E,
                                              int* __restrict__ cursor,
                                              int* __restrict__ entries,
                                              int srcoff, int tag) {
  int i = blockIdx.x * 256 + threadIdx.x;
  if (i < E) {
    int pos = atomicAdd(&cursor[ei[E + i]], 1);
    entries[pos] = (ei[i] + srcoff) | (tag << 30);
  }
}

// ---------------- HGT gather: one 32-lane group per (dst, head), no atomics --------
__global__ __launch_bounds__(256) void hgt_gather_k(
    const float* __restrict__ q, const unsigned short* __restrict__ ktbl,
    const unsigned short* __restrict__ vtbl, const int* __restrict__ rowptr,
    const int* __restrict__ entries, const float* __restrict__ pbase, int nd,
    float* __restrict__ out) {
  int g = blockIdx.x * 8 + (threadIdx.x >> 5);
  int dst = g >> 2, h = g & 3, c = threadIdx.x & 31;
  if (dst >= nd) return;
  int col = h * 32 + c;
  float qv = q[(size_t)dst * 128 + col];
  int i0 = rowptr[dst], i1 = rowptr[dst + 1];
  float sum = 0.f, acc = 0.f;
  for (int i = i0; i < i1; ++i) {
    int e = entries[i];
    int lin = e & 0x3FFFFFFF;
    int tag = (unsigned)e >> 30;
    float part = qv * bf2f(ktbl[(size_t)lin * 128 + col]);
#pragma unroll
    for (int m = 16; m > 0; m >>= 1) part += __shfl_xor(part, m);
    float w = expf(part * SCALE * pbase[tag * 8 + h]);
    sum += w;
    acc = fmaf(w, bf2f(vtbl[(size_t)lin * 128 + col]), acc);
  }
  out[(size_t)dst * 128 + col] = acc / (sum + 1e-16f);
}

// ---------------- LayerNorm (row=128): out = LN(alpha*A + beta*B)*g + b -------------
template <typename AT, typename BT>
__global__ __launch_bounds__(128) void ln_k(const AT* __restrict__ A,
                                            const BT* __restrict__ B, float alpha,
                                            float beta, const float* __restrict__ g,
                                            const float* __restrict__ b,
                                            float* __restrict__ out, int relu) {
  int row = blockIdx.x;
  int t = threadIdx.x;
  float v = alpha * ldc(A + (size_t)row * 128 + t);
  if (B) v += beta * ldc(B + (size_t)row * 128 + t);
  float s1 = v, s2 = v * v;
#pragma unroll
  for (int m = 32; m > 0; m >>= 1) {
    s1 += __shfl_xor(s1, m, 64);
    s2 += __shfl_xor(s2, m, 64);
  }
  __shared__ float r1[2], r2[2];
  int w = t >> 6;
  if ((t & 63) == 0) { r1[w] = s1; r2[w] = s2; }
  __syncthreads();
  float S1 = r1[0] + r1[1], S2 = r2[0] + r2[1];
  float mu = S1 * (1.f / 128.f);
  float var = S2 * (1.f / 128.f) - mu * mu;
  float rr = rsqrtf(fmaxf(var, 0.f) + 1e-5f);
  float o = (v - mu) * rr * g[t] + b[t];
  if (relu) o = fmaxf(o, 0.f);
  out[(size_t)row * 128 + t] = o;
}

// ---------------- kvs partial: part[g][h][128][128] = sum_{n in chunk g} K V^T ------
__global__ __launch_bounds__(256) void kvsred_k(const unsigned short* __restrict__ Kb,
                                                const unsigned short* __restrict__ Vb,
                                                float* __restrict__ part,
                                                float* __restrict__ ksum, int chunk) {
  const int h = blockIdx.y;
  const int n0 = blockIdx.x * chunk;
  const int iters = chunk >> 3;          // 75
  __shared__ float ks[8][132];
  __shared__ float vs[8][132];
  const int tid = threadIdx.x;
  const int ti = tid >> 4, tj = tid & 15;

  const int sw = tid >> 7;               // 0 = K, 1 = V
  const int sni = (tid >> 4) & 7;        // row within 8-row tile
  const int sc = (tid & 15) << 3;        // col base (8 bf16 per thread)
  const unsigned short* src =
      (sw ? Vb : Kb) + (size_t)(n0 + sni) * 512 + h * 128 + sc;
  float* dstrow = (sw ? &vs[0][0] : &ks[0][0]) + sni * 132 + sc;

  float acc[8][8];
#pragma unroll
  for (int i = 0; i < 8; ++i)
#pragma unroll
    for (int j = 0; j < 8; ++j) acc[i][j] = 0.f;
  float ksloc = 0.f;

  uint4 r = *reinterpret_cast<const uint4*>(src);
  for (int it = 0; it < iters; ++it) {
    __syncthreads();
    float4 lo, hi;
    lo.x = bf2f((unsigned short)(r.x & 0xffffu)); lo.y = bf2f((unsigned short)(r.x >> 16));
    lo.z = bf2f((unsigned short)(r.y & 0xffffu)); lo.w = bf2f((unsigned short)(r.y >> 16));
    hi.x = bf2f((unsigned short)(r.z & 0xffffu)); hi.y = bf2f((unsigned short)(r.z >> 16));
    hi.z = bf2f((unsigned short)(r.w & 0xffffu)); hi.w = bf2f((unsigned short)(r.w >> 16));
    *reinterpret_cast<float4*>(dstrow) = lo;
    *reinterpret_cast<float4*>(dstrow + 4) = hi;
    if (it + 1 < iters)
      r = *reinterpret_cast<const uint4*>(src + (size_t)(it + 1) * 8 * 512);
    __syncthreads();
#pragma unroll
    for (int ni = 0; ni < 8; ++ni) {
      float kk[8], vv[8];
      *reinterpret_cast<float4*>(kk) =
          *reinterpret_cast<const float4*>(&ks[ni][ti * 4]);
      *reinterpret_cast<float4*>(kk + 4) =
          *reinterpret_cast<const float4*>(&ks[ni][64 + ti * 4]);
      *reinterpret_cast<float4*>(vv) =
          *reinterpret_cast<const float4*>(&vs[ni][tj * 4]);
      *reinterpret_cast<float4*>(vv + 4) =
          *reinterpret_cast<const float4*>(&vs[ni][64 + tj * 4]);
#pragma unroll
      for (int i = 0; i < 8; ++i)
#pragma unroll
        for (int j = 0; j < 8; ++j) acc[i][j] = fmaf(kk[i], vv[j], acc[i][j]);
      if (tid < 128) ksloc += ks[ni][tid];
    }
  }
  float* pb = part + (size_t)(blockIdx.x * 4 + h) * 16384;
#pragma unroll
  for (int i = 0; i < 8; ++i) {
    int m = ti * 4 + (i & 3) + ((i >> 2) << 6);
    *reinterpret_cast<float4*>(pb + m * 128 + tj * 4) =
        make_float4(acc[i][0], acc[i][1], acc[i][2], acc[i][3]);
    *reinterpret_cast<float4*>(pb + m * 128 + 64 + tj * 4) =
        make_float4(acc[i][4], acc[i][5], acc[i][6], acc[i][7]);
  }
  if (tid < 128) atomicAdd(&ksum[h * 128 + tid], ksloc);
}

// ---------------- kvs final reduce: kvs[c] = sum_g part[g][c] ----------------------
__global__ __launch_bounds__(256) void kvsfin_k(const float* __restrict__ part,
                                                float* __restrict__ kvs, int G) {
  int c = blockIdx.x * 256 + threadIdx.x;   // c = h*16384 + m*128 + d, 65536 total
  int hh = c >> 14, md = c & 16383;
  const float* p = part + (size_t)hh * 16384 + md;
  float s = 0.f;
#pragma unroll 4
  for (int g = 0; g < G; ++g) s += p[(size_t)g * 65536];
  kvs[c] = s;
}

// ---------------- SG attention apply v2: gemm128 structure, 128-row blocks ----------
// Per head h: acc[8][8] = Q_h[128rows x 128k] * kvs[h][128k x 128d], den fused in
// k-loop (den[i] += Q*ksum, redundant across tj), folded per head into out[8][8]:
// out += (acc*f + 60000*V_h)/den. K staged in 4x32 chunks, same XOR swizzle as
// gemm128 (conflict-free). LDS 33KB (was 51KB).
__global__ __launch_bounds__(256) void sgapply_k(const unsigned short* __restrict__ Qb,
                                                 const unsigned short* __restrict__ Vb,
                                                 const float* __restrict__ kvs,
                                                 const float* __restrict__ ksum,
                                                 const float* __restrict__ ssqq,
                                                 const float* __restrict__ ssqk,
                                                 unsigned short* __restrict__ attnb,
                                                 int N) {
  __shared__ float Xs[128 * 32];
  __shared__ float Ws[32 * 128];
  __shared__ float kss[32];
  __shared__ float fsh_s;
  const int tid = threadIdx.x;
  const int ti = tid >> 4;
  const int tj = tid & 15;
  const int row0 = blockIdx.x * 128;
  if (tid == 0) fsh_s = 1.0f / (sqrtf(*ssqq) * sqrtf(*ssqk));

  float out[8][8];
#pragma unroll
  for (int i = 0; i < 8; ++i)
#pragma unroll
    for (int j = 0; j < 8; ++j) out[i][j] = 0.f;

  for (int h = 0; h < 4; ++h) {
    float acc[8][8];
    float den[8];
#pragma unroll
    for (int i = 0; i < 8; ++i) {
      den[i] = 0.f;
#pragma unroll
      for (int j = 0; j < 8; ++j) acc[i][j] = 0.f;
    }
    for (int ks = 0; ks < 128; ks += 32) {
      __syncthreads();   // previous chunk/head compute done before overwrite
      // stage Q chunk: 128 rows x 32 k (bf16 -> f32, swizzled as gemm128)
      for (int v = tid; v < 1024; v += 256) {
        int kq = v & 7, r = v >> 3;
        int rg = row0 + r; if (rg >= N) rg = N - 1;
        ushort4 q4 = *reinterpret_cast<const ushort4*>(
            Qb + (size_t)rg * 512 + h * 128 + ks + kq * 4);
        float4 x4 = make_float4(bf2f(q4.x), bf2f(q4.y), bf2f(q4.z), bf2f(q4.w));
        *reinterpret_cast<float4*>(&Xs[r * 32 + ((kq ^ ((r >> 3) & 7)) << 2)]) = x4;
      }
      // stage kvs chunk: 32 k-rows x 128 d
      for (int v = tid; v < 1024; v += 256) {
        int cq = v & 31, k = v >> 5;
        *reinterpret_cast<float4*>(&Ws[k * 128 + cq * 4]) =
            *reinterpret_cast<const float4*>(kvs + (size_t)h * 16384 +
                                             (size_t)(ks + k) * 128 + cq * 4);
      }
      if (tid < 32) kss[tid] = ksum[h * 128 + ks + tid];
      __syncthreads();
#pragma unroll
      for (int k = 0; k < 32; k += 4) {
        float xr[8][4];
#pragma unroll
        for (int i = 0; i < 8; ++i)
          *reinterpret_cast<float4*>(xr[i]) = *reinterpret_cast<const float4*>(
              &Xs[(ti * 8 + i) * 32 + ((((k >> 2)) ^ (ti & 7)) << 2)]);
        float wr[4][8];
        float kv[4];
#pragma unroll
        for (int dk = 0; dk < 4; ++dk) {
          *reinterpret_cast<float4*>(&wr[dk][0]) =
              *reinterpret_cast<const float4*>(&Ws[(k + dk) * 128 + tj * 4]);
          *reinterpret_cast<float4*>(&wr[dk][4]) =
              *reinterpret_cast<const float4*>(&Ws[(k + dk) * 128 + 64 + tj * 4]);
          kv[dk] = kss[k + dk];
        }
#pragma unroll
        for (int i = 0; i < 8; ++i)
#pragma unroll
          for (int dk = 0; dk < 4; ++dk) {
            den[i] = fmaf(xr[i][dk], kv[dk], den[i]);
#pragma unroll
            for (int j = 0; j < 8; ++j)
              acc[i][j] = fmaf(xr[i][dk], wr[dk][j], acc[i][j]);
          }
      }
    }
    // fold this head into out
    float f = fsh_s;
#pragma unroll
    for (int i = 0; i < 8; ++i) {
      int rg = row0 + ti * 8 + i; if (rg >= N) rg = N - 1;
      ushort4 v0 = *reinterpret_cast<const ushort4*>(
          Vb + (size_t)rg * 512 + h * 128 + tj * 4);
      ushort4 v1 = *reinterpret_cast<const ushort4*>(
          Vb + (size_t)rg * 512 + h * 128 + 64 + tj * 4);
      float rd = 1.0f / (den[i] * f + 60000.0f);
      out[i][0] += (acc[i][0] * f + 60000.0f * bf2f(v0.x)) * rd;
      out[i][1] += (acc[i][1] * f + 60000.0f * bf2f(v0.y)) * rd;
      out[i][2] += (acc[i][2] * f + 60000.0f * bf2f(v0.z)) * rd;
      out[i][3] += (acc[i][3] * f + 60000.0f * bf2f(v0.w)) * rd;
      out[i][4] += (acc[i][4] * f + 60000.0f * bf2f(v1.x)) * rd;
      out[i][5] += (acc[i][5] * f + 60000.0f * bf2f(v1.y)) * rd;
      out[i][6] += (acc[i][6] * f + 60000.0f * bf2f(v1.z)) * rd;
      out[i][7] += (acc[i][7] * f + 60000.0f * bf2f(v1.w)) * rd;
    }
  }
#pragma unroll
  for (int i = 0; i < 8; ++i) {
    int rg = row0 + ti * 8 + i;
    if (rg < N) {
      ushort4 s0, s1;
      s0.x = f2bf(0.25f * out[i][0]); s0.y = f2bf(0.25f * out[i][1]);
      s0.z = f2bf(0.25f * out[i][2]); s0.w = f2bf(0.25f * out[i][3]);
      s1.x = f2bf(0.25f * out[i][4]); s1.y = f2bf(0.25f * out[i][5]);
      s1.z = f2bf(0.25f * out[i][6]); s1.w = f2bf(0.25f * out[i][7]);
      *reinterpret_cast<ushort4*>(attnb + (size_t)rg * 128 + tj * 4) = s0;
      *reinterpret_cast<ushort4*>(attnb + (size_t)rg * 128 + 64 + tj * 4) = s1;
    }
  }
}

// ---------------- host ----------------
extern "C" void kernel_launch(void* const* d_in, const int* in_sizes, int n_in,
                              void* d_out, int out_size, void* d_ws, size_t ws_size,
                              hipStream_t stream) {
  const float* x_ent = (const float*)d_in[0];
  const float* x_att = (const float*)d_in[1];
  const float* Wkqv_e = (const float*)d_in[2];
  const float* bkqv_e = (const float*)d_in[3];
  const float* Wkqv_a = (const float*)d_in[4];
  const float* bkqv_a = (const float*)d_in[5];
  const float* Wout_e = (const float*)d_in[6];
  const float* bout_e = (const float*)d_in[7];
  const float* Wout_a = (const float*)d_in[8];
  const float* bout_a = (const float*)d_in[9];
  const float* skip_e = (const float*)d_in[10];
  const float* skip_a = (const float*)d_in[11];
  const float* a_rel = (const float*)d_in[12];
  const float* m_rel = (const float*)d_in[13];
  const float* p_rel = (const float*)d_in[14];
  const float* ln_ent_g = (const float*)d_in[15];
  const float* ln_ent_b = (const float*)d_in[16];
  const float* sg_fc_W = (const float*)d_in[17];
  const float* sg_fc_b = (const float*)d_in[18];
  const float* sg_ln0_g = (const float*)d_in[19];
  const float* sg_ln0_b = (const float*)d_in[20];
  const float* sg_Wq = (const float*)d_in[21];
  const float* sg_bq = (const float*)d_in[22];
  const float* sg_Wk = (const float*)d_in[23];
  const float* sg_bk = (const float*)d_in[24];
  const float* sg_Wv = (const float*)d_in[25];
  const float* sg_bv = (const float*)d_in[26];
  const float* sg_ln1_g = (const float*)d_in[27];
  const float* sg_ln1_b = (const float*)d_in[28];
  const float* proj_W1 = (const float*)d_in[29];
  const float* proj_b1 = (const float*)d_in[30];
  const float* proj_W2 = (const float*)d_in[31];
  const float* proj_b2 = (const float*)d_in[32];
  const int* ei_ee = (const int*)d_in[33];
  const int* ei_ea = (const int*)d_in[34];
  const int* ei_ae = (const int*)d_in[35];

  char* ws = (char*)d_ws;
  // ---- fixed region ----
  const size_t O_HE = 0;                         // h_e f32 (30.72M)
  const size_t O_HA = 30720000;                  // h_a f32 (15.36M) | SG: attnb bf16
  const size_t O_Z0 = 46080000;                  // z0 f32 (30.72M)
  const size_t O_WKT = 76800000;                 // 3*16384 f32
  const size_t O_WVT = 76996608;
  const size_t O_BKT = 77193216;
  const size_t O_BVT = 77194752;
  const size_t O_KVS = 77196288;                 // kvs(262144)+ksum(2048)+ssq(64)
  // ---- CSR region ----
  const size_t O_RPE = 77460544;                 // rowptr_e (60001) -> 240064
  const size_t O_RPA = O_RPE + 240064;           // rowptr_a (30001) -> 120064
  const size_t O_CUE = O_RPA + 120064;           // cursor/deg_e -> 240000
  const size_t O_CUA = O_CUE + 240000;           // cursor/deg_a -> 120000
  const size_t O_ENE = O_CUA + 120000;           // entries_e (225000) -> 900000
  const size_t O_ENA = O_ENE + 900000;           // entries_a (75000) -> 300000
  const size_t O_UN = O_ENA + 300000;            // union; 79,380,672
  // HGT view of union:
  float* q_e = (float*)(ws + O_UN);                                 // 30.72M (also out_e)
  float* q_a = (float*)(ws + O_UN + 30720000);                      // 15.36M (also out_a)
  unsigned short* ktbl = (unsigned short*)(ws + O_UN + 46080000);   // 150000x128 bf16
  unsigned short* vtbl = (unsigned short*)(ws + O_UN + 84480000);   // 150000x128 bf16
  // SG view of union:
  float* tmpf = (float*)(ws + O_UN);                                // fc out f32
  unsigned short* Vb = (unsigned short*)(ws + O_UN);                // NE*512 bf16
  unsigned short* KQb = (unsigned short*)(ws + O_UN + 61440000);    // K then Q
  unsigned short* attnb = (unsigned short*)(ws + O_HA);             // NE*128 bf16

  float* h_e = (float*)(ws + O_HE);
  float* h_a = (float*)(ws + O_HA);
  float* z0 = (float*)(ws + O_Z0);
  float* Wkt = (float*)(ws + O_WKT);
  float* Wvt = (float*)(ws + O_WVT);
  float* bkt = (float*)(ws + O_BKT);
  float* bvt = (float*)(ws + O_BVT);
  float* kvs = (float*)(ws + O_KVS);
  float* ksum = (float*)(ws + O_KVS + 262144);
  float* ssq_q = (float*)(ws + O_KVS + 262144 + 2048);
  float* ssq_k = ssq_q + 1;
  int* rowptr_e = (int*)(ws + O_RPE);
  int* rowptr_a = (int*)(ws + O_RPA);
  int* cursor_e = (int*)(ws + O_CUE);
  int* cursor_a = (int*)(ws + O_CUA);
  int* entries_e = (int*)(ws + O_ENE);
  int* entries_a = (int*)(ws + O_ENA);

  const int GB_E = (NE + 127) / 128;    // 469 (last block tail-guarded)
  const int GB_A = (NA + 127) / 128;    // 235

  hipMemcpyAsync(h_e, x_ent, (size_t)NE * 128 * 4, hipMemcpyDeviceToDevice, stream);
  hipMemcpyAsync(h_a, x_att, (size_t)NA * 128 * 4, hipMemcpyDeviceToDevice, stream);

  // ---- CSR build (graph identical across layers) ----
  hipMemsetAsync(ws + O_CUE, 0, 360000, stream);   // cursor_e + cursor_a
  deg_k<<<(E_EE + 255) / 256, 256, 0, stream>>>(ei_ee, E_EE, cursor_e);
  deg_k<<<(E_AE + 255) / 256, 256, 0, stream>>>(ei_ae, E_AE, cursor_e);
  deg_k<<<(E_EA + 255) / 256, 256, 0, stream>>>(ei_ea, E_EA, cursor_a);
  scan_k<<<1, 1024, 0, stream>>>(cursor_e, rowptr_e, NE);
  scan_k<<<1, 1024, 0, stream>>>(cursor_a, rowptr_a, NA);
  fill_k<<<(E_EE + 255) / 256, 256, 0, stream>>>(ei_ee, E_EE, cursor_e, entries_e, 0, 0);
  fill_k<<<(E_AE + 255) / 256, 256, 0, stream>>>(ei_ae, E_AE, cursor_e, entries_e, NE, 1);
  fill_k<<<(E_EA + 255) / 256, 256, 0, stream>>>(ei_ea, E_EA, cursor_a, entries_a, 0, 0);

  for (int l = 0; l < 2; ++l) {
    const float* Wke = Wkqv_e + (size_t)l * 49152;
    const float* Wka = Wkqv_a + (size_t)l * 49152;
    const float* bke = bkqv_e + (size_t)l * 384;
    const float* bka = bkqv_a + (size_t)l * 384;

    wrel_k<<<dim3(3, 2), 256, 0, stream>>>(Wke, Wka, bke, bka,
                                           a_rel + (size_t)l * 12288,
                                           m_rel + (size_t)l * 12288, Wkt, Wvt, bkt, bvt);
    // q projections (cols 128..255 of Wkqv)
    gemm128_k<0, 0><<<GB_E, 256, 0, stream>>>(h_e, 128, Wke + 128, 384, bke + 128, NE,
                                              q_e, nullptr, 128, nullptr, nullptr);
    gemm128_k<0, 0><<<GB_A, 256, 0, stream>>>(h_a, 128, Wka + 128, 384, bka + 128, NA,
                                              q_a, nullptr, 128, nullptr, nullptr);
    // kt/vt tables (bf16): rows [0,NE)=rel0(src e), [NE,NE+NA)=rel2(src a),
    //                      [90000,150000)=rel1(src e, dst a)
    gemm128_k<0, 2><<<GB_E, 256, 0, stream>>>(h_e, 128, Wkt, 128, bkt, NE,
                                              nullptr, ktbl, 128, nullptr, nullptr);
    gemm128_k<0, 2><<<GB_A, 256, 0, stream>>>(h_a, 128, Wkt + 2 * 16384, 128,
                                              bkt + 2 * 128, NA, nullptr,
                                              ktbl + (size_t)NE * 128, 128, nullptr, nullptr);
    gemm128_k<0, 2><<<GB_E, 256, 0, stream>>>(h_e, 128, Wkt + 1 * 16384, 128,
                                              bkt + 1 * 128, NE, nullptr,
                                              ktbl + (size_t)90000 * 128, 128, nullptr, nullptr);
    gemm128_k<0, 2><<<GB_E, 256, 0, stream>>>(h_e, 128, Wvt, 128, bvt, NE,
                                              nullptr, vtbl, 128, nullptr, nullptr);
    gemm128_k<0, 2><<<GB_A, 256, 0, stream>>>(h_a, 128, Wvt + 2 * 16384, 128,
                                              bvt + 2 * 128, NA, nullptr,
                                              vtbl + (size_t)NE * 128, 128, nullptr, nullptr);
    gemm128_k<0, 2><<<GB_E, 256, 0, stream>>>(h_e, 128, Wvt + 1 * 16384, 128,
                                              bvt + 1 * 128, NE, nullptr,
                                              vtbl + (size_t)90000 * 128, 128, nullptr, nullptr);
    // gather (writes message in-place over q buffers)
    hgt_gather_k<<<30000, 256, 0, stream>>>(q_e, ktbl, vtbl, rowptr_e, entries_e,
                                            p_rel + (size_t)l * 12, NE, q_e);
    hgt_gather_k<<<15000, 256, 0, stream>>>(q_a, ktbl + (size_t)90000 * 128,
                                            vtbl + (size_t)90000 * 128, rowptr_a,
                                            entries_a, p_rel + (size_t)l * 12 + 4, NA, q_a);
    // out proj (gelu on msg) + gated skip + inter-layer gelu, in-place on h
    gemm128_k<1, 3><<<GB_E, 256, 0, stream>>>(q_e, 128, Wout_e + (size_t)l * 16384, 128,
                                              bout_e + (size_t)l * 128, NE, h_e, nullptr,
                                              128, skip_e + l, nullptr);
    gemm128_k<1, 3><<<GB_A, 256, 0, stream>>>(q_a, 128, Wout_a + (size_t)l * 16384, 128,
                                              bout_a + (size_t)l * 128, NA, h_a, nullptr,
                                              128, skip_a + l, nullptr);
  }

  // -------- SGFormer --------
  gemm128_k<0, 0><<<GB_E, 256, 0, stream>>>(h_e, 128, sg_fc_W, 128, sg_fc_b, NE,
                                            tmpf, nullptr, 128, nullptr, nullptr);
  ln_k<float, float><<<NE, 128, 0, stream>>>(tmpf, nullptr, 1.f, 0.f, sg_ln0_g,
                                             sg_ln0_b, z0, 1);
  hipMemsetAsync(ws + O_KVS, 0, 264256, stream);
  gemm128_k<0, 2><<<dim3(GB_E, 4), 256, 0, stream>>>(z0, 128, sg_Wv, 512, sg_bv, NE,
                                                     nullptr, Vb, 512, nullptr, nullptr);
  gemm128_k<0, 2><<<dim3(GB_E, 4), 256, 0, stream>>>(z0, 128, sg_Wk, 512, sg_bk, NE,
                                                     nullptr, KQb, 512, nullptr, ssq_k);
  // partials into d_out (dead until final GEMM): 400 slabs x 64KB = 25.6MB <= 30.72MB
  kvsred_k<<<dim3(100, 4), 256, 0, stream>>>(KQb, Vb, (float*)d_out, ksum, 600);
  kvsfin_k<<<256, 256, 0, stream>>>((const float*)d_out, kvs, 100);
  gemm128_k<0, 2><<<dim3(GB_E, 4), 256, 0, stream>>>(z0, 128, sg_Wq, 512, sg_bq, NE,
                                                     nullptr, KQb, 512, nullptr, ssq_q);
  sgapply_k<<<GB_E, 256, 0, stream>>>(KQb, Vb, kvs, ksum, ssq_q, ssq_k, attnb, NE);
  ln_k<unsigned short, float><<<NE, 128, 0, stream>>>(attnb, z0, 0.5f, 0.5f, sg_ln1_g,
                                                      sg_ln1_b, z0, 0);
  ln_k<float, float><<<NE, 128, 0, stream>>>(h_e, z0, 0.9f, 0.1f, ln_ent_g, ln_ent_b,
                                             h_e, 0);
  gemm128_k<0, 1><<<GB_E, 256, 0, stream>>>(h_e, 128, proj_W1, 128, proj_b1, NE,
                                            z0, nullptr, 128, nullptr, nullptr);
  gemm128_k<0, 0><<<GB_E, 256, 0, stream>>>(z0, 128, proj_W2, 128, proj_b2, NE,
                                            (float*)d_out, nullptr, 128, nullptr, nullptr);
}

// Round 7
// 2069.938 us; speedup vs baseline: 1.0315x; 1.0315x over previous
//
#include <hip/hip_runtime.h>

// ---------------- constants ----------------
#define NE 60000
#define NA 30000
#define E_EE 150000
#define E_EA 75000
#define E_AE 75000
#define SCALE 0.17677669529663689f   // 1/sqrt(32)

__device__ __forceinline__ float bf2f(unsigned short u) {
  return __uint_as_float(((unsigned)u) << 16);
}
__device__ __forceinline__ unsigned short f2bf(float f) {
  unsigned u = __float_as_uint(f);
  u = u + 0x7FFFu + ((u >> 16) & 1u);   // RNE
  return (unsigned short)(u >> 16);
}
__device__ __forceinline__ float ldc(const float* p) { return *p; }
__device__ __forceinline__ float ldc(const unsigned short* p) { return bf2f(*p); }
__device__ __forceinline__ float gelu_f(float x) {
  return 0.5f * x * (1.0f + erff(x * 0.7071067811865476f));
}

// ---------------- fused relation weights (all f32) ----------------
__global__ __launch_bounds__(256) void wrel_k(
    const float* __restrict__ Wk_e, const float* __restrict__ Wk_a,
    const float* __restrict__ bk_e, const float* __restrict__ bk_a,
    const float* __restrict__ a_rel, const float* __restrict__ m_rel,
    float* __restrict__ Wkt, float* __restrict__ Wvt,
    float* __restrict__ bkt, float* __restrict__ bvt) {
  int t = blockIdx.x;        // relation 0..2
  int part = blockIdx.y;     // 0: key (a_rel, cols 0..127), 1: value (m_rel, cols 256..)
  const float* W = (t < 2) ? Wk_e : Wk_a;
  const float* bb = (t < 2) ? bk_e : bk_a;
  const float* A = (part ? m_rel : a_rel) + t * 4096;
  int coff = part ? 256 : 0;
  float* Wo = (part ? Wvt : Wkt) + t * 16384;
  float* bo = (part ? bvt : bkt) + t * 128;
  __shared__ float As[4096];
  for (int u = threadIdx.x; u < 4096; u += 256) As[u] = A[u];
  __syncthreads();
  for (int u = threadIdx.x; u < 16384; u += 256) {
    int i = u >> 7, c = u & 127;
    int hh = c >> 5, e = c & 31;
    const float* wr = W + i * 384 + coff + hh * 32;
    const float* ar = As + hh * 1024 + e;
    float acc = 0.f;
#pragma unroll
    for (int d = 0; d < 32; ++d) acc = fmaf(wr[d], ar[d * 32], acc);
    Wo[u] = acc;
  }
  if (threadIdx.x < 128) {
    int c = threadIdx.x, hh = c >> 5, e = c & 31;
    const float* br = bb + coff + hh * 32;
    const float* ar = As + hh * 1024 + e;
    float acc = 0.f;
#pragma unroll
    for (int d = 0; d < 32; ++d) acc = fmaf(br[d], ar[d * 32], acc);
    bo[c] = acc;
  }
}

// ---------------- tiled GEMM v5: 128 rows x 128 cols per block, 256 threads ---------
// 8x8 per-thread tile -> 2 FLOP/LDS-byte. K staged in 4 steps of 32. LDS 32KB.
// ACT: 0 none, 1 gelu(X).
// EPI: 0 f32 store; 1 relu f32; 2 bf16 store (+ atomic ssq if ssq!=null);
//      3 blend: fout = gelu(g*acc + (1-g)*fout), g = sigmoid(*skipp)
template <int ACT, int EPI>
__global__ __launch_bounds__(256) void gemm128_k(
    const float* __restrict__ X, int ldx,
    const float* __restrict__ W, int ldw,
    const float* __restrict__ bias, int N,
    float* __restrict__ fout, unsigned short* __restrict__ bout, int ldo,
    const float* __restrict__ skipp, float* __restrict__ ssq) {
  __shared__ float Xs[128 * 32];
  __shared__ float Ws[32 * 128];
  const int tid = threadIdx.x;
  const int ti = tid >> 4;             // 0..15 -> rows ti*8..+7
  const int tj = tid & 15;             // cols {tj*4..+3} and {64+tj*4..+3}
  const int row0 = blockIdx.x * 128;
  const int cb = blockIdx.y * 128;
  const int c0 = cb + tj * 4;
  const int c1 = cb + 64 + tj * 4;

  float acc[8][8];
  {
    float bc[8] = {0.f, 0.f, 0.f, 0.f, 0.f, 0.f, 0.f, 0.f};
    if (bias) {
#pragma unroll
      for (int j = 0; j < 4; ++j) { bc[j] = bias[c0 + j]; bc[4 + j] = bias[c1 + j]; }
    }
#pragma unroll
    for (int i = 0; i < 8; ++i)
#pragma unroll
      for (int j = 0; j < 8; ++j) acc[i][j] = bc[j];
  }

  for (int ks = 0; ks < 128; ks += 32) {
    __syncthreads();   // previous step's compute done before overwriting LDS
    for (int v = tid; v < 1024; v += 256) {
      int kq = v & 7, r = v >> 3;
      int rg = row0 + r; if (rg >= N) rg = N - 1;
      float4 x4 = *reinterpret_cast<const float4*>(X + (size_t)rg * ldx + ks + kq * 4);
      if (ACT == 1) {
        x4.x = gelu_f(x4.x); x4.y = gelu_f(x4.y);
        x4.z = gelu_f(x4.z); x4.w = gelu_f(x4.w);
      }
      *reinterpret_cast<float4*>(&Xs[r * 32 + ((kq ^ ((r >> 3) & 7)) << 2)]) = x4;
    }
    for (int v = tid; v < 1024; v += 256) {
      int cq = v & 31, k = v >> 5;
      *reinterpret_cast<float4*>(&Ws[k * 128 + cq * 4]) =
          *reinterpret_cast<const float4*>(W + (size_t)(ks + k) * ldw + cb + cq * 4);
    }
    __syncthreads();
#pragma unroll
    for (int k = 0; k < 32; k += 4) {
      float xr[8][4];
#pragma unroll
      for (int i = 0; i < 8; ++i)
        *reinterpret_cast<float4*>(xr[i]) = *reinterpret_cast<const float4*>(
            &Xs[(ti * 8 + i) * 32 + ((((k >> 2)) ^ (ti & 7)) << 2)]);
      float wr[4][8];
#pragma unroll
      for (int dk = 0; dk < 4; ++dk) {
        *reinterpret_cast<float4*>(&wr[dk][0]) =
            *reinterpret_cast<const float4*>(&Ws[(k + dk) * 128 + tj * 4]);
        *reinterpret_cast<float4*>(&wr[dk][4]) =
            *reinterpret_cast<const float4*>(&Ws[(k + dk) * 128 + 64 + tj * 4]);
      }
#pragma unroll
      for (int i = 0; i < 8; ++i)
#pragma unroll
        for (int dk = 0; dk < 4; ++dk)
#pragma unroll
          for (int j = 0; j < 8; ++j)
            acc[i][j] = fmaf(xr[i][dk], wr[dk][j], acc[i][j]);
    }
  }

  if (EPI == 0 || EPI == 1) {
#pragma unroll
    for (int i = 0; i < 8; ++i) {
      int rg = row0 + ti * 8 + i;
      if (rg < N) {
        float4 a = make_float4(acc[i][0], acc[i][1], acc[i][2], acc[i][3]);
        float4 b = make_float4(acc[i][4], acc[i][5], acc[i][6], acc[i][7]);
        if (EPI == 1) {
          a.x = fmaxf(a.x, 0.f); a.y = fmaxf(a.y, 0.f);
          a.z = fmaxf(a.z, 0.f); a.w = fmaxf(a.w, 0.f);
          b.x = fmaxf(b.x, 0.f); b.y = fmaxf(b.y, 0.f);
          b.z = fmaxf(b.z, 0.f); b.w = fmaxf(b.w, 0.f);
        }
        *reinterpret_cast<float4*>(fout + (size_t)rg * ldo + c0) = a;
        *reinterpret_cast<float4*>(fout + (size_t)rg * ldo + c1) = b;
      }
    }
  } else if (EPI == 2) {
    float loc = 0.f;
#pragma unroll
    for (int i = 0; i < 8; ++i) {
      int rg = row0 + ti * 8 + i;
      if (rg < N) {
        ushort4 s0, s1;
        s0.x = f2bf(acc[i][0]); s0.y = f2bf(acc[i][1]);
        s0.z = f2bf(acc[i][2]); s0.w = f2bf(acc[i][3]);
        s1.x = f2bf(acc[i][4]); s1.y = f2bf(acc[i][5]);
        s1.z = f2bf(acc[i][6]); s1.w = f2bf(acc[i][7]);
        *reinterpret_cast<ushort4*>(bout + (size_t)rg * ldo + c0) = s0;
        *reinterpret_cast<ushort4*>(bout + (size_t)rg * ldo + c1) = s1;
#pragma unroll
        for (int j = 0; j < 8; ++j) loc += acc[i][j] * acc[i][j];
      }
    }
    if (ssq) {
      __syncthreads();
      Xs[tid] = loc;
      __syncthreads();
      if (tid < 128) Xs[tid] += Xs[tid + 128];
      __syncthreads();
      if (tid < 64) {
        float v = Xs[tid] + Xs[tid + 64];
#pragma unroll
        for (int m = 32; m > 0; m >>= 1) v += __shfl_down(v, m, 64);
        if (tid == 0) atomicAdd(ssq, v);
      }
    }
  } else {  // EPI == 3
    float g = 1.f / (1.f + expf(-*skipp));
    float g1 = 1.f - g;
#pragma unroll
    for (int i = 0; i < 8; ++i) {
      int rg = row0 + ti * 8 + i;
      if (rg < N) {
        float4 o0 = *reinterpret_cast<const float4*>(fout + (size_t)rg * ldo + c0);
        float4 o1 = *reinterpret_cast<const float4*>(fout + (size_t)rg * ldo + c1);
        float4 a, b;
        a.x = gelu_f(g * acc[i][0] + g1 * o0.x);
        a.y = gelu_f(g * acc[i][1] + g1 * o0.y);
        a.z = gelu_f(g * acc[i][2] + g1 * o0.z);
        a.w = gelu_f(g * acc[i][3] + g1 * o0.w);
        b.x = gelu_f(g * acc[i][4] + g1 * o1.x);
        b.y = gelu_f(g * acc[i][5] + g1 * o1.y);
        b.z = gelu_f(g * acc[i][6] + g1 * o1.z);
        b.w = gelu_f(g * acc[i][7] + g1 * o1.w);
        *reinterpret_cast<float4*>(fout + (size_t)rg * ldo + c0) = a;
        *reinterpret_cast<float4*>(fout + (size_t)rg * ldo + c1) = b;
      }
    }
  }
}

// ---------------- CSR build ----------------
__global__ __launch_bounds__(256) void deg_k(const int* __restrict__ ei, int E,
                                             int* __restrict__ deg) {
  int i = blockIdx.x * 256 + threadIdx.x;
  if (i < E) atomicAdd(&deg[ei[E + i]], 1);
}

// exclusive scan over deg_cursor[0..n), writing rowptr[0..n] and exclusive back
// into deg_cursor (becomes the fill cursor). Single block, 1024 threads.
__global__ __launch_bounds__(1024) void scan_k(int* __restrict__ deg_cursor,
                                               int* __restrict__ rowptr, int n) {
  __shared__ int sd[1024];
  __shared__ int carry;
  int tid = threadIdx.x;
  if (tid == 0) carry = 0;
  __syncthreads();
  for (int base = 0; base < n; base += 1024) {
    int v = (base + tid < n) ? deg_cursor[base + tid] : 0;
    sd[tid] = v;
    __syncthreads();
    for (int off = 1; off < 1024; off <<= 1) {
      int t = (tid >= off) ? sd[tid - off] : 0;
      __syncthreads();
      sd[tid] += t;
      __syncthreads();
    }
    int c0 = carry;
    if (base + tid < n) {
      int excl = c0 + sd[tid] - v;
      rowptr[base + tid] = excl;
      deg_cursor[base + tid] = excl;
    }
    __syncthreads();
    if (tid == 0) carry = c0 + sd[1023];
    __syncthreads();
  }
  if (tid == 0) rowptr[n] = carry;
}

__global__ __launch_bounds__(256) void fill_k(const int* __restrict__ ei, int E,
                                              int* __restrict__ cursor,
                                              int* __restrict__ entries,
                                              int srcoff, int tag) {
  int i = blockIdx.x * 256 + threadIdx.x;
  if (i < E) {
    int pos = atomicAdd(&cursor[ei[E + i]], 1);
    entries[pos] = (ei[i] + srcoff) | (tag << 30);
  }
}

// ---------------- HGT gather: one 32-lane group per (dst, head), no atomics --------
__global__ __launch_bounds__(256) void hgt_gather_k(
    const float* __restrict__ q, const unsigned short* __restrict__ ktbl,
    const unsigned short* __restrict__ vtbl, const int* __restrict__ rowptr,
    const int* __restrict__ entries, const float* __restrict__ pbase, int nd,
    float* __restrict__ out) {
  int g = blockIdx.x * 8 + (threadIdx.x >> 5);
  int dst = g >> 2, h = g & 3, c = threadIdx.x & 31;
  if (dst >= nd) return;
  int col = h * 32 + c;
  float qv = q[(size_t)dst * 128 + col];
  int i0 = rowptr[dst], i1 = rowptr[dst + 1];
  float sum = 0.f, acc = 0.f;
  for (int i = i0; i < i1; ++i) {
    int e = entries[i];
    int lin = e & 0x3FFFFFFF;
    int tag = (unsigned)e >> 30;
    float part = qv * bf2f(ktbl[(size_t)lin * 128 + col]);
#pragma unroll
    for (int m = 16; m > 0; m >>= 1) part += __shfl_xor(part, m);
    float w = expf(part * SCALE * pbase[tag * 8 + h]);
    sum += w;
    acc = fmaf(w, bf2f(vtbl[(size_t)lin * 128 + col]), acc);
  }
  out[(size_t)dst * 128 + col] = acc / (sum + 1e-16f);
}

// ---------------- LayerNorm (row=128): out = LN(alpha*A + beta*B)*g + b -------------
template <typename AT, typename BT>
__global__ __launch_bounds__(128) void ln_k(const AT* __restrict__ A,
                                            const BT* __restrict__ B, float alpha,
                                            float beta, const float* __restrict__ g,
                                            const float* __restrict__ b,
                                            float* __restrict__ out, int relu) {
  int row = blockIdx.x;
  int t = threadIdx.x;
  float v = alpha * ldc(A + (size_t)row * 128 + t);
  if (B) v += beta * ldc(B + (size_t)row * 128 + t);
  float s1 = v, s2 = v * v;
#pragma unroll
  for (int m = 32; m > 0; m >>= 1) {
    s1 += __shfl_xor(s1, m, 64);
    s2 += __shfl_xor(s2, m, 64);
  }
  __shared__ float r1[2], r2[2];
  int w = t >> 6;
  if ((t & 63) == 0) { r1[w] = s1; r2[w] = s2; }
  __syncthreads();
  float S1 = r1[0] + r1[1], S2 = r2[0] + r2[1];
  float mu = S1 * (1.f / 128.f);
  float var = S2 * (1.f / 128.f) - mu * mu;
  float rr = rsqrtf(fmaxf(var, 0.f) + 1e-5f);
  float o = (v - mu) * rr * g[t] + b[t];
  if (relu) o = fmaxf(o, 0.f);
  out[(size_t)row * 128 + t] = o;
}

// ---------------- kvs partial: part[g][h][128][128] = sum_{n in chunk g} K V^T ------
__global__ __launch_bounds__(256) void kvsred_k(const unsigned short* __restrict__ Kb,
                                                const unsigned short* __restrict__ Vb,
                                                float* __restrict__ part,
                                                float* __restrict__ ksum, int chunk) {
  const int h = blockIdx.y;
  const int n0 = blockIdx.x * chunk;
  const int iters = chunk >> 3;          // 75
  __shared__ float ks[8][132];
  __shared__ float vs[8][132];
  const int tid = threadIdx.x;
  const int ti = tid >> 4, tj = tid & 15;

  const int sw = tid >> 7;               // 0 = K, 1 = V
  const int sni = (tid >> 4) & 7;        // row within 8-row tile
  const int sc = (tid & 15) << 3;        // col base (8 bf16 per thread)
  const unsigned short* src =
      (sw ? Vb : Kb) + (size_t)(n0 + sni) * 512 + h * 128 + sc;
  float* dstrow = (sw ? &vs[0][0] : &ks[0][0]) + sni * 132 + sc;

  float acc[8][8];
#pragma unroll
  for (int i = 0; i < 8; ++i)
#pragma unroll
    for (int j = 0; j < 8; ++j) acc[i][j] = 0.f;
  float ksloc = 0.f;

  uint4 r = *reinterpret_cast<const uint4*>(src);
  for (int it = 0; it < iters; ++it) {
    __syncthreads();
    float4 lo, hi;
    lo.x = bf2f((unsigned short)(r.x & 0xffffu)); lo.y = bf2f((unsigned short)(r.x >> 16));
    lo.z = bf2f((unsigned short)(r.y & 0xffffu)); lo.w = bf2f((unsigned short)(r.y >> 16));
    hi.x = bf2f((unsigned short)(r.z & 0xffffu)); hi.y = bf2f((unsigned short)(r.z >> 16));
    hi.z = bf2f((unsigned short)(r.w & 0xffffu)); hi.w = bf2f((unsigned short)(r.w >> 16));
    *reinterpret_cast<float4*>(dstrow) = lo;
    *reinterpret_cast<float4*>(dstrow + 4) = hi;
    if (it + 1 < iters)
      r = *reinterpret_cast<const uint4*>(src + (size_t)(it + 1) * 8 * 512);
    __syncthreads();
#pragma unroll
    for (int ni = 0; ni < 8; ++ni) {
      float kk[8], vv[8];
      *reinterpret_cast<float4*>(kk) =
          *reinterpret_cast<const float4*>(&ks[ni][ti * 4]);
      *reinterpret_cast<float4*>(kk + 4) =
          *reinterpret_cast<const float4*>(&ks[ni][64 + ti * 4]);
      *reinterpret_cast<float4*>(vv) =
          *reinterpret_cast<const float4*>(&vs[ni][tj * 4]);
      *reinterpret_cast<float4*>(vv + 4) =
          *reinterpret_cast<const float4*>(&vs[ni][64 + tj * 4]);
#pragma unroll
      for (int i = 0; i < 8; ++i)
#pragma unroll
        for (int j = 0; j < 8; ++j) acc[i][j] = fmaf(kk[i], vv[j], acc[i][j]);
      if (tid < 128) ksloc += ks[ni][tid];
    }
  }
  float* pb = part + (size_t)(blockIdx.x * 4 + h) * 16384;
#pragma unroll
  for (int i = 0; i < 8; ++i) {
    int m = ti * 4 + (i & 3) + ((i >> 2) << 6);
    *reinterpret_cast<float4*>(pb + m * 128 + tj * 4) =
        make_float4(acc[i][0], acc[i][1], acc[i][2], acc[i][3]);
    *reinterpret_cast<float4*>(pb + m * 128 + 64 + tj * 4) =
        make_float4(acc[i][4], acc[i][5], acc[i][6], acc[i][7]);
  }
  if (tid < 128) atomicAdd(&ksum[h * 128 + tid], ksloc);
}

// ---------------- kvs final reduce: kvs[c] = sum_g part[g][c] ----------------------
__global__ __launch_bounds__(256) void kvsfin_k(const float* __restrict__ part,
                                                float* __restrict__ kvs, int G) {
  int c = blockIdx.x * 256 + threadIdx.x;   // c = h*16384 + m*128 + d, 65536 total
  int hh = c >> 14, md = c & 16383;
  const float* p = part + (size_t)hh * 16384 + md;
  float s = 0.f;
#pragma unroll 4
  for (int g = 0; g < G; ++g) s += p[(size_t)g * 65536];
  kvs[c] = s;
}

// ---------------- SG attention apply v3: gemm128 k-loop, f32 global accumulator -----
// v2 regressed (VGPR 240, 1 block/CU): out[8][8] persisted across heads in registers.
// v3 evicts it: per head, contribution (acc*f + 60000*V)/den is read-modify-written
// into outacc (f32, d_out slab — dead until final GEMM). No atomics: each block owns
// its 128 rows exclusively; h==0 writes, h>0 RMW. OOB rows SKIP (no clamp -> no
// double-RMW). Register budget back to gemm128's proven envelope.
__global__ __launch_bounds__(256) void sgapply_k(const unsigned short* __restrict__ Qb,
                                                 const unsigned short* __restrict__ Vb,
                                                 const float* __restrict__ kvs,
                                                 const float* __restrict__ ksum,
                                                 const float* __restrict__ ssqq,
                                                 const float* __restrict__ ssqk,
                                                 float* __restrict__ outacc,
                                                 int N) {
  __shared__ float Xs[128 * 32];
  __shared__ float Ws[32 * 128];
  __shared__ float kss[32];
  __shared__ float fsh_s;
  const int tid = threadIdx.x;
  const int ti = tid >> 4;
  const int tj = tid & 15;
  const int row0 = blockIdx.x * 128;
  if (tid == 0) fsh_s = 1.0f / (sqrtf(*ssqq) * sqrtf(*ssqk));

  for (int h = 0; h < 4; ++h) {
    float acc[8][8];
    float den[8];
#pragma unroll
    for (int i = 0; i < 8; ++i) {
      den[i] = 0.f;
#pragma unroll
      for (int j = 0; j < 8; ++j) acc[i][j] = 0.f;
    }
    for (int ks = 0; ks < 128; ks += 32) {
      __syncthreads();   // previous chunk/head compute done before overwrite
      for (int v = tid; v < 1024; v += 256) {
        int kq = v & 7, r = v >> 3;
        int rg = row0 + r; if (rg >= N) rg = N - 1;
        ushort4 q4 = *reinterpret_cast<const ushort4*>(
            Qb + (size_t)rg * 512 + h * 128 + ks + kq * 4);
        float4 x4 = make_float4(bf2f(q4.x), bf2f(q4.y), bf2f(q4.z), bf2f(q4.w));
        *reinterpret_cast<float4*>(&Xs[r * 32 + ((kq ^ ((r >> 3) & 7)) << 2)]) = x4;
      }
      for (int v = tid; v < 1024; v += 256) {
        int cq = v & 31, k = v >> 5;
        *reinterpret_cast<float4*>(&Ws[k * 128 + cq * 4]) =
            *reinterpret_cast<const float4*>(kvs + (size_t)h * 16384 +
                                             (size_t)(ks + k) * 128 + cq * 4);
      }
      if (tid < 32) kss[tid] = ksum[h * 128 + ks + tid];
      __syncthreads();
#pragma unroll
      for (int k = 0; k < 32; k += 4) {
        float xr[8][4];
#pragma unroll
        for (int i = 0; i < 8; ++i)
          *reinterpret_cast<float4*>(xr[i]) = *reinterpret_cast<const float4*>(
              &Xs[(ti * 8 + i) * 32 + ((((k >> 2)) ^ (ti & 7)) << 2)]);
        float wr[4][8];
        float kv[4];
#pragma unroll
        for (int dk = 0; dk < 4; ++dk) {
          *reinterpret_cast<float4*>(&wr[dk][0]) =
              *reinterpret_cast<const float4*>(&Ws[(k + dk) * 128 + tj * 4]);
          *reinterpret_cast<float4*>(&wr[dk][4]) =
              *reinterpret_cast<const float4*>(&Ws[(k + dk) * 128 + 64 + tj * 4]);
          kv[dk] = kss[k + dk];
        }
#pragma unroll
        for (int i = 0; i < 8; ++i)
#pragma unroll
          for (int dk = 0; dk < 4; ++dk) {
            den[i] = fmaf(xr[i][dk], kv[dk], den[i]);
#pragma unroll
            for (int j = 0; j < 8; ++j)
              acc[i][j] = fmaf(xr[i][dk], wr[dk][j], acc[i][j]);
          }
      }
    }
    // fold this head into the f32 global accumulator (block owns its rows)
    float f = fsh_s;
#pragma unroll
    for (int i = 0; i < 8; ++i) {
      int rg = row0 + ti * 8 + i;
      if (rg < N) {
        ushort4 v0 = *reinterpret_cast<const ushort4*>(
            Vb + (size_t)rg * 512 + h * 128 + tj * 4);
        ushort4 v1 = *reinterpret_cast<const ushort4*>(
            Vb + (size_t)rg * 512 + h * 128 + 64 + tj * 4);
        float rd = 1.0f / (den[i] * f + 60000.0f);
        float4 a, b;
        a.x = (acc[i][0] * f + 60000.0f * bf2f(v0.x)) * rd;
        a.y = (acc[i][1] * f + 60000.0f * bf2f(v0.y)) * rd;
        a.z = (acc[i][2] * f + 60000.0f * bf2f(v0.z)) * rd;
        a.w = (acc[i][3] * f + 60000.0f * bf2f(v0.w)) * rd;
        b.x = (acc[i][4] * f + 60000.0f * bf2f(v1.x)) * rd;
        b.y = (acc[i][5] * f + 60000.0f * bf2f(v1.y)) * rd;
        b.z = (acc[i][6] * f + 60000.0f * bf2f(v1.z)) * rd;
        b.w = (acc[i][7] * f + 60000.0f * bf2f(v1.w)) * rd;
        float* p0 = outacc + (size_t)rg * 128 + tj * 4;
        float* p1 = outacc + (size_t)rg * 128 + 64 + tj * 4;
        if (h > 0) {
          float4 o0 = *reinterpret_cast<const float4*>(p0);
          float4 o1 = *reinterpret_cast<const float4*>(p1);
          a.x += o0.x; a.y += o0.y; a.z += o0.z; a.w += o0.w;
          b.x += o1.x; b.y += o1.y; b.z += o1.z; b.w += o1.w;
        }
        *reinterpret_cast<float4*>(p0) = a;
        *reinterpret_cast<float4*>(p1) = b;
      }
    }
  }
}

// ---------------- host ----------------
extern "C" void kernel_launch(void* const* d_in, const int* in_sizes, int n_in,
                              void* d_out, int out_size, void* d_ws, size_t ws_size,
                              hipStream_t stream) {
  const float* x_ent = (const float*)d_in[0];
  const float* x_att = (const float*)d_in[1];
  const float* Wkqv_e = (const float*)d_in[2];
  const float* bkqv_e = (const float*)d_in[3];
  const float* Wkqv_a = (const float*)d_in[4];
  const float* bkqv_a = (const float*)d_in[5];
  const float* Wout_e = (const float*)d_in[6];
  const float* bout_e = (const float*)d_in[7];
  const float* Wout_a = (const float*)d_in[8];
  const float* bout_a = (const float*)d_in[9];
  const float* skip_e = (const float*)d_in[10];
  const float* skip_a = (const float*)d_in[11];
  const float* a_rel = (const float*)d_in[12];
  const float* m_rel = (const float*)d_in[13];
  const float* p_rel = (const float*)d_in[14];
  const float* ln_ent_g = (const float*)d_in[15];
  const float* ln_ent_b = (const float*)d_in[16];
  const float* sg_fc_W = (const float*)d_in[17];
  const float* sg_fc_b = (const float*)d_in[18];
  const float* sg_ln0_g = (const float*)d_in[19];
  const float* sg_ln0_b = (const float*)d_in[20];
  const float* sg_Wq = (const float*)d_in[21];
  const float* sg_bq = (const float*)d_in[22];
  const float* sg_Wk = (const float*)d_in[23];
  const float* sg_bk = (const float*)d_in[24];
  const float* sg_Wv = (const float*)d_in[25];
  const float* sg_bv = (const float*)d_in[26];
  const float* sg_ln1_g = (const float*)d_in[27];
  const float* sg_ln1_b = (const float*)d_in[28];
  const float* proj_W1 = (const float*)d_in[29];
  const float* proj_b1 = (const float*)d_in[30];
  const float* proj_W2 = (const float*)d_in[31];
  const float* proj_b2 = (const float*)d_in[32];
  const int* ei_ee = (const int*)d_in[33];
  const int* ei_ea = (const int*)d_in[34];
  const int* ei_ae = (const int*)d_in[35];

  char* ws = (char*)d_ws;
  // ---- fixed region ----
  const size_t O_HE = 0;                         // h_e f32 (30.72M)
  const size_t O_HA = 30720000;                  // h_a f32 (15.36M)
  const size_t O_Z0 = 46080000;                  // z0 f32 (30.72M)
  const size_t O_WKT = 76800000;                 // 3*16384 f32
  const size_t O_WVT = 76996608;
  const size_t O_BKT = 77193216;
  const size_t O_BVT = 77194752;
  const size_t O_KVS = 77196288;                 // kvs(262144)+ksum(2048)+ssq(64)
  // ---- CSR region ----
  const size_t O_RPE = 77460544;                 // rowptr_e (60001) -> 240064
  const size_t O_RPA = O_RPE + 240064;           // rowptr_a (30001) -> 120064
  const size_t O_CUE = O_RPA + 120064;           // cursor/deg_e -> 240000
  const size_t O_CUA = O_CUE + 240000;           // cursor/deg_a -> 120000
  const size_t O_ENE = O_CUA + 120000;           // entries_e (225000) -> 900000
  const size_t O_ENA = O_ENE + 900000;           // entries_a (75000) -> 300000
  const size_t O_UN = O_ENA + 300000;            // union; 79,380,672
  // HGT view of union:
  float* q_e = (float*)(ws + O_UN);                                 // 30.72M (also out_e)
  float* q_a = (float*)(ws + O_UN + 30720000);                      // 15.36M (also out_a)
  unsigned short* ktbl = (unsigned short*)(ws + O_UN + 46080000);   // 150000x128 bf16
  unsigned short* vtbl = (unsigned short*)(ws + O_UN + 84480000);   // 150000x128 bf16
  // SG view of union:
  float* tmpf = (float*)(ws + O_UN);                                // fc out f32
  unsigned short* Vb = (unsigned short*)(ws + O_UN);                // NE*512 bf16
  unsigned short* KQb = (unsigned short*)(ws + O_UN + 61440000);    // K then Q

  float* h_e = (float*)(ws + O_HE);
  float* h_a = (float*)(ws + O_HA);
  float* z0 = (float*)(ws + O_Z0);
  float* Wkt = (float*)(ws + O_WKT);
  float* Wvt = (float*)(ws + O_WVT);
  float* bkt = (float*)(ws + O_BKT);
  float* bvt = (float*)(ws + O_BVT);
  float* kvs = (float*)(ws + O_KVS);
  float* ksum = (float*)(ws + O_KVS + 262144);
  float* ssq_q = (float*)(ws + O_KVS + 262144 + 2048);
  float* ssq_k = ssq_q + 1;
  int* rowptr_e = (int*)(ws + O_RPE);
  int* rowptr_a = (int*)(ws + O_RPA);
  int* cursor_e = (int*)(ws + O_CUE);
  int* cursor_a = (int*)(ws + O_CUA);
  int* entries_e = (int*)(ws + O_ENE);
  int* entries_a = (int*)(ws + O_ENA);

  const int GB_E = (NE + 127) / 128;    // 469 (last block tail-guarded)
  const int GB_A = (NA + 127) / 128;    // 235

  hipMemcpyAsync(h_e, x_ent, (size_t)NE * 128 * 4, hipMemcpyDeviceToDevice, stream);
  hipMemcpyAsync(h_a, x_att, (size_t)NA * 128 * 4, hipMemcpyDeviceToDevice, stream);

  // ---- CSR build (graph identical across layers) ----
  hipMemsetAsync(ws + O_CUE, 0, 360000, stream);   // cursor_e + cursor_a
  deg_k<<<(E_EE + 255) / 256, 256, 0, stream>>>(ei_ee, E_EE, cursor_e);
  deg_k<<<(E_AE + 255) / 256, 256, 0, stream>>>(ei_ae, E_AE, cursor_e);
  deg_k<<<(E_EA + 255) / 256, 256, 0, stream>>>(ei_ea, E_EA, cursor_a);
  scan_k<<<1, 1024, 0, stream>>>(cursor_e, rowptr_e, NE);
  scan_k<<<1, 1024, 0, stream>>>(cursor_a, rowptr_a, NA);
  fill_k<<<(E_EE + 255) / 256, 256, 0, stream>>>(ei_ee, E_EE, cursor_e, entries_e, 0, 0);
  fill_k<<<(E_AE + 255) / 256, 256, 0, stream>>>(ei_ae, E_AE, cursor_e, entries_e, NE, 1);
  fill_k<<<(E_EA + 255) / 256, 256, 0, stream>>>(ei_ea, E_EA, cursor_a, entries_a, 0, 0);

  for (int l = 0; l < 2; ++l) {
    const float* Wke = Wkqv_e + (size_t)l * 49152;
    const float* Wka = Wkqv_a + (size_t)l * 49152;
    const float* bke = bkqv_e + (size_t)l * 384;
    const float* bka = bkqv_a + (size_t)l * 384;

    wrel_k<<<dim3(3, 2), 256, 0, stream>>>(Wke, Wka, bke, bka,
                                           a_rel + (size_t)l * 12288,
                                           m_rel + (size_t)l * 12288, Wkt, Wvt, bkt, bvt);
    // q projections (cols 128..255 of Wkqv)
    gemm128_k<0, 0><<<GB_E, 256, 0, stream>>>(h_e, 128, Wke + 128, 384, bke + 128, NE,
                                              q_e, nullptr, 128, nullptr, nullptr);
    gemm128_k<0, 0><<<GB_A, 256, 0, stream>>>(h_a, 128, Wka + 128, 384, bka + 128, NA,
                                              q_a, nullptr, 128, nullptr, nullptr);
    // kt/vt tables (bf16): rows [0,NE)=rel0(src e), [NE,NE+NA)=rel2(src a),
    //                      [90000,150000)=rel1(src e, dst a)
    gemm128_k<0, 2><<<GB_E, 256, 0, stream>>>(h_e, 128, Wkt, 128, bkt, NE,
                                              nullptr, ktbl, 128, nullptr, nullptr);
    gemm128_k<0, 2><<<GB_A, 256, 0, stream>>>(h_a, 128, Wkt + 2 * 16384, 128,
                                              bkt + 2 * 128, NA, nullptr,
                                              ktbl + (size_t)NE * 128, 128, nullptr, nullptr);
    gemm128_k<0, 2><<<GB_E, 256, 0, stream>>>(h_e, 128, Wkt + 1 * 16384, 128,
                                              bkt + 1 * 128, NE, nullptr,
                                              ktbl + (size_t)90000 * 128, 128, nullptr, nullptr);
    gemm128_k<0, 2><<<GB_E, 256, 0, stream>>>(h_e, 128, Wvt, 128, bvt, NE,
                                              nullptr, vtbl, 128, nullptr, nullptr);
    gemm128_k<0, 2><<<GB_A, 256, 0, stream>>>(h_a, 128, Wvt + 2 * 16384, 128,
                                              bvt + 2 * 128, NA, nullptr,
                                              vtbl + (size_t)NE * 128, 128, nullptr, nullptr);
    gemm128_k<0, 2><<<GB_E, 256, 0, stream>>>(h_e, 128, Wvt + 1 * 16384, 128,
                                              bvt + 1 * 128, NE, nullptr,
                                              vtbl + (size_t)90000 * 128, 128, nullptr, nullptr);
    // gather (writes message in-place over q buffers)
    hgt_gather_k<<<30000, 256, 0, stream>>>(q_e, ktbl, vtbl, rowptr_e, entries_e,
                                            p_rel + (size_t)l * 12, NE, q_e);
    hgt_gather_k<<<15000, 256, 0, stream>>>(q_a, ktbl + (size_t)90000 * 128,
                                            vtbl + (size_t)90000 * 128, rowptr_a,
                                            entries_a, p_rel + (size_t)l * 12 + 4, NA, q_a);
    // out proj (gelu on msg) + gated skip + inter-layer gelu, in-place on h
    gemm128_k<1, 3><<<GB_E, 256, 0, stream>>>(q_e, 128, Wout_e + (size_t)l * 16384, 128,
                                              bout_e + (size_t)l * 128, NE, h_e, nullptr,
                                              128, skip_e + l, nullptr);
    gemm128_k<1, 3><<<GB_A, 256, 0, stream>>>(q_a, 128, Wout_a + (size_t)l * 16384, 128,
                                              bout_a + (size_t)l * 128, NA, h_a, nullptr,
                                              128, skip_a + l, nullptr);
  }

  // -------- SGFormer --------
  gemm128_k<0, 0><<<GB_E, 256, 0, stream>>>(h_e, 128, sg_fc_W, 128, sg_fc_b, NE,
                                            tmpf, nullptr, 128, nullptr, nullptr);
  ln_k<float, float><<<NE, 128, 0, stream>>>(tmpf, nullptr, 1.f, 0.f, sg_ln0_g,
                                             sg_ln0_b, z0, 1);
  hipMemsetAsync(ws + O_KVS, 0, 264256, stream);
  gemm128_k<0, 2><<<dim3(GB_E, 4), 256, 0, stream>>>(z0, 128, sg_Wv, 512, sg_bv, NE,
                                                     nullptr, Vb, 512, nullptr, nullptr);
  gemm128_k<0, 2><<<dim3(GB_E, 4), 256, 0, stream>>>(z0, 128, sg_Wk, 512, sg_bk, NE,
                                                     nullptr, KQb, 512, nullptr, ssq_k);
  // partials into d_out (dead until sgapply): 400 slabs x 64KB = 25.6MB <= 30.72MB
  kvsred_k<<<dim3(100, 4), 256, 0, stream>>>(KQb, Vb, (float*)d_out, ksum, 600);
  kvsfin_k<<<256, 256, 0, stream>>>((const float*)d_out, kvs, 100);
  gemm128_k<0, 2><<<dim3(GB_E, 4), 256, 0, stream>>>(z0, 128, sg_Wq, 512, sg_bq, NE,
                                                     nullptr, KQb, 512, nullptr, ssq_q);
  // sgapply accumulates f32 head sums into d_out (kvs partials already consumed)
  sgapply_k<<<GB_E, 256, 0, stream>>>(KQb, Vb, kvs, ksum, ssq_q, ssq_k,
                                      (float*)d_out, NE);
  // h_global = LN(0.5*mean(out) + 0.5*z0) = LN(0.125*sum + 0.5*z0)
  ln_k<float, float><<<NE, 128, 0, stream>>>((const float*)d_out, z0, 0.125f, 0.5f,
                                             sg_ln1_g, sg_ln1_b, z0, 0);
  ln_k<float, float><<<NE, 128, 0, stream>>>(h_e, z0, 0.9f, 0.1f, ln_ent_g, ln_ent_b,
                                             h_e, 0);
  gemm128_k<0, 1><<<GB_E, 256, 0, stream>>>(h_e, 128, proj_W1, 128, proj_b1, NE,
                                            z0, nullptr, 128, nullptr, nullptr);
  gemm128_k<0, 0><<<GB_E, 256, 0, stream>>>(z0, 128, proj_W2, 128, proj_b2, NE,
                                            (float*)d_out, nullptr, 128, nullptr, nullptr);
}

// Round 8
// 2025.109 us; speedup vs baseline: 1.0543x; 1.0221x over previous
//
#include <hip/hip_runtime.h>

// ---------------- constants ----------------
#define NE 60000
#define NA 30000
#define E_EE 150000
#define E_EA 75000
#define E_AE 75000
#define SCALE 0.17677669529663689f   // 1/sqrt(32)

__device__ __forceinline__ float bf2f(unsigned short u) {
  return __uint_as_float(((unsigned)u) << 16);
}
__device__ __forceinline__ unsigned short f2bf(float f) {
  unsigned u = __float_as_uint(f);
  u = u + 0x7FFFu + ((u >> 16) & 1u);   // RNE
  return (unsigned short)(u >> 16);
}
__device__ __forceinline__ float ldc(const float* p) { return *p; }
__device__ __forceinline__ float ldc(const unsigned short* p) { return bf2f(*p); }
__device__ __forceinline__ float gelu_f(float x) {
  return 0.5f * x * (1.0f + erff(x * 0.7071067811865476f));
}

// ---------------- fused relation weights (all f32) ----------------
__global__ __launch_bounds__(256) void wrel_k(
    const float* __restrict__ Wk_e, const float* __restrict__ Wk_a,
    const float* __restrict__ bk_e, const float* __restrict__ bk_a,
    const float* __restrict__ a_rel, const float* __restrict__ m_rel,
    float* __restrict__ Wkt, float* __restrict__ Wvt,
    float* __restrict__ bkt, float* __restrict__ bvt) {
  int t = blockIdx.x;        // relation 0..2
  int part = blockIdx.y;     // 0: key (a_rel, cols 0..127), 1: value (m_rel, cols 256..)
  const float* W = (t < 2) ? Wk_e : Wk_a;
  const float* bb = (t < 2) ? bk_e : bk_a;
  const float* A = (part ? m_rel : a_rel) + t * 4096;
  int coff = part ? 256 : 0;
  float* Wo = (part ? Wvt : Wkt) + t * 16384;
  float* bo = (part ? bvt : bkt) + t * 128;
  __shared__ float As[4096];
  for (int u = threadIdx.x; u < 4096; u += 256) As[u] = A[u];
  __syncthreads();
  for (int u = threadIdx.x; u < 16384; u += 256) {
    int i = u >> 7, c = u & 127;
    int hh = c >> 5, e = c & 31;
    const float* wr = W + i * 384 + coff + hh * 32;
    const float* ar = As + hh * 1024 + e;
    float acc = 0.f;
#pragma unroll
    for (int d = 0; d < 32; ++d) acc = fmaf(wr[d], ar[d * 32], acc);
    Wo[u] = acc;
  }
  if (threadIdx.x < 128) {
    int c = threadIdx.x, hh = c >> 5, e = c & 31;
    const float* br = bb + coff + hh * 32;
    const float* ar = As + hh * 1024 + e;
    float acc = 0.f;
#pragma unroll
    for (int d = 0; d < 32; ++d) acc = fmaf(br[d], ar[d * 32], acc);
    bo[c] = acc;
  }
}

// ---------------- tiled GEMM (128-row): used where grid >= ~1800 blocks ------------
// 8x8 per-thread tile, 0.5 B/FLOP LDS intensity (100% VALU cap). Keep for the
// dim3(·,4) V/K/Q dispatches (1876 blocks, well-occupied).
template <int ACT, int EPI>
__global__ __launch_bounds__(256) void gemm128_k(
    const float* __restrict__ X, int ldx,
    const float* __restrict__ W, int ldw,
    const float* __restrict__ bias, int N,
    float* __restrict__ fout, unsigned short* __restrict__ bout, int ldo,
    const float* __restrict__ skipp, float* __restrict__ ssq) {
  __shared__ float Xs[128 * 32];
  __shared__ float Ws[32 * 128];
  const int tid = threadIdx.x;
  const int ti = tid >> 4;             // 0..15 -> rows ti*8..+7
  const int tj = tid & 15;             // cols {tj*4..+3} and {64+tj*4..+3}
  const int row0 = blockIdx.x * 128;
  const int cb = blockIdx.y * 128;
  const int c0 = cb + tj * 4;
  const int c1 = cb + 64 + tj * 4;

  float acc[8][8];
  {
    float bc[8] = {0.f, 0.f, 0.f, 0.f, 0.f, 0.f, 0.f, 0.f};
    if (bias) {
#pragma unroll
      for (int j = 0; j < 4; ++j) { bc[j] = bias[c0 + j]; bc[4 + j] = bias[c1 + j]; }
    }
#pragma unroll
    for (int i = 0; i < 8; ++i)
#pragma unroll
      for (int j = 0; j < 8; ++j) acc[i][j] = bc[j];
  }

  for (int ks = 0; ks < 128; ks += 32) {
    __syncthreads();
    for (int v = tid; v < 1024; v += 256) {
      int kq = v & 7, r = v >> 3;
      int rg = row0 + r; if (rg >= N) rg = N - 1;
      float4 x4 = *reinterpret_cast<const float4*>(X + (size_t)rg * ldx + ks + kq * 4);
      if (ACT == 1) {
        x4.x = gelu_f(x4.x); x4.y = gelu_f(x4.y);
        x4.z = gelu_f(x4.z); x4.w = gelu_f(x4.w);
      }
      *reinterpret_cast<float4*>(&Xs[r * 32 + ((kq ^ ((r >> 3) & 7)) << 2)]) = x4;
    }
    for (int v = tid; v < 1024; v += 256) {
      int cq = v & 31, k = v >> 5;
      *reinterpret_cast<float4*>(&Ws[k * 128 + cq * 4]) =
          *reinterpret_cast<const float4*>(W + (size_t)(ks + k) * ldw + cb + cq * 4);
    }
    __syncthreads();
#pragma unroll
    for (int k = 0; k < 32; k += 4) {
      float xr[8][4];
#pragma unroll
      for (int i = 0; i < 8; ++i)
        *reinterpret_cast<float4*>(xr[i]) = *reinterpret_cast<const float4*>(
            &Xs[(ti * 8 + i) * 32 + ((((k >> 2)) ^ (ti & 7)) << 2)]);
      float wr[4][8];
#pragma unroll
      for (int dk = 0; dk < 4; ++dk) {
        *reinterpret_cast<float4*>(&wr[dk][0]) =
            *reinterpret_cast<const float4*>(&Ws[(k + dk) * 128 + tj * 4]);
        *reinterpret_cast<float4*>(&wr[dk][4]) =
            *reinterpret_cast<const float4*>(&Ws[(k + dk) * 128 + 64 + tj * 4]);
      }
#pragma unroll
      for (int i = 0; i < 8; ++i)
#pragma unroll
        for (int dk = 0; dk < 4; ++dk)
#pragma unroll
          for (int j = 0; j < 8; ++j)
            acc[i][j] = fmaf(xr[i][dk], wr[dk][j], acc[i][j]);
    }
  }

  if (EPI == 0 || EPI == 1) {
#pragma unroll
    for (int i = 0; i < 8; ++i) {
      int rg = row0 + ti * 8 + i;
      if (rg < N) {
        float4 a = make_float4(acc[i][0], acc[i][1], acc[i][2], acc[i][3]);
        float4 b = make_float4(acc[i][4], acc[i][5], acc[i][6], acc[i][7]);
        if (EPI == 1) {
          a.x = fmaxf(a.x, 0.f); a.y = fmaxf(a.y, 0.f);
          a.z = fmaxf(a.z, 0.f); a.w = fmaxf(a.w, 0.f);
          b.x = fmaxf(b.x, 0.f); b.y = fmaxf(b.y, 0.f);
          b.z = fmaxf(b.z, 0.f); b.w = fmaxf(b.w, 0.f);
        }
        *reinterpret_cast<float4*>(fout + (size_t)rg * ldo + c0) = a;
        *reinterpret_cast<float4*>(fout + (size_t)rg * ldo + c1) = b;
      }
    }
  } else if (EPI == 2) {
    float loc = 0.f;
#pragma unroll
    for (int i = 0; i < 8; ++i) {
      int rg = row0 + ti * 8 + i;
      if (rg < N) {
        ushort4 s0, s1;
        s0.x = f2bf(acc[i][0]); s0.y = f2bf(acc[i][1]);
        s0.z = f2bf(acc[i][2]); s0.w = f2bf(acc[i][3]);
        s1.x = f2bf(acc[i][4]); s1.y = f2bf(acc[i][5]);
        s1.z = f2bf(acc[i][6]); s1.w = f2bf(acc[i][7]);
        *reinterpret_cast<ushort4*>(bout + (size_t)rg * ldo + c0) = s0;
        *reinterpret_cast<ushort4*>(bout + (size_t)rg * ldo + c1) = s1;
#pragma unroll
        for (int j = 0; j < 8; ++j) loc += acc[i][j] * acc[i][j];
      }
    }
    if (ssq) {
      __syncthreads();
      Xs[tid] = loc;
      __syncthreads();
      if (tid < 128) Xs[tid] += Xs[tid + 128];
      __syncthreads();
      if (tid < 64) {
        float v = Xs[tid] + Xs[tid + 64];
#pragma unroll
        for (int m = 32; m > 0; m >>= 1) v += __shfl_down(v, m, 64);
        if (tid == 0) atomicAdd(ssq, v);
      }
    }
  } else {  // EPI == 3
    float g = 1.f / (1.f + expf(-*skipp));
    float g1 = 1.f - g;
#pragma unroll
    for (int i = 0; i < 8; ++i) {
      int rg = row0 + ti * 8 + i;
      if (rg < N) {
        float4 o0 = *reinterpret_cast<const float4*>(fout + (size_t)rg * ldo + c0);
        float4 o1 = *reinterpret_cast<const float4*>(fout + (size_t)rg * ldo + c1);
        float4 a, b;
        a.x = gelu_f(g * acc[i][0] + g1 * o0.x);
        a.y = gelu_f(g * acc[i][1] + g1 * o0.y);
        a.z = gelu_f(g * acc[i][2] + g1 * o0.z);
        a.w = gelu_f(g * acc[i][3] + g1 * o0.w);
        b.x = gelu_f(g * acc[i][4] + g1 * o1.x);
        b.y = gelu_f(g * acc[i][5] + g1 * o1.y);
        b.z = gelu_f(g * acc[i][6] + g1 * o1.z);
        b.w = gelu_f(g * acc[i][7] + g1 * o1.w);
        *reinterpret_cast<float4*>(fout + (size_t)rg * ldo + c0) = a;
        *reinterpret_cast<float4*>(fout + (size_t)rg * ldo + c1) = b;
      }
    }
  }
}

// ---------------- tiled GEMM v6 (64-row): for the 128-col dispatches ---------------
// Round-7 counters: all single-col-block gemms run 469 (NE) / 235 (NA) blocks =
// 1.8 / 0.9 blocks/CU -> occupancy-starved regardless of tile quality. 64-row
// blocks double the grid (938/469) and cut VGPR to ~100 (4 blocks/CU). Cost:
// 4x8 per-thread tile = 0.75 B/FLOP -> LDS caps VALU at 67% (acceptable vs <50%
// delivered at 1.8 blocks/CU).
template <int ACT, int EPI>
__global__ __launch_bounds__(256) void gemm64_k(
    const float* __restrict__ X, int ldx,
    const float* __restrict__ W, int ldw,
    const float* __restrict__ bias, int N,
    float* __restrict__ fout, unsigned short* __restrict__ bout, int ldo,
    const float* __restrict__ skipp, float* __restrict__ ssq) {
  __shared__ float Xs[64 * 32];
  __shared__ float Ws[32 * 128];
  const int tid = threadIdx.x;
  const int ti = tid >> 4;             // 0..15 -> rows ti*4..+3
  const int tj = tid & 15;             // cols {tj*4..+3} and {64+tj*4..+3}
  const int row0 = blockIdx.x * 64;
  const int cb = blockIdx.y * 128;
  const int c0 = cb + tj * 4;
  const int c1 = cb + 64 + tj * 4;

  float acc[4][8];
  {
    float bc[8] = {0.f, 0.f, 0.f, 0.f, 0.f, 0.f, 0.f, 0.f};
    if (bias) {
#pragma unroll
      for (int j = 0; j < 4; ++j) { bc[j] = bias[c0 + j]; bc[4 + j] = bias[c1 + j]; }
    }
#pragma unroll
    for (int i = 0; i < 4; ++i)
#pragma unroll
      for (int j = 0; j < 8; ++j) acc[i][j] = bc[j];
  }

  for (int ks = 0; ks < 128; ks += 32) {
    __syncthreads();
    // stage X: 64 rows x 32 k = 512 float4, 2 per thread
    for (int v = tid; v < 512; v += 256) {
      int kq = v & 7, r = v >> 3;
      int rg = row0 + r; if (rg >= N) rg = N - 1;
      float4 x4 = *reinterpret_cast<const float4*>(X + (size_t)rg * ldx + ks + kq * 4);
      if (ACT == 1) {
        x4.x = gelu_f(x4.x); x4.y = gelu_f(x4.y);
        x4.z = gelu_f(x4.z); x4.w = gelu_f(x4.w);
      }
      *reinterpret_cast<float4*>(&Xs[r * 32 + ((kq ^ ((r >> 3) & 7)) << 2)]) = x4;
    }
    // stage W: 32 k-rows x 128 cols = 1024 float4, 4 per thread
    for (int v = tid; v < 1024; v += 256) {
      int cq = v & 31, k = v >> 5;
      *reinterpret_cast<float4*>(&Ws[k * 128 + cq * 4]) =
          *reinterpret_cast<const float4*>(W + (size_t)(ks + k) * ldw + cb + cq * 4);
    }
    __syncthreads();
#pragma unroll
    for (int k = 0; k < 32; k += 4) {
      float xr[4][4];
#pragma unroll
      for (int i = 0; i < 4; ++i)
        *reinterpret_cast<float4*>(xr[i]) = *reinterpret_cast<const float4*>(
            &Xs[(ti * 4 + i) * 32 + ((((k >> 2)) ^ (ti >> 1)) << 2)]);
      float wr[4][8];
#pragma unroll
      for (int dk = 0; dk < 4; ++dk) {
        *reinterpret_cast<float4*>(&wr[dk][0]) =
            *reinterpret_cast<const float4*>(&Ws[(k + dk) * 128 + tj * 4]);
        *reinterpret_cast<float4*>(&wr[dk][4]) =
            *reinterpret_cast<const float4*>(&Ws[(k + dk) * 128 + 64 + tj * 4]);
      }
#pragma unroll
      for (int i = 0; i < 4; ++i)
#pragma unroll
        for (int dk = 0; dk < 4; ++dk)
#pragma unroll
          for (int j = 0; j < 8; ++j)
            acc[i][j] = fmaf(xr[i][dk], wr[dk][j], acc[i][j]);
    }
  }

  if (EPI == 0 || EPI == 1) {
#pragma unroll
    for (int i = 0; i < 4; ++i) {
      int rg = row0 + ti * 4 + i;
      if (rg < N) {
        float4 a = make_float4(acc[i][0], acc[i][1], acc[i][2], acc[i][3]);
        float4 b = make_float4(acc[i][4], acc[i][5], acc[i][6], acc[i][7]);
        if (EPI == 1) {
          a.x = fmaxf(a.x, 0.f); a.y = fmaxf(a.y, 0.f);
          a.z = fmaxf(a.z, 0.f); a.w = fmaxf(a.w, 0.f);
          b.x = fmaxf(b.x, 0.f); b.y = fmaxf(b.y, 0.f);
          b.z = fmaxf(b.z, 0.f); b.w = fmaxf(b.w, 0.f);
        }
        *reinterpret_cast<float4*>(fout + (size_t)rg * ldo + c0) = a;
        *reinterpret_cast<float4*>(fout + (size_t)rg * ldo + c1) = b;
      }
    }
  } else if (EPI == 2) {
    float loc = 0.f;
#pragma unroll
    for (int i = 0; i < 4; ++i) {
      int rg = row0 + ti * 4 + i;
      if (rg < N) {
        ushort4 s0, s1;
        s0.x = f2bf(acc[i][0]); s0.y = f2bf(acc[i][1]);
        s0.z = f2bf(acc[i][2]); s0.w = f2bf(acc[i][3]);
        s1.x = f2bf(acc[i][4]); s1.y = f2bf(acc[i][5]);
        s1.z = f2bf(acc[i][6]); s1.w = f2bf(acc[i][7]);
        *reinterpret_cast<ushort4*>(bout + (size_t)rg * ldo + c0) = s0;
        *reinterpret_cast<ushort4*>(bout + (size_t)rg * ldo + c1) = s1;
#pragma unroll
        for (int j = 0; j < 8; ++j) loc += acc[i][j] * acc[i][j];
      }
    }
    if (ssq) {
      __syncthreads();
      Xs[tid] = loc;
      __syncthreads();
      if (tid < 128) Xs[tid] += Xs[tid + 128];
      __syncthreads();
      if (tid < 64) {
        float v = Xs[tid] + Xs[tid + 64];
#pragma unroll
        for (int m = 32; m > 0; m >>= 1) v += __shfl_down(v, m, 64);
        if (tid == 0) atomicAdd(ssq, v);
      }
    }
  } else {  // EPI == 3
    float g = 1.f / (1.f + expf(-*skipp));
    float g1 = 1.f - g;
#pragma unroll
    for (int i = 0; i < 4; ++i) {
      int rg = row0 + ti * 4 + i;
      if (rg < N) {
        float4 o0 = *reinterpret_cast<const float4*>(fout + (size_t)rg * ldo + c0);
        float4 o1 = *reinterpret_cast<const float4*>(fout + (size_t)rg * ldo + c1);
        float4 a, b;
        a.x = gelu_f(g * acc[i][0] + g1 * o0.x);
        a.y = gelu_f(g * acc[i][1] + g1 * o0.y);
        a.z = gelu_f(g * acc[i][2] + g1 * o0.z);
        a.w = gelu_f(g * acc[i][3] + g1 * o0.w);
        b.x = gelu_f(g * acc[i][4] + g1 * o1.x);
        b.y = gelu_f(g * acc[i][5] + g1 * o1.y);
        b.z = gelu_f(g * acc[i][6] + g1 * o1.z);
        b.w = gelu_f(g * acc[i][7] + g1 * o1.w);
        *reinterpret_cast<float4*>(fout + (size_t)rg * ldo + c0) = a;
        *reinterpret_cast<float4*>(fout + (size_t)rg * ldo + c1) = b;
      }
    }
  }
}

// ---------------- CSR build ----------------
__global__ __launch_bounds__(256) void deg_k(const int* __restrict__ ei, int E,
                                             int* __restrict__ deg) {
  int i = blockIdx.x * 256 + threadIdx.x;
  if (i < E) atomicAdd(&deg[ei[E + i]], 1);
}

// exclusive scan over deg_cursor[0..n), writing rowptr[0..n] and exclusive back
// into deg_cursor (becomes the fill cursor). Single block, 1024 threads.
__global__ __launch_bounds__(1024) void scan_k(int* __restrict__ deg_cursor,
                                               int* __restrict__ rowptr, int n) {
  __shared__ int sd[1024];
  __shared__ int carry;
  int tid = threadIdx.x;
  if (tid == 0) carry = 0;
  __syncthreads();
  for (int base = 0; base < n; base += 1024) {
    int v = (base + tid < n) ? deg_cursor[base + tid] : 0;
    sd[tid] = v;
    __syncthreads();
    for (int off = 1; off < 1024; off <<= 1) {
      int t = (tid >= off) ? sd[tid - off] : 0;
      __syncthreads();
      sd[tid] += t;
      __syncthreads();
    }
    int c0 = carry;
    if (base + tid < n) {
      int excl = c0 + sd[tid] - v;
      rowptr[base + tid] = excl;
      deg_cursor[base + tid] = excl;
    }
    __syncthreads();
    if (tid == 0) carry = c0 + sd[1023];
    __syncthreads();
  }
  if (tid == 0) rowptr[n] = carry;
}

__global__ __launch_bounds__(256) void fill_k(const int* __restrict__ ei, int E,
                                              int* __restrict__ cursor,
                                              int* __restrict__ entries,
                                              int srcoff, int tag) {
  int i = blockIdx.x * 256 + threadIdx.x;
  if (i < E) {
    int pos = atomicAdd(&cursor[ei[E + i]], 1);
    entries[pos] = (ei[i] + srcoff) | (tag << 30);
  }
}

// ---------------- HGT gather: one 32-lane group per (dst, head), no atomics --------
__global__ __launch_bounds__(256) void hgt_gather_k(
    const float* __restrict__ q, const unsigned short* __restrict__ ktbl,
    const unsigned short* __restrict__ vtbl, const int* __restrict__ rowptr,
    const int* __restrict__ entries, const float* __restrict__ pbase, int nd,
    float* __restrict__ out) {
  int g = blockIdx.x * 8 + (threadIdx.x >> 5);
  int dst = g >> 2, h = g & 3, c = threadIdx.x & 31;
  if (dst >= nd) return;
  int col = h * 32 + c;
  float qv = q[(size_t)dst * 128 + col];
  int i0 = rowptr[dst], i1 = rowptr[dst + 1];
  float sum = 0.f, acc = 0.f;
  for (int i = i0; i < i1; ++i) {
    int e = entries[i];
    int lin = e & 0x3FFFFFFF;
    int tag = (unsigned)e >> 30;
    float part = qv * bf2f(ktbl[(size_t)lin * 128 + col]);
#pragma unroll
    for (int m = 16; m > 0; m >>= 1) part += __shfl_xor(part, m);
    float w = expf(part * SCALE * pbase[tag * 8 + h]);
    sum += w;
    acc = fmaf(w, bf2f(vtbl[(size_t)lin * 128 + col]), acc);
  }
  out[(size_t)dst * 128 + col] = acc / (sum + 1e-16f);
}

// ---------------- LayerNorm (row=128): out = LN(alpha*A + beta*B)*g + b -------------
template <typename AT, typename BT>
__global__ __launch_bounds__(128) void ln_k(const AT* __restrict__ A,
                                            const BT* __restrict__ B, float alpha,
                                            float beta, const float* __restrict__ g,
                                            const float* __restrict__ b,
                                            float* __restrict__ out, int relu) {
  int row = blockIdx.x;
  int t = threadIdx.x;
  float v = alpha * ldc(A + (size_t)row * 128 + t);
  if (B) v += beta * ldc(B + (size_t)row * 128 + t);
  float s1 = v, s2 = v * v;
#pragma unroll
  for (int m = 32; m > 0; m >>= 1) {
    s1 += __shfl_xor(s1, m, 64);
    s2 += __shfl_xor(s2, m, 64);
  }
  __shared__ float r1[2], r2[2];
  int w = t >> 6;
  if ((t & 63) == 0) { r1[w] = s1; r2[w] = s2; }
  __syncthreads();
  float S1 = r1[0] + r1[1], S2 = r2[0] + r2[1];
  float mu = S1 * (1.f / 128.f);
  float var = S2 * (1.f / 128.f) - mu * mu;
  float rr = rsqrtf(fmaxf(var, 0.f) + 1e-5f);
  float o = (v - mu) * rr * g[t] + b[t];
  if (relu) o = fmaxf(o, 0.f);
  out[(size_t)row * 128 + t] = o;
}

// ---------------- kvs partial: part[g][h][128][128] = sum_{n in chunk g} K V^T ------
__global__ __launch_bounds__(256) void kvsred_k(const unsigned short* __restrict__ Kb,
                                                const unsigned short* __restrict__ Vb,
                                                float* __restrict__ part,
                                                float* __restrict__ ksum, int chunk) {
  const int h = blockIdx.y;
  const int n0 = blockIdx.x * chunk;
  const int iters = chunk >> 3;          // 75
  __shared__ float ks[8][132];
  __shared__ float vs[8][132];
  const int tid = threadIdx.x;
  const int ti = tid >> 4, tj = tid & 15;

  const int sw = tid >> 7;               // 0 = K, 1 = V
  const int sni = (tid >> 4) & 7;        // row within 8-row tile
  const int sc = (tid & 15) << 3;        // col base (8 bf16 per thread)
  const unsigned short* src =
      (sw ? Vb : Kb) + (size_t)(n0 + sni) * 512 + h * 128 + sc;
  float* dstrow = (sw ? &vs[0][0] : &ks[0][0]) + sni * 132 + sc;

  float acc[8][8];
#pragma unroll
  for (int i = 0; i < 8; ++i)
#pragma unroll
    for (int j = 0; j < 8; ++j) acc[i][j] = 0.f;
  float ksloc = 0.f;

  uint4 r = *reinterpret_cast<const uint4*>(src);
  for (int it = 0; it < iters; ++it) {
    __syncthreads();
    float4 lo, hi;
    lo.x = bf2f((unsigned short)(r.x & 0xffffu)); lo.y = bf2f((unsigned short)(r.x >> 16));
    lo.z = bf2f((unsigned short)(r.y & 0xffffu)); lo.w = bf2f((unsigned short)(r.y >> 16));
    hi.x = bf2f((unsigned short)(r.z & 0xffffu)); hi.y = bf2f((unsigned short)(r.z >> 16));
    hi.z = bf2f((unsigned short)(r.w & 0xffffu)); hi.w = bf2f((unsigned short)(r.w >> 16));
    *reinterpret_cast<float4*>(dstrow) = lo;
    *reinterpret_cast<float4*>(dstrow + 4) = hi;
    if (it + 1 < iters)
      r = *reinterpret_cast<const uint4*>(src + (size_t)(it + 1) * 8 * 512);
    __syncthreads();
#pragma unroll
    for (int ni = 0; ni < 8; ++ni) {
      float kk[8], vv[8];
      *reinterpret_cast<float4*>(kk) =
          *reinterpret_cast<const float4*>(&ks[ni][ti * 4]);
      *reinterpret_cast<float4*>(kk + 4) =
          *reinterpret_cast<const float4*>(&ks[ni][64 + ti * 4]);
      *reinterpret_cast<float4*>(vv) =
          *reinterpret_cast<const float4*>(&vs[ni][tj * 4]);
      *reinterpret_cast<float4*>(vv + 4) =
          *reinterpret_cast<const float4*>(&vs[ni][64 + tj * 4]);
#pragma unroll
      for (int i = 0; i < 8; ++i)
#pragma unroll
        for (int j = 0; j < 8; ++j) acc[i][j] = fmaf(kk[i], vv[j], acc[i][j]);
      if (tid < 128) ksloc += ks[ni][tid];
    }
  }
  float* pb = part + (size_t)(blockIdx.x * 4 + h) * 16384;
#pragma unroll
  for (int i = 0; i < 8; ++i) {
    int m = ti * 4 + (i & 3) + ((i >> 2) << 6);
    *reinterpret_cast<float4*>(pb + m * 128 + tj * 4) =
        make_float4(acc[i][0], acc[i][1], acc[i][2], acc[i][3]);
    *reinterpret_cast<float4*>(pb + m * 128 + 64 + tj * 4) =
        make_float4(acc[i][4], acc[i][5], acc[i][6], acc[i][7]);
  }
  if (tid < 128) atomicAdd(&ksum[h * 128 + tid], ksloc);
}

// ---------------- kvs final reduce: kvs[c] = sum_g part[g][c] ----------------------
__global__ __launch_bounds__(256) void kvsfin_k(const float* __restrict__ part,
                                                float* __restrict__ kvs, int G) {
  int c = blockIdx.x * 256 + threadIdx.x;   // c = h*16384 + m*128 + d, 65536 total
  int hh = c >> 14, md = c & 16383;
  const float* p = part + (size_t)hh * 16384 + md;
  float s = 0.f;
#pragma unroll 4
  for (int g = 0; g < G; ++g) s += p[(size_t)g * 65536];
  kvs[c] = s;
}

// ---------------- SG attention apply v4: 64-row blocks, cross-head sum in regs ------
// v3's limiter was grid (469 blocks = 1.8/CU) + 215MB f32 RMW traffic. v4: 64-row
// blocks (938 = 3.7/CU); per-thread state shrinks to out[4][8]+acc[4][8] = 64 VGPR,
// small enough to keep the head sum in registers (v2 needed 128 and spilled the
// occupancy). No global RMW; single bf16 attnb store; round-5 ln path restored.
__global__ __launch_bounds__(256) void sgapply_k(const unsigned short* __restrict__ Qb,
                                                 const unsigned short* __restrict__ Vb,
                                                 const float* __restrict__ kvs,
                                                 const float* __restrict__ ksum,
                                                 const float* __restrict__ ssqq,
                                                 const float* __restrict__ ssqk,
                                                 unsigned short* __restrict__ attnb,
                                                 int N) {
  __shared__ float Xs[64 * 32];
  __shared__ float Ws[32 * 128];
  __shared__ float kss[32];
  __shared__ float fsh_s;
  const int tid = threadIdx.x;
  const int ti = tid >> 4;
  const int tj = tid & 15;
  const int row0 = blockIdx.x * 64;
  if (tid == 0) fsh_s = 1.0f / (sqrtf(*ssqq) * sqrtf(*ssqk));

  float out[4][8];
#pragma unroll
  for (int i = 0; i < 4; ++i)
#pragma unroll
    for (int j = 0; j < 8; ++j) out[i][j] = 0.f;

  for (int h = 0; h < 4; ++h) {
    float acc[4][8];
    float den[4];
#pragma unroll
    for (int i = 0; i < 4; ++i) {
      den[i] = 0.f;
#pragma unroll
      for (int j = 0; j < 8; ++j) acc[i][j] = 0.f;
    }
    for (int ks = 0; ks < 128; ks += 32) {
      __syncthreads();   // previous chunk/head compute done before overwrite
      for (int v = tid; v < 512; v += 256) {
        int kq = v & 7, r = v >> 3;
        int rg = row0 + r; if (rg >= N) rg = N - 1;
        ushort4 q4 = *reinterpret_cast<const ushort4*>(
            Qb + (size_t)rg * 512 + h * 128 + ks + kq * 4);
        float4 x4 = make_float4(bf2f(q4.x), bf2f(q4.y), bf2f(q4.z), bf2f(q4.w));
        *reinterpret_cast<float4*>(&Xs[r * 32 + ((kq ^ ((r >> 3) & 7)) << 2)]) = x4;
      }
      for (int v = tid; v < 1024; v += 256) {
        int cq = v & 31, k = v >> 5;
        *reinterpret_cast<float4*>(&Ws[k * 128 + cq * 4]) =
            *reinterpret_cast<const float4*>(kvs + (size_t)h * 16384 +
                                             (size_t)(ks + k) * 128 + cq * 4);
      }
      if (tid < 32) kss[tid] = ksum[h * 128 + ks + tid];
      __syncthreads();
#pragma unroll
      for (int k = 0; k < 32; k += 4) {
        float xr[4][4];
#pragma unroll
        for (int i = 0; i < 4; ++i)
          *reinterpret_cast<float4*>(xr[i]) = *reinterpret_cast<const float4*>(
              &Xs[(ti * 4 + i) * 32 + ((((k >> 2)) ^ (ti >> 1)) << 2)]);
        float wr[4][8];
        float kv[4];
#pragma unroll
        for (int dk = 0; dk < 4; ++dk) {
          *reinterpret_cast<float4*>(&wr[dk][0]) =
              *reinterpret_cast<const float4*>(&Ws[(k + dk) * 128 + tj * 4]);
          *reinterpret_cast<float4*>(&wr[dk][4]) =
              *reinterpret_cast<const float4*>(&Ws[(k + dk) * 128 + 64 + tj * 4]);
          kv[dk] = kss[k + dk];
        }
#pragma unroll
        for (int i = 0; i < 4; ++i)
#pragma unroll
          for (int dk = 0; dk < 4; ++dk) {
            den[i] = fmaf(xr[i][dk], kv[dk], den[i]);
#pragma unroll
            for (int j = 0; j < 8; ++j)
              acc[i][j] = fmaf(xr[i][dk], wr[dk][j], acc[i][j]);
          }
      }
    }
    // fold this head into the register accumulator
    float f = fsh_s;
#pragma unroll
    for (int i = 0; i < 4; ++i) {
      int rg = row0 + ti * 4 + i;
      if (rg < N) {
        ushort4 v0 = *reinterpret_cast<const ushort4*>(
            Vb + (size_t)rg * 512 + h * 128 + tj * 4);
        ushort4 v1 = *reinterpret_cast<const ushort4*>(
            Vb + (size_t)rg * 512 + h * 128 + 64 + tj * 4);
        float rd = 1.0f / (den[i] * f + 60000.0f);
        out[i][0] += (acc[i][0] * f + 60000.0f * bf2f(v0.x)) * rd;
        out[i][1] += (acc[i][1] * f + 60000.0f * bf2f(v0.y)) * rd;
        out[i][2] += (acc[i][2] * f + 60000.0f * bf2f(v0.z)) * rd;
        out[i][3] += (acc[i][3] * f + 60000.0f * bf2f(v0.w)) * rd;
        out[i][4] += (acc[i][4] * f + 60000.0f * bf2f(v1.x)) * rd;
        out[i][5] += (acc[i][5] * f + 60000.0f * bf2f(v1.y)) * rd;
        out[i][6] += (acc[i][6] * f + 60000.0f * bf2f(v1.z)) * rd;
        out[i][7] += (acc[i][7] * f + 60000.0f * bf2f(v1.w)) * rd;
      }
    }
  }
#pragma unroll
  for (int i = 0; i < 4; ++i) {
    int rg = row0 + ti * 4 + i;
    if (rg < N) {
      ushort4 s0, s1;
      s0.x = f2bf(0.25f * out[i][0]); s0.y = f2bf(0.25f * out[i][1]);
      s0.z = f2bf(0.25f * out[i][2]); s0.w = f2bf(0.25f * out[i][3]);
      s1.x = f2bf(0.25f * out[i][4]); s1.y = f2bf(0.25f * out[i][5]);
      s1.z = f2bf(0.25f * out[i][6]); s1.w = f2bf(0.25f * out[i][7]);
      *reinterpret_cast<ushort4*>(attnb + (size_t)rg * 128 + tj * 4) = s0;
      *reinterpret_cast<ushort4*>(attnb + (size_t)rg * 128 + 64 + tj * 4) = s1;
    }
  }
}

// ---------------- host ----------------
extern "C" void kernel_launch(void* const* d_in, const int* in_sizes, int n_in,
                              void* d_out, int out_size, void* d_ws, size_t ws_size,
                              hipStream_t stream) {
  const float* x_ent = (const float*)d_in[0];
  const float* x_att = (const float*)d_in[1];
  const float* Wkqv_e = (const float*)d_in[2];
  const float* bkqv_e = (const float*)d_in[3];
  const float* Wkqv_a = (const float*)d_in[4];
  const float* bkqv_a = (const float*)d_in[5];
  const float* Wout_e = (const float*)d_in[6];
  const float* bout_e = (const float*)d_in[7];
  const float* Wout_a = (const float*)d_in[8];
  const float* bout_a = (const float*)d_in[9];
  const float* skip_e = (const float*)d_in[10];
  const float* skip_a = (const float*)d_in[11];
  const float* a_rel = (const float*)d_in[12];
  const float* m_rel = (const float*)d_in[13];
  const float* p_rel = (const float*)d_in[14];
  const float* ln_ent_g = (const float*)d_in[15];
  const float* ln_ent_b = (const float*)d_in[16];
  const float* sg_fc_W = (const float*)d_in[17];
  const float* sg_fc_b = (const float*)d_in[18];
  const float* sg_ln0_g = (const float*)d_in[19];
  const float* sg_ln0_b = (const float*)d_in[20];
  const float* sg_Wq = (const float*)d_in[21];
  const float* sg_bq = (const float*)d_in[22];
  const float* sg_Wk = (const float*)d_in[23];
  const float* sg_bk = (const float*)d_in[24];
  const float* sg_Wv = (const float*)d_in[25];
  const float* sg_bv = (const float*)d_in[26];
  const float* sg_ln1_g = (const float*)d_in[27];
  const float* sg_ln1_b = (const float*)d_in[28];
  const float* proj_W1 = (const float*)d_in[29];
  const float* proj_b1 = (const float*)d_in[30];
  const float* proj_W2 = (const float*)d_in[31];
  const float* proj_b2 = (const float*)d_in[32];
  const int* ei_ee = (const int*)d_in[33];
  const int* ei_ea = (const int*)d_in[34];
  const int* ei_ae = (const int*)d_in[35];

  char* ws = (char*)d_ws;
  // ---- fixed region ----
  const size_t O_HE = 0;                         // h_e f32 (30.72M)
  const size_t O_HA = 30720000;                  // h_a f32 (15.36M) | SG: attnb bf16
  const size_t O_Z0 = 46080000;                  // z0 f32 (30.72M)
  const size_t O_WKT = 76800000;                 // 3*16384 f32
  const size_t O_WVT = 76996608;
  const size_t O_BKT = 77193216;
  const size_t O_BVT = 77194752;
  const size_t O_KVS = 77196288;                 // kvs(262144)+ksum(2048)+ssq(64)
  // ---- CSR region ----
  const size_t O_RPE = 77460544;                 // rowptr_e (60001) -> 240064
  const size_t O_RPA = O_RPE + 240064;           // rowptr_a (30001) -> 120064
  const size_t O_CUE = O_RPA + 120064;           // cursor/deg_e -> 240000
  const size_t O_CUA = O_CUE + 240000;           // cursor/deg_a -> 120000
  const size_t O_ENE = O_CUA + 120000;           // entries_e (225000) -> 900000
  const size_t O_ENA = O_ENE + 900000;           // entries_a (75000) -> 300000
  const size_t O_UN = O_ENA + 300000;            // union; 79,380,672
  // HGT view of union:
  float* q_e = (float*)(ws + O_UN);                                 // 30.72M (also out_e)
  float* q_a = (float*)(ws + O_UN + 30720000);                      // 15.36M (also out_a)
  unsigned short* ktbl = (unsigned short*)(ws + O_UN + 46080000);   // 150000x128 bf16
  unsigned short* vtbl = (unsigned short*)(ws + O_UN + 84480000);   // 150000x128 bf16
  // SG view of union:
  float* tmpf = (float*)(ws + O_UN);                                // fc out f32
  unsigned short* Vb = (unsigned short*)(ws + O_UN);                // NE*512 bf16
  unsigned short* KQb = (unsigned short*)(ws + O_UN + 61440000);    // K then Q
  unsigned short* attnb = (unsigned short*)(ws + O_HA);             // NE*128 bf16

  float* h_e = (float*)(ws + O_HE);
  float* h_a = (float*)(ws + O_HA);
  float* z0 = (float*)(ws + O_Z0);
  float* Wkt = (float*)(ws + O_WKT);
  float* Wvt = (float*)(ws + O_WVT);
  float* bkt = (float*)(ws + O_BKT);
  float* bvt = (float*)(ws + O_BVT);
  float* kvs = (float*)(ws + O_KVS);
  float* ksum = (float*)(ws + O_KVS + 262144);
  float* ssq_q = (float*)(ws + O_KVS + 262144 + 2048);
  float* ssq_k = ssq_q + 1;
  int* rowptr_e = (int*)(ws + O_RPE);
  int* rowptr_a = (int*)(ws + O_RPA);
  int* cursor_e = (int*)(ws + O_CUE);
  int* cursor_a = (int*)(ws + O_CUA);
  int* entries_e = (int*)(ws + O_ENE);
  int* entries_a = (int*)(ws + O_ENA);

  const int GB_E = (NE + 127) / 128;    // 469  (128-row grid, dim3(·,4) dispatches)
  const int G64_E = (NE + 63) / 64;     // 938  (64-row grid)
  const int G64_A = (NA + 63) / 64;     // 469

  hipMemcpyAsync(h_e, x_ent, (size_t)NE * 128 * 4, hipMemcpyDeviceToDevice, stream);
  hipMemcpyAsync(h_a, x_att, (size_t)NA * 128 * 4, hipMemcpyDeviceToDevice, stream);

  // ---- CSR build (graph identical across layers) ----
  hipMemsetAsync(ws + O_CUE, 0, 360000, stream);   // cursor_e + cursor_a
  deg_k<<<(E_EE + 255) / 256, 256, 0, stream>>>(ei_ee, E_EE, cursor_e);
  deg_k<<<(E_AE + 255) / 256, 256, 0, stream>>>(ei_ae, E_AE, cursor_e);
  deg_k<<<(E_EA + 255) / 256, 256, 0, stream>>>(ei_ea, E_EA, cursor_a);
  scan_k<<<1, 1024, 0, stream>>>(cursor_e, rowptr_e, NE);
  scan_k<<<1, 1024, 0, stream>>>(cursor_a, rowptr_a, NA);
  fill_k<<<(E_EE + 255) / 256, 256, 0, stream>>>(ei_ee, E_EE, cursor_e, entries_e, 0, 0);
  fill_k<<<(E_AE + 255) / 256, 256, 0, stream>>>(ei_ae, E_AE, cursor_e, entries_e, NE, 1);
  fill_k<<<(E_EA + 255) / 256, 256, 0, stream>>>(ei_ea, E_EA, cursor_a, entries_a, 0, 0);

  for (int l = 0; l < 2; ++l) {
    const float* Wke = Wkqv_e + (size_t)l * 49152;
    const float* Wka = Wkqv_a + (size_t)l * 49152;
    const float* bke = bkqv_e + (size_t)l * 384;
    const float* bka = bkqv_a + (size_t)l * 384;

    wrel_k<<<dim3(3, 2), 256, 0, stream>>>(Wke, Wka, bke, bka,
                                           a_rel + (size_t)l * 12288,
                                           m_rel + (size_t)l * 12288, Wkt, Wvt, bkt, bvt);
    // q projections (cols 128..255 of Wkqv)
    gemm64_k<0, 0><<<G64_E, 256, 0, stream>>>(h_e, 128, Wke + 128, 384, bke + 128, NE,
                                              q_e, nullptr, 128, nullptr, nullptr);
    gemm64_k<0, 0><<<G64_A, 256, 0, stream>>>(h_a, 128, Wka + 128, 384, bka + 128, NA,
                                              q_a, nullptr, 128, nullptr, nullptr);
    // kt/vt tables (bf16): rows [0,NE)=rel0(src e), [NE,NE+NA)=rel2(src a),
    //                      [90000,150000)=rel1(src e, dst a)
    gemm64_k<0, 2><<<G64_E, 256, 0, stream>>>(h_e, 128, Wkt, 128, bkt, NE,
                                              nullptr, ktbl, 128, nullptr, nullptr);
    gemm64_k<0, 2><<<G64_A, 256, 0, stream>>>(h_a, 128, Wkt + 2 * 16384, 128,
                                              bkt + 2 * 128, NA, nullptr,
                                              ktbl + (size_t)NE * 128, 128, nullptr, nullptr);
    gemm64_k<0, 2><<<G64_E, 256, 0, stream>>>(h_e, 128, Wkt + 1 * 16384, 128,
                                              bkt + 1 * 128, NE, nullptr,
                                              ktbl + (size_t)90000 * 128, 128, nullptr, nullptr);
    gemm64_k<0, 2><<<G64_E, 256, 0, stream>>>(h_e, 128, Wvt, 128, bvt, NE,
                                              nullptr, vtbl, 128, nullptr, nullptr);
    gemm64_k<0, 2><<<G64_A, 256, 0, stream>>>(h_a, 128, Wvt + 2 * 16384, 128,
                                              bvt + 2 * 128, NA, nullptr,
                                              vtbl + (size_t)NE * 128, 128, nullptr, nullptr);
    gemm64_k<0, 2><<<G64_E, 256, 0, stream>>>(h_e, 128, Wvt + 1 * 16384, 128,
                                              bvt + 1 * 128, NE, nullptr,
                                              vtbl + (size_t)90000 * 128, 128, nullptr, nullptr);
    // gather (writes message in-place over q buffers)
    hgt_gather_k<<<30000, 256, 0, stream>>>(q_e, ktbl, vtbl, rowptr_e, entries_e,
                                            p_rel + (size_t)l * 12, NE, q_e);
    hgt_gather_k<<<15000, 256, 0, stream>>>(q_a, ktbl + (size_t)90000 * 128,
                                            vtbl + (size_t)90000 * 128, rowptr_a,
                                            entries_a, p_rel + (size_t)l * 12 + 4, NA, q_a);
    // out proj (gelu on msg) + gated skip + inter-layer gelu, in-place on h
    gemm64_k<1, 3><<<G64_E, 256, 0, stream>>>(q_e, 128, Wout_e + (size_t)l * 16384, 128,
                                              bout_e + (size_t)l * 128, NE, h_e, nullptr,
                                              128, skip_e + l, nullptr);
    gemm64_k<1, 3><<<G64_A, 256, 0, stream>>>(q_a, 128, Wout_a + (size_t)l * 16384, 128,
                                              bout_a + (size_t)l * 128, NA, h_a, nullptr,
                                              128, skip_a + l, nullptr);
  }

  // -------- SGFormer --------
  gemm64_k<0, 0><<<G64_E, 256, 0, stream>>>(h_e, 128, sg_fc_W, 128, sg_fc_b, NE,
                                            tmpf, nullptr, 128, nullptr, nullptr);
  ln_k<float, float><<<NE, 128, 0, stream>>>(tmpf, nullptr, 1.f, 0.f, sg_ln0_g,
                                             sg_ln0_b, z0, 1);
  hipMemsetAsync(ws + O_KVS, 0, 264256, stream);
  gemm128_k<0, 2><<<dim3(GB_E, 4), 256, 0, stream>>>(z0, 128, sg_Wv, 512, sg_bv, NE,
                                                     nullptr, Vb, 512, nullptr, nullptr);
  gemm128_k<0, 2><<<dim3(GB_E, 4), 256, 0, stream>>>(z0, 128, sg_Wk, 512, sg_bk, NE,
                                                     nullptr, KQb, 512, nullptr, ssq_k);
  // partials into d_out (dead until proj2): 400 slabs x 64KB = 25.6MB <= 30.72MB
  kvsred_k<<<dim3(100, 4), 256, 0, stream>>>(KQb, Vb, (float*)d_out, ksum, 600);
  kvsfin_k<<<256, 256, 0, stream>>>((const float*)d_out, kvs, 100);
  gemm128_k<0, 2><<<dim3(GB_E, 4), 256, 0, stream>>>(z0, 128, sg_Wq, 512, sg_bq, NE,
                                                     nullptr, KQb, 512, nullptr, ssq_q);
  sgapply_k<<<G64_E, 256, 0, stream>>>(KQb, Vb, kvs, ksum, ssq_q, ssq_k, attnb, NE);
  ln_k<unsigned short, float><<<NE, 128, 0, stream>>>(attnb, z0, 0.5f, 0.5f, sg_ln1_g,
                                                      sg_ln1_b, z0, 0);
  ln_k<float, float><<<NE, 128, 0, stream>>>(h_e, z0, 0.9f, 0.1f, ln_ent_g, ln_ent_b,
                                             h_e, 0);
  gemm64_k<0, 1><<<G64_E, 256, 0, stream>>>(h_e, 128, proj_W1, 128, proj_b1, NE,
                                            z0, nullptr, 128, nullptr, nullptr);
  gemm64_k<0, 0><<<G64_E, 256, 0, stream>>>(z0, 128, proj_W2, 128, proj_b2, NE,
                                            (float*)d_out, nullptr, 128, nullptr, nullptr);
}

// Round 10
// 1981.123 us; speedup vs baseline: 1.0777x; 1.0222x over previous
//
#include <hip/hip_runtime.h>

// ---------------- constants ----------------
#define NE 60000
#define NA 30000
#define E_EE 150000
#define E_EA 75000
#define E_AE 75000
#define SCALE 0.17677669529663689f   // 1/sqrt(32)

typedef __attribute__((ext_vector_type(8))) short bf16x8;
typedef __attribute__((ext_vector_type(4))) float f32x4;

__device__ __forceinline__ float bf2f(unsigned short u) {
  return __uint_as_float(((unsigned)u) << 16);
}
__device__ __forceinline__ unsigned short f2bf(float f) {
  unsigned u = __float_as_uint(f);
  u = u + 0x7FFFu + ((u >> 16) & 1u);   // RNE
  return (unsigned short)(u >> 16);
}
__device__ __forceinline__ float ldc(const float* p) { return *p; }
__device__ __forceinline__ float ldc(const unsigned short* p) { return bf2f(*p); }
__device__ __forceinline__ float gelu_f(float x) {
  return 0.5f * x * (1.0f + erff(x * 0.7071067811865476f));
}

// ---------------- fused relation weights (all f32) ----------------
__global__ __launch_bounds__(256) void wrel_k(
    const float* __restrict__ Wk_e, const float* __restrict__ Wk_a,
    const float* __restrict__ bk_e, const float* __restrict__ bk_a,
    const float* __restrict__ a_rel, const float* __restrict__ m_rel,
    float* __restrict__ Wkt, float* __restrict__ Wvt,
    float* __restrict__ bkt, float* __restrict__ bvt) {
  int t = blockIdx.x;        // relation 0..2
  int part = blockIdx.y;     // 0: key (a_rel, cols 0..127), 1: value (m_rel, cols 256..)
  const float* W = (t < 2) ? Wk_e : Wk_a;
  const float* bb = (t < 2) ? bk_e : bk_a;
  const float* A = (part ? m_rel : a_rel) + t * 4096;
  int coff = part ? 256 : 0;
  float* Wo = (part ? Wvt : Wkt) + t * 16384;
  float* bo = (part ? bvt : bkt) + t * 128;
  __shared__ float As[4096];
  for (int u = threadIdx.x; u < 4096; u += 256) As[u] = A[u];
  __syncthreads();
  for (int u = threadIdx.x; u < 16384; u += 256) {
    int i = u >> 7, c = u & 127;
    int hh = c >> 5, e = c & 31;
    const float* wr = W + i * 384 + coff + hh * 32;
    const float* ar = As + hh * 1024 + e;
    float acc = 0.f;
#pragma unroll
    for (int d = 0; d < 32; ++d) acc = fmaf(wr[d], ar[d * 32], acc);
    Wo[u] = acc;
  }
  if (threadIdx.x < 128) {
    int c = threadIdx.x, hh = c >> 5, e = c & 31;
    const float* br = bb + coff + hh * 32;
    const float* ar = As + hh * 1024 + e;
    float acc = 0.f;
#pragma unroll
    for (int d = 0; d < 32; ++d) acc = fmaf(br[d], ar[d * 32], acc);
    bo[c] = acc;
  }
}

// ---------------- tiled GEMM (128-row): used where grid >= ~1800 blocks ------------
template <int ACT, int EPI>
__global__ __launch_bounds__(256) void gemm128_k(
    const float* __restrict__ X, int ldx,
    const float* __restrict__ W, int ldw,
    const float* __restrict__ bias, int N,
    float* __restrict__ fout, unsigned short* __restrict__ bout, int ldo,
    const float* __restrict__ skipp, float* __restrict__ ssq) {
  __shared__ float Xs[128 * 32];
  __shared__ float Ws[32 * 128];
  const int tid = threadIdx.x;
  const int ti = tid >> 4;             // 0..15 -> rows ti*8..+7
  const int tj = tid & 15;             // cols {tj*4..+3} and {64+tj*4..+3}
  const int row0 = blockIdx.x * 128;
  const int cb = blockIdx.y * 128;
  const int c0 = cb + tj * 4;
  const int c1 = cb + 64 + tj * 4;

  float acc[8][8];
  {
    float bc[8] = {0.f, 0.f, 0.f, 0.f, 0.f, 0.f, 0.f, 0.f};
    if (bias) {
#pragma unroll
      for (int j = 0; j < 4; ++j) { bc[j] = bias[c0 + j]; bc[4 + j] = bias[c1 + j]; }
    }
#pragma unroll
    for (int i = 0; i < 8; ++i)
#pragma unroll
      for (int j = 0; j < 8; ++j) acc[i][j] = bc[j];
  }

  for (int ks = 0; ks < 128; ks += 32) {
    __syncthreads();
    for (int v = tid; v < 1024; v += 256) {
      int kq = v & 7, r = v >> 3;
      int rg = row0 + r; if (rg >= N) rg = N - 1;
      float4 x4 = *reinterpret_cast<const float4*>(X + (size_t)rg * ldx + ks + kq * 4);
      if (ACT == 1) {
        x4.x = gelu_f(x4.x); x4.y = gelu_f(x4.y);
        x4.z = gelu_f(x4.z); x4.w = gelu_f(x4.w);
      }
      *reinterpret_cast<float4*>(&Xs[r * 32 + ((kq ^ ((r >> 3) & 7)) << 2)]) = x4;
    }
    for (int v = tid; v < 1024; v += 256) {
      int cq = v & 31, k = v >> 5;
      *reinterpret_cast<float4*>(&Ws[k * 128 + cq * 4]) =
          *reinterpret_cast<const float4*>(W + (size_t)(ks + k) * ldw + cb + cq * 4);
    }
    __syncthreads();
#pragma unroll
    for (int k = 0; k < 32; k += 4) {
      float xr[8][4];
#pragma unroll
      for (int i = 0; i < 8; ++i)
        *reinterpret_cast<float4*>(xr[i]) = *reinterpret_cast<const float4*>(
            &Xs[(ti * 8 + i) * 32 + ((((k >> 2)) ^ (ti & 7)) << 2)]);
      float wr[4][8];
#pragma unroll
      for (int dk = 0; dk < 4; ++dk) {
        *reinterpret_cast<float4*>(&wr[dk][0]) =
            *reinterpret_cast<const float4*>(&Ws[(k + dk) * 128 + tj * 4]);
        *reinterpret_cast<float4*>(&wr[dk][4]) =
            *reinterpret_cast<const float4*>(&Ws[(k + dk) * 128 + 64 + tj * 4]);
      }
#pragma unroll
      for (int i = 0; i < 8; ++i)
#pragma unroll
        for (int dk = 0; dk < 4; ++dk)
#pragma unroll
          for (int j = 0; j < 8; ++j)
            acc[i][j] = fmaf(xr[i][dk], wr[dk][j], acc[i][j]);
    }
  }

  if (EPI == 0 || EPI == 1) {
#pragma unroll
    for (int i = 0; i < 8; ++i) {
      int rg = row0 + ti * 8 + i;
      if (rg < N) {
        float4 a = make_float4(acc[i][0], acc[i][1], acc[i][2], acc[i][3]);
        float4 b = make_float4(acc[i][4], acc[i][5], acc[i][6], acc[i][7]);
        if (EPI == 1) {
          a.x = fmaxf(a.x, 0.f); a.y = fmaxf(a.y, 0.f);
          a.z = fmaxf(a.z, 0.f); a.w = fmaxf(a.w, 0.f);
          b.x = fmaxf(b.x, 0.f); b.y = fmaxf(b.y, 0.f);
          b.z = fmaxf(b.z, 0.f); b.w = fmaxf(b.w, 0.f);
        }
        *reinterpret_cast<float4*>(fout + (size_t)rg * ldo + c0) = a;
        *reinterpret_cast<float4*>(fout + (size_t)rg * ldo + c1) = b;
      }
    }
  } else if (EPI == 2) {
    float loc = 0.f;
#pragma unroll
    for (int i = 0; i < 8; ++i) {
      int rg = row0 + ti * 8 + i;
      if (rg < N) {
        ushort4 s0, s1;
        s0.x = f2bf(acc[i][0]); s0.y = f2bf(acc[i][1]);
        s0.z = f2bf(acc[i][2]); s0.w = f2bf(acc[i][3]);
        s1.x = f2bf(acc[i][4]); s1.y = f2bf(acc[i][5]);
        s1.z = f2bf(acc[i][6]); s1.w = f2bf(acc[i][7]);
        *reinterpret_cast<ushort4*>(bout + (size_t)rg * ldo + c0) = s0;
        *reinterpret_cast<ushort4*>(bout + (size_t)rg * ldo + c1) = s1;
#pragma unroll
        for (int j = 0; j < 8; ++j) loc += acc[i][j] * acc[i][j];
      }
    }
    if (ssq) {
      __syncthreads();
      Xs[tid] = loc;
      __syncthreads();
      if (tid < 128) Xs[tid] += Xs[tid + 128];
      __syncthreads();
      if (tid < 64) {
        float v = Xs[tid] + Xs[tid + 64];
#pragma unroll
        for (int m = 32; m > 0; m >>= 1) v += __shfl_down(v, m, 64);
        if (tid == 0) atomicAdd(ssq, v);
      }
    }
  } else {  // EPI == 3
    float g = 1.f / (1.f + expf(-*skipp));
    float g1 = 1.f - g;
#pragma unroll
    for (int i = 0; i < 8; ++i) {
      int rg = row0 + ti * 8 + i;
      if (rg < N) {
        float4 o0 = *reinterpret_cast<const float4*>(fout + (size_t)rg * ldo + c0);
        float4 o1 = *reinterpret_cast<const float4*>(fout + (size_t)rg * ldo + c1);
        float4 a, b;
        a.x = gelu_f(g * acc[i][0] + g1 * o0.x);
        a.y = gelu_f(g * acc[i][1] + g1 * o0.y);
        a.z = gelu_f(g * acc[i][2] + g1 * o0.z);
        a.w = gelu_f(g * acc[i][3] + g1 * o0.w);
        b.x = gelu_f(g * acc[i][4] + g1 * o1.x);
        b.y = gelu_f(g * acc[i][5] + g1 * o1.y);
        b.z = gelu_f(g * acc[i][6] + g1 * o1.z);
        b.w = gelu_f(g * acc[i][7] + g1 * o1.w);
        *reinterpret_cast<float4*>(fout + (size_t)rg * ldo + c0) = a;
        *reinterpret_cast<float4*>(fout + (size_t)rg * ldo + c1) = b;
      }
    }
  }
}

// ---------------- tiled GEMM v6 (64-row): for the 128-col dispatches ---------------
template <int ACT, int EPI>
__global__ __launch_bounds__(256) void gemm64_k(
    const float* __restrict__ X, int ldx,
    const float* __restrict__ W, int ldw,
    const float* __restrict__ bias, int N,
    float* __restrict__ fout, unsigned short* __restrict__ bout, int ldo,
    const float* __restrict__ skipp, float* __restrict__ ssq) {
  __shared__ float Xs[64 * 32];
  __shared__ float Ws[32 * 128];
  const int tid = threadIdx.x;
  const int ti = tid >> 4;             // 0..15 -> rows ti*4..+3
  const int tj = tid & 15;             // cols {tj*4..+3} and {64+tj*4..+3}
  const int row0 = blockIdx.x * 64;
  const int cb = blockIdx.y * 128;
  const int c0 = cb + tj * 4;
  const int c1 = cb + 64 + tj * 4;

  float acc[4][8];
  {
    float bc[8] = {0.f, 0.f, 0.f, 0.f, 0.f, 0.f, 0.f, 0.f};
    if (bias) {
#pragma unroll
      for (int j = 0; j < 4; ++j) { bc[j] = bias[c0 + j]; bc[4 + j] = bias[c1 + j]; }
    }
#pragma unroll
    for (int i = 0; i < 4; ++i)
#pragma unroll
      for (int j = 0; j < 8; ++j) acc[i][j] = bc[j];
  }

  for (int ks = 0; ks < 128; ks += 32) {
    __syncthreads();
    for (int v = tid; v < 512; v += 256) {
      int kq = v & 7, r = v >> 3;
      int rg = row0 + r; if (rg >= N) rg = N - 1;
      float4 x4 = *reinterpret_cast<const float4*>(X + (size_t)rg * ldx + ks + kq * 4);
      if (ACT == 1) {
        x4.x = gelu_f(x4.x); x4.y = gelu_f(x4.y);
        x4.z = gelu_f(x4.z); x4.w = gelu_f(x4.w);
      }
      *reinterpret_cast<float4*>(&Xs[r * 32 + ((kq ^ ((r >> 3) & 7)) << 2)]) = x4;
    }
    for (int v = tid; v < 1024; v += 256) {
      int cq = v & 31, k = v >> 5;
      *reinterpret_cast<float4*>(&Ws[k * 128 + cq * 4]) =
          *reinterpret_cast<const float4*>(W + (size_t)(ks + k) * ldw + cb + cq * 4);
    }
    __syncthreads();
#pragma unroll
    for (int k = 0; k < 32; k += 4) {
      float xr[4][4];
#pragma unroll
      for (int i = 0; i < 4; ++i)
        *reinterpret_cast<float4*>(xr[i]) = *reinterpret_cast<const float4*>(
            &Xs[(ti * 4 + i) * 32 + ((((k >> 2)) ^ (ti >> 1)) << 2)]);
      float wr[4][8];
#pragma unroll
      for (int dk = 0; dk < 4; ++dk) {
        *reinterpret_cast<float4*>(&wr[dk][0]) =
            *reinterpret_cast<const float4*>(&Ws[(k + dk) * 128 + tj * 4]);
        *reinterpret_cast<float4*>(&wr[dk][4]) =
            *reinterpret_cast<const float4*>(&Ws[(k + dk) * 128 + 64 + tj * 4]);
      }
#pragma unroll
      for (int i = 0; i < 4; ++i)
#pragma unroll
        for (int dk = 0; dk < 4; ++dk)
#pragma unroll
          for (int j = 0; j < 8; ++j)
            acc[i][j] = fmaf(xr[i][dk], wr[dk][j], acc[i][j]);
    }
  }

  if (EPI == 0 || EPI == 1) {
#pragma unroll
    for (int i = 0; i < 4; ++i) {
      int rg = row0 + ti * 4 + i;
      if (rg < N) {
        float4 a = make_float4(acc[i][0], acc[i][1], acc[i][2], acc[i][3]);
        float4 b = make_float4(acc[i][4], acc[i][5], acc[i][6], acc[i][7]);
        if (EPI == 1) {
          a.x = fmaxf(a.x, 0.f); a.y = fmaxf(a.y, 0.f);
          a.z = fmaxf(a.z, 0.f); a.w = fmaxf(a.w, 0.f);
          b.x = fmaxf(b.x, 0.f); b.y = fmaxf(b.y, 0.f);
          b.z = fmaxf(b.z, 0.f); b.w = fmaxf(b.w, 0.f);
        }
        *reinterpret_cast<float4*>(fout + (size_t)rg * ldo + c0) = a;
        *reinterpret_cast<float4*>(fout + (size_t)rg * ldo + c1) = b;
      }
    }
  } else if (EPI == 2) {
    float loc = 0.f;
#pragma unroll
    for (int i = 0; i < 4; ++i) {
      int rg = row0 + ti * 4 + i;
      if (rg < N) {
        ushort4 s0, s1;
        s0.x = f2bf(acc[i][0]); s0.y = f2bf(acc[i][1]);
        s0.z = f2bf(acc[i][2]); s0.w = f2bf(acc[i][3]);
        s1.x = f2bf(acc[i][4]); s1.y = f2bf(acc[i][5]);
        s1.z = f2bf(acc[i][6]); s1.w = f2bf(acc[i][7]);
        *reinterpret_cast<ushort4*>(bout + (size_t)rg * ldo + c0) = s0;
        *reinterpret_cast<ushort4*>(bout + (size_t)rg * ldo + c1) = s1;
#pragma unroll
        for (int j = 0; j < 8; ++j) loc += acc[i][j] * acc[i][j];
      }
    }
    if (ssq) {
      __syncthreads();
      Xs[tid] = loc;
      __syncthreads();
      if (tid < 128) Xs[tid] += Xs[tid + 128];
      __syncthreads();
      if (tid < 64) {
        float v = Xs[tid] + Xs[tid + 64];
#pragma unroll
        for (int m = 32; m > 0; m >>= 1) v += __shfl_down(v, m, 64);
        if (tid == 0) atomicAdd(ssq, v);
      }
    }
  } else {  // EPI == 3
    float g = 1.f / (1.f + expf(-*skipp));
    float g1 = 1.f - g;
#pragma unroll
    for (int i = 0; i < 4; ++i) {
      int rg = row0 + ti * 4 + i;
      if (rg < N) {
        float4 o0 = *reinterpret_cast<const float4*>(fout + (size_t)rg * ldo + c0);
        float4 o1 = *reinterpret_cast<const float4*>(fout + (size_t)rg * ldo + c1);
        float4 a, b;
        a.x = gelu_f(g * acc[i][0] + g1 * o0.x);
        a.y = gelu_f(g * acc[i][1] + g1 * o0.y);
        a.z = gelu_f(g * acc[i][2] + g1 * o0.z);
        a.w = gelu_f(g * acc[i][3] + g1 * o0.w);
        b.x = gelu_f(g * acc[i][4] + g1 * o1.x);
        b.y = gelu_f(g * acc[i][5] + g1 * o1.y);
        b.z = gelu_f(g * acc[i][6] + g1 * o1.z);
        b.w = gelu_f(g * acc[i][7] + g1 * o1.w);
        *reinterpret_cast<float4*>(fout + (size_t)rg * ldo + c0) = a;
        *reinterpret_cast<float4*>(fout + (size_t)rg * ldo + c1) = b;
      }
    }
  }
}

// ---------------- CSR build ----------------
__global__ __launch_bounds__(256) void deg_k(const int* __restrict__ ei, int E,
                                             int* __restrict__ deg) {
  int i = blockIdx.x * 256 + threadIdx.x;
  if (i < E) atomicAdd(&deg[ei[E + i]], 1);
}

// exclusive scan over deg_cursor[0..n), writing rowptr[0..n] and exclusive back
// into deg_cursor (becomes the fill cursor). Single block, 1024 threads.
__global__ __launch_bounds__(1024) void scan_k(int* __restrict__ deg_cursor,
                                               int* __restrict__ rowptr, int n) {
  __shared__ int sd[1024];
  __shared__ int carry;
  int tid = threadIdx.x;
  if (tid == 0) carry = 0;
  __syncthreads();
  for (int base = 0; base < n; base += 1024) {
    int v = (base + tid < n) ? deg_cursor[base + tid] : 0;
    sd[tid] = v;
    __syncthreads();
    for (int off = 1; off < 1024; off <<= 1) {
      int t = (tid >= off) ? sd[tid - off] : 0;
      __syncthreads();
      sd[tid] += t;
      __syncthreads();
    }
    int c0 = carry;
    if (base + tid < n) {
      int excl = c0 + sd[tid] - v;
      rowptr[base + tid] = excl;
      deg_cursor[base + tid] = excl;
    }
    __syncthreads();
    if (tid == 0) carry = c0 + sd[1023];
    __syncthreads();
  }
  if (tid == 0) rowptr[n] = carry;
}

__global__ __launch_bounds__(256) void fill_k(const int* __restrict__ ei, int E,
                                              int* __restrict__ cursor,
                                              int* __restrict__ entries,
                                              int srcoff, int tag) {
  int i = blockIdx.x * 256 + threadIdx.x;
  if (i < E) {
    int pos = atomicAdd(&cursor[ei[E + i]], 1);
    entries[pos] = (ei[i] + srcoff) | (tag << 30);
  }
}

// ---------------- HGT gather: one 32-lane group per (dst, head), no atomics --------
__global__ __launch_bounds__(256) void hgt_gather_k(
    const float* __restrict__ q, const unsigned short* __restrict__ ktbl,
    const unsigned short* __restrict__ vtbl, const int* __restrict__ rowptr,
    const int* __restrict__ entries, const float* __restrict__ pbase, int nd,
    float* __restrict__ out) {
  int g = blockIdx.x * 8 + (threadIdx.x >> 5);
  int dst = g >> 2, h = g & 3, c = threadIdx.x & 31;
  if (dst >= nd) return;
  int col = h * 32 + c;
  float qv = q[(size_t)dst * 128 + col];
  int i0 = rowptr[dst], i1 = rowptr[dst + 1];
  float sum = 0.f, acc = 0.f;
  for (int i = i0; i < i1; ++i) {
    int e = entries[i];
    int lin = e & 0x3FFFFFFF;
    int tag = (unsigned)e >> 30;
    float part = qv * bf2f(ktbl[(size_t)lin * 128 + col]);
#pragma unroll
    for (int m = 16; m > 0; m >>= 1) part += __shfl_xor(part, m);
    float w = expf(part * SCALE * pbase[tag * 8 + h]);
    sum += w;
    acc = fmaf(w, bf2f(vtbl[(size_t)lin * 128 + col]), acc);
  }
  out[(size_t)dst * 128 + col] = acc / (sum + 1e-16f);
}

// ---------------- LayerNorm (row=128): out = LN(alpha*A + beta*B)*g + b -------------
template <typename AT, typename BT>
__global__ __launch_bounds__(128) void ln_k(const AT* __restrict__ A,
                                            const BT* __restrict__ B, float alpha,
                                            float beta, const float* __restrict__ g,
                                            const float* __restrict__ b,
                                            float* __restrict__ out, int relu) {
  int row = blockIdx.x;
  int t = threadIdx.x;
  float v = alpha * ldc(A + (size_t)row * 128 + t);
  if (B) v += beta * ldc(B + (size_t)row * 128 + t);
  float s1 = v, s2 = v * v;
#pragma unroll
  for (int m = 32; m > 0; m >>= 1) {
    s1 += __shfl_xor(s1, m, 64);
    s2 += __shfl_xor(s2, m, 64);
  }
  __shared__ float r1[2], r2[2];
  int w = t >> 6;
  if ((t & 63) == 0) { r1[w] = s1; r2[w] = s2; }
  __syncthreads();
  float S1 = r1[0] + r1[1], S2 = r2[0] + r2[1];
  float mu = S1 * (1.f / 128.f);
  float var = S2 * (1.f / 128.f) - mu * mu;
  float rr = rsqrtf(fmaxf(var, 0.f) + 1e-5f);
  float o = (v - mu) * rr * g[t] + b[t];
  if (relu) o = fmaxf(o, 0.f);
  out[(size_t)row * 128 + t] = o;
}

// ---------------- kvs partial: part[g][h][128][128] = sum_{n in chunk g} K V^T ------
__global__ __launch_bounds__(256) void kvsred_k(const unsigned short* __restrict__ Kb,
                                                const unsigned short* __restrict__ Vb,
                                                float* __restrict__ part,
                                                float* __restrict__ ksum, int chunk) {
  const int h = blockIdx.y;
  const int n0 = blockIdx.x * chunk;
  const int iters = chunk >> 3;          // 75
  __shared__ float ks[8][132];
  __shared__ float vs[8][132];
  const int tid = threadIdx.x;
  const int ti = tid >> 4, tj = tid & 15;

  const int sw = tid >> 7;               // 0 = K, 1 = V
  const int sni = (tid >> 4) & 7;        // row within 8-row tile
  const int sc = (tid & 15) << 3;        // col base (8 bf16 per thread)
  const unsigned short* src =
      (sw ? Vb : Kb) + (size_t)(n0 + sni) * 512 + h * 128 + sc;
  float* dstrow = (sw ? &vs[0][0] : &ks[0][0]) + sni * 132 + sc;

  float acc[8][8];
#pragma unroll
  for (int i = 0; i < 8; ++i)
#pragma unroll
    for (int j = 0; j < 8; ++j) acc[i][j] = 0.f;
  float ksloc = 0.f;

  uint4 r = *reinterpret_cast<const uint4*>(src);
  for (int it = 0; it < iters; ++it) {
    __syncthreads();
    float4 lo, hi;
    lo.x = bf2f((unsigned short)(r.x & 0xffffu)); lo.y = bf2f((unsigned short)(r.x >> 16));
    lo.z = bf2f((unsigned short)(r.y & 0xffffu)); lo.w = bf2f((unsigned short)(r.y >> 16));
    hi.x = bf2f((unsigned short)(r.z & 0xffffu)); hi.y = bf2f((unsigned short)(r.z >> 16));
    hi.z = bf2f((unsigned short)(r.w & 0xffffu)); hi.w = bf2f((unsigned short)(r.w >> 16));
    *reinterpret_cast<float4*>(dstrow) = lo;
    *reinterpret_cast<float4*>(dstrow + 4) = hi;
    if (it + 1 < iters)
      r = *reinterpret_cast<const uint4*>(src + (size_t)(it + 1) * 8 * 512);
    __syncthreads();
#pragma unroll
    for (int ni = 0; ni < 8; ++ni) {
      float kk[8], vv[8];
      *reinterpret_cast<float4*>(kk) =
          *reinterpret_cast<const float4*>(&ks[ni][ti * 4]);
      *reinterpret_cast<float4*>(kk + 4) =
          *reinterpret_cast<const float4*>(&ks[ni][64 + ti * 4]);
      *reinterpret_cast<float4*>(vv) =
          *reinterpret_cast<const float4*>(&vs[ni][tj * 4]);
      *reinterpret_cast<float4*>(vv + 4) =
          *reinterpret_cast<const float4*>(&vs[ni][64 + tj * 4]);
#pragma unroll
      for (int i = 0; i < 8; ++i)
#pragma unroll
        for (int j = 0; j < 8; ++j) acc[i][j] = fmaf(kk[i], vv[j], acc[i][j]);
      if (tid < 128) ksloc += ks[ni][tid];
    }
  }
  float* pb = part + (size_t)(blockIdx.x * 4 + h) * 16384;
#pragma unroll
  for (int i = 0; i < 8; ++i) {
    int m = ti * 4 + (i & 3) + ((i >> 2) << 6);
    *reinterpret_cast<float4*>(pb + m * 128 + tj * 4) =
        make_float4(acc[i][0], acc[i][1], acc[i][2], acc[i][3]);
    *reinterpret_cast<float4*>(pb + m * 128 + 64 + tj * 4) =
        make_float4(acc[i][4], acc[i][5], acc[i][6], acc[i][7]);
  }
  if (tid < 128) atomicAdd(&ksum[h * 128 + tid], ksloc);
}

// ---------------- kvs final reduce: kvs[c]=sum_g part; also kvsT bf16 [h][d][k] -----
__global__ __launch_bounds__(256) void kvsfin_k(const float* __restrict__ part,
                                                float* __restrict__ kvs,
                                                unsigned short* __restrict__ kvsT,
                                                int G) {
  int c = blockIdx.x * 256 + threadIdx.x;   // c = h*16384 + m*128 + d (m = k index)
  int hh = c >> 14, md = c & 16383;
  int m = md >> 7, d = md & 127;
  const float* p = part + (size_t)hh * 16384 + md;
  float s = 0.f;
#pragma unroll 4
  for (int g = 0; g < G; ++g) s += p[(size_t)g * 65536];
  kvs[c] = s;
  kvsT[hh * 16384 + d * 128 + m] = f2bf(s);   // transposed bf16 for MFMA B-operand
}

// ---------------- SG attention apply v5b: MFMA (bf16), full 2048-slot B tile --------
// Round-9 failure root cause: Bs held only 1024 fragment slots (d-cols 0..63);
// consumer indexed up to slot 2047 -> OOB LDS reads for d>=64 (absmax 1.4 on those
// columns). Fix: Bs = 2048 slots (32KB), staging covers all 128 d-cols.
// Per head h: C[64n x 128d] = Q_h[64 x 128k] (A-frags direct from global) x
// kvsT[h][d][k] (B-frags pre-packed in LDS, lane-consecutive slots).
// mfma_f32_16x16x32_bf16: A lane l = A[row l&15][k-slot (l>>4)*8+j]; B lane l =
// B[k-slot (l>>4)*8+j][col l&15]; C/D lane l reg r = C[(l>>4)*4+r][l&15] (m89).
// (Any within-fragment k-permutation applied identically to A and B cancels.)
__global__ __launch_bounds__(256) void sgapply_k(const unsigned short* __restrict__ Qb,
                                                 const unsigned short* __restrict__ Vb,
                                                 const unsigned short* __restrict__ kvsT,
                                                 const float* __restrict__ ksum,
                                                 const float* __restrict__ ssqq,
                                                 const float* __restrict__ ssqk,
                                                 unsigned short* __restrict__ attnb,
                                                 int N) {
  __shared__ short Bs[16384];       // 2048 fragment slots x 8 bf16 = 32KB
  __shared__ float den_s[64];
  __shared__ float fsh_s;
  const int tid = threadIdx.x;
  const int lane = tid & 63;
  const int w = tid >> 6;           // wave 0..3 -> rows w*16..+15
  const int n0 = blockIdx.x * 64;
  if (tid == 0) fsh_s = 1.0f / (sqrtf(*ssqq) * sqrtf(*ssqk));

  float out[8][4];
#pragma unroll
  for (int dt = 0; dt < 8; ++dt)
#pragma unroll
    for (int r = 0; r < 4; ++r) out[dt][r] = 0.f;

  // A-row for this lane (fixed across heads): row = n0 + w*16 + (lane&15)
  int arow = n0 + w * 16 + (lane & 15);
  if (arow >= N) arow = N - 1;
  const int kofs = (lane >> 4) * 8;   // k offset within 32-slab

  for (int h = 0; h < 4; ++h) {
    __syncthreads();   // previous head's compute done; also fsh_s visible (h=0)
    // stage B-fragments: slot s = (dt*4 + kslab)*64 + l holds B[k][d] for
    // d = dt*16 + (l&15), k = kslab*32 + (l>>4)*8 .. +7. 2048 slots = all 128 d.
    for (int s = tid; s < 2048; s += 256) {
      int l = s & 63, dtks = s >> 6;        // dtks 0..31: dt = dtks>>2, kslab = dtks&3
      int d = (dtks >> 2) * 16 + (l & 15);
      int kk = (dtks & 3) * 32 + (l >> 4) * 8;
      *reinterpret_cast<bf16x8*>(&Bs[s * 8]) =
          *reinterpret_cast<const bf16x8*>(kvsT + h * 16384 + d * 128 + kk);
    }
    // den for the block's 64 rows: 4 threads per row, 32 k each
    {
      int r = tid >> 2, seg = tid & 3;
      int rg = n0 + r; if (rg >= N) rg = N - 1;
      const unsigned short* qp = Qb + (size_t)rg * 512 + h * 128 + seg * 32;
      const float* kp = ksum + h * 128 + seg * 32;
      float p = 0.f;
#pragma unroll
      for (int u = 0; u < 32; u += 8) {
        bf16x8 q8 = *reinterpret_cast<const bf16x8*>(qp + u);
#pragma unroll
        for (int j = 0; j < 8; ++j)
          p = fmaf(bf2f((unsigned short)q8[j]), kp[u + j], p);
      }
      p += __shfl_xor(p, 1);
      p += __shfl_xor(p, 2);
      if (seg == 0) den_s[r] = p * fsh_s + 60000.0f;
    }
    __syncthreads();
    // A-fragments for this head (4 k-slabs), direct from global
    bf16x8 afr[4];
    {
      const unsigned short* qrow = Qb + (size_t)arow * 512 + h * 128 + kofs;
#pragma unroll
      for (int ks = 0; ks < 4; ++ks)
        afr[ks] = *reinterpret_cast<const bf16x8*>(qrow + ks * 32);
    }
    float f = fsh_s;
#pragma unroll
    for (int dt = 0; dt < 8; ++dt) {
      f32x4 acc = {0.f, 0.f, 0.f, 0.f};
#pragma unroll
      for (int ks = 0; ks < 4; ++ks) {
        bf16x8 b = *reinterpret_cast<const bf16x8*>(&Bs[((dt * 4 + ks) * 64 + lane) * 8]);
        acc = __builtin_amdgcn_mfma_f32_16x16x32_bf16(afr[ks], b, acc, 0, 0, 0);
      }
      int dcol = dt * 16 + (lane & 15);
#pragma unroll
      for (int r = 0; r < 4; ++r) {
        int rl = w * 16 + (lane >> 4) * 4 + r;
        int rg = n0 + rl;
        if (rg < N) {
          float v = bf2f(Vb[(size_t)rg * 512 + h * 128 + dcol]);
          float rd = 1.0f / den_s[rl];
          out[dt][r] += (acc[r] * f + 60000.0f * v) * rd;
        }
      }
    }
  }
  // store bf16 attn (mean over 4 heads)
#pragma unroll
  for (int dt = 0; dt < 8; ++dt) {
    int dcol = dt * 16 + (lane & 15);
#pragma unroll
    for (int r = 0; r < 4; ++r) {
      int rg = n0 + w * 16 + (lane >> 4) * 4 + r;
      if (rg < N) attnb[(size_t)rg * 128 + dcol] = f2bf(0.25f * out[dt][r]);
    }
  }
}

// ---------------- host ----------------
extern "C" void kernel_launch(void* const* d_in, const int* in_sizes, int n_in,
                              void* d_out, int out_size, void* d_ws, size_t ws_size,
                              hipStream_t stream) {
  const float* x_ent = (const float*)d_in[0];
  const float* x_att = (const float*)d_in[1];
  const float* Wkqv_e = (const float*)d_in[2];
  const float* bkqv_e = (const float*)d_in[3];
  const float* Wkqv_a = (const float*)d_in[4];
  const float* bkqv_a = (const float*)d_in[5];
  const float* Wout_e = (const float*)d_in[6];
  const float* bout_e = (const float*)d_in[7];
  const float* Wout_a = (const float*)d_in[8];
  const float* bout_a = (const float*)d_in[9];
  const float* skip_e = (const float*)d_in[10];
  const float* skip_a = (const float*)d_in[11];
  const float* a_rel = (const float*)d_in[12];
  const float* m_rel = (const float*)d_in[13];
  const float* p_rel = (const float*)d_in[14];
  const float* ln_ent_g = (const float*)d_in[15];
  const float* ln_ent_b = (const float*)d_in[16];
  const float* sg_fc_W = (const float*)d_in[17];
  const float* sg_fc_b = (const float*)d_in[18];
  const float* sg_ln0_g = (const float*)d_in[19];
  const float* sg_ln0_b = (const float*)d_in[20];
  const float* sg_Wq = (const float*)d_in[21];
  const float* sg_bq = (const float*)d_in[22];
  const float* sg_Wk = (const float*)d_in[23];
  const float* sg_bk = (const float*)d_in[24];
  const float* sg_Wv = (const float*)d_in[25];
  const float* sg_bv = (const float*)d_in[26];
  const float* sg_ln1_g = (const float*)d_in[27];
  const float* sg_ln1_b = (const float*)d_in[28];
  const float* proj_W1 = (const float*)d_in[29];
  const float* proj_b1 = (const float*)d_in[30];
  const float* proj_W2 = (const float*)d_in[31];
  const float* proj_b2 = (const float*)d_in[32];
  const int* ei_ee = (const int*)d_in[33];
  const int* ei_ea = (const int*)d_in[34];
  const int* ei_ae = (const int*)d_in[35];

  char* ws = (char*)d_ws;
  // ---- fixed region ----
  const size_t O_HE = 0;                         // h_e f32 (30.72M)
  const size_t O_HA = 30720000;                  // h_a f32 (15.36M) | SG: attnb bf16
  const size_t O_Z0 = 46080000;                  // z0 f32 (30.72M)
  const size_t O_WKT = 76800000;                 // 3*16384 f32
  const size_t O_WVT = 76996608;
  const size_t O_BKT = 77193216;
  const size_t O_BVT = 77194752;
  const size_t O_KVS = 77196288;                 // kvs(262144)+ksum(2048)+ssq(64)
  // ---- CSR region ----
  const size_t O_RPE = 77460544;                 // rowptr_e (60001) -> 240064
  const size_t O_RPA = O_RPE + 240064;           // rowptr_a (30001) -> 120064
  const size_t O_CUE = O_RPA + 120064;           // cursor/deg_e -> 240000
  const size_t O_CUA = O_CUE + 240000;           // cursor/deg_a -> 120000
  const size_t O_ENE = O_CUA + 120000;           // entries_e (225000) -> 900000
  const size_t O_ENA = O_ENE + 900000;           // entries_a (75000) -> 300000
  const size_t O_UN = O_ENA + 300000;            // union; 79,380,672
  // HGT view of union:
  float* q_e = (float*)(ws + O_UN);                                 // 30.72M (also out_e)
  float* q_a = (float*)(ws + O_UN + 30720000);                      // 15.36M (also out_a)
  unsigned short* ktbl = (unsigned short*)(ws + O_UN + 46080000);   // 150000x128 bf16
  unsigned short* vtbl = (unsigned short*)(ws + O_UN + 84480000);   // 150000x128 bf16
  // SG view of union:
  float* tmpf = (float*)(ws + O_UN);                                // fc out f32
  unsigned short* Vb = (unsigned short*)(ws + O_UN);                // NE*512 bf16
  unsigned short* KQb = (unsigned short*)(ws + O_UN + 61440000);    // K then Q
  unsigned short* attnb = (unsigned short*)(ws + O_HA);             // NE*128 bf16

  float* h_e = (float*)(ws + O_HE);
  float* h_a = (float*)(ws + O_HA);
  float* z0 = (float*)(ws + O_Z0);
  float* Wkt = (float*)(ws + O_WKT);
  float* Wvt = (float*)(ws + O_WVT);
  float* bkt = (float*)(ws + O_BKT);
  float* bvt = (float*)(ws + O_BVT);
  float* kvs = (float*)(ws + O_KVS);
  float* ksum = (float*)(ws + O_KVS + 262144);
  float* ssq_q = (float*)(ws + O_KVS + 262144 + 2048);
  float* ssq_k = ssq_q + 1;
  int* rowptr_e = (int*)(ws + O_RPE);
  int* rowptr_a = (int*)(ws + O_RPA);
  int* cursor_e = (int*)(ws + O_CUE);
  int* cursor_a = (int*)(ws + O_CUA);
  int* entries_e = (int*)(ws + O_ENE);
  int* entries_a = (int*)(ws + O_ENA);

  const int GB_E = (NE + 127) / 128;    // 469  (128-row grid, dim3(·,4) dispatches)
  const int G64_E = (NE + 63) / 64;     // 938  (64-row grid)
  const int G64_A = (NA + 63) / 64;     // 469

  hipMemcpyAsync(h_e, x_ent, (size_t)NE * 128 * 4, hipMemcpyDeviceToDevice, stream);
  hipMemcpyAsync(h_a, x_att, (size_t)NA * 128 * 4, hipMemcpyDeviceToDevice, stream);

  // ---- CSR build (graph identical across layers) ----
  hipMemsetAsync(ws + O_CUE, 0, 360000, stream);   // cursor_e + cursor_a
  deg_k<<<(E_EE + 255) / 256, 256, 0, stream>>>(ei_ee, E_EE, cursor_e);
  deg_k<<<(E_AE + 255) / 256, 256, 0, stream>>>(ei_ae, E_AE, cursor_e);
  deg_k<<<(E_EA + 255) / 256, 256, 0, stream>>>(ei_ea, E_EA, cursor_a);
  scan_k<<<1, 1024, 0, stream>>>(cursor_e, rowptr_e, NE);
  scan_k<<<1, 1024, 0, stream>>>(cursor_a, rowptr_a, NA);
  fill_k<<<(E_EE + 255) / 256, 256, 0, stream>>>(ei_ee, E_EE, cursor_e, entries_e, 0, 0);
  fill_k<<<(E_AE + 255) / 256, 256, 0, stream>>>(ei_ae, E_AE, cursor_e, entries_e, NE, 1);
  fill_k<<<(E_EA + 255) / 256, 256, 0, stream>>>(ei_ea, E_EA, cursor_a, entries_a, 0, 0);

  for (int l = 0; l < 2; ++l) {
    const float* Wke = Wkqv_e + (size_t)l * 49152;
    const float* Wka = Wkqv_a + (size_t)l * 49152;
    const float* bke = bkqv_e + (size_t)l * 384;
    const float* bka = bkqv_a + (size_t)l * 384;

    wrel_k<<<dim3(3, 2), 256, 0, stream>>>(Wke, Wka, bke, bka,
                                           a_rel + (size_t)l * 12288,
                                           m_rel + (size_t)l * 12288, Wkt, Wvt, bkt, bvt);
    // q projections (cols 128..255 of Wkqv)
    gemm64_k<0, 0><<<G64_E, 256, 0, stream>>>(h_e, 128, Wke + 128, 384, bke + 128, NE,
                                              q_e, nullptr, 128, nullptr, nullptr);
    gemm64_k<0, 0><<<G64_A, 256, 0, stream>>>(h_a, 128, Wka + 128, 384, bka + 128, NA,
                                              q_a, nullptr, 128, nullptr, nullptr);
    // kt/vt tables (bf16): rows [0,NE)=rel0(src e), [NE,NE+NA)=rel2(src a),
    //                      [90000,150000)=rel1(src e, dst a)
    gemm64_k<0, 2><<<G64_E, 256, 0, stream>>>(h_e, 128, Wkt, 128, bkt, NE,
                                              nullptr, ktbl, 128, nullptr, nullptr);
    gemm64_k<0, 2><<<G64_A, 256, 0, stream>>>(h_a, 128, Wkt + 2 * 16384, 128,
                                              bkt + 2 * 128, NA, nullptr,
                                              ktbl + (size_t)NE * 128, 128, nullptr, nullptr);
    gemm64_k<0, 2><<<G64_E, 256, 0, stream>>>(h_e, 128, Wkt + 1 * 16384, 128,
                                              bkt + 1 * 128, NE, nullptr,
                                              ktbl + (size_t)90000 * 128, 128, nullptr, nullptr);
    gemm64_k<0, 2><<<G64_E, 256, 0, stream>>>(h_e, 128, Wvt, 128, bvt, NE,
                                              nullptr, vtbl, 128, nullptr, nullptr);
    gemm64_k<0, 2><<<G64_A, 256, 0, stream>>>(h_a, 128, Wvt + 2 * 16384, 128,
                                              bvt + 2 * 128, NA, nullptr,
                                              vtbl + (size_t)NE * 128, 128, nullptr, nullptr);
    gemm64_k<0, 2><<<G64_E, 256, 0, stream>>>(h_e, 128, Wvt + 1 * 16384, 128,
                                              bvt + 1 * 128, NE, nullptr,
                                              vtbl + (size_t)90000 * 128, 128, nullptr, nullptr);
    // gather (writes message in-place over q buffers)
    hgt_gather_k<<<30000, 256, 0, stream>>>(q_e, ktbl, vtbl, rowptr_e, entries_e,
                                            p_rel + (size_t)l * 12, NE, q_e);
    hgt_gather_k<<<15000, 256, 0, stream>>>(q_a, ktbl + (size_t)90000 * 128,
                                            vtbl + (size_t)90000 * 128, rowptr_a,
                                            entries_a, p_rel + (size_t)l * 12 + 4, NA, q_a);
    // out proj (gelu on msg) + gated skip + inter-layer gelu, in-place on h
    gemm64_k<1, 3><<<G64_E, 256, 0, stream>>>(q_e, 128, Wout_e + (size_t)l * 16384, 128,
                                              bout_e + (size_t)l * 128, NE, h_e, nullptr,
                                              128, skip_e + l, nullptr);
    gemm64_k<1, 3><<<G64_A, 256, 0, stream>>>(q_a, 128, Wout_a + (size_t)l * 16384, 128,
                                              bout_a + (size_t)l * 128, NA, h_a, nullptr,
                                              128, skip_a + l, nullptr);
  }

  // -------- SGFormer --------
  gemm64_k<0, 0><<<G64_E, 256, 0, stream>>>(h_e, 128, sg_fc_W, 128, sg_fc_b, NE,
                                            tmpf, nullptr, 128, nullptr, nullptr);
  ln_k<float, float><<<NE, 128, 0, stream>>>(tmpf, nullptr, 1.f, 0.f, sg_ln0_g,
                                             sg_ln0_b, z0, 1);
  hipMemsetAsync(ws + O_KVS, 0, 264256, stream);
  gemm128_k<0, 2><<<dim3(GB_E, 4), 256, 0, stream>>>(z0, 128, sg_Wv, 512, sg_bv, NE,
                                                     nullptr, Vb, 512, nullptr, nullptr);
  gemm128_k<0, 2><<<dim3(GB_E, 4), 256, 0, stream>>>(z0, 128, sg_Wk, 512, sg_bk, NE,
                                                     nullptr, KQb, 512, nullptr, ssq_k);
  // partials into d_out (dead until proj2): 400 slabs x 64KB = 25.6MB; kvsT bf16
  // (128KB) right after at +26,214,400 (out_size 30.72MB has room)
  unsigned short* kvsT = (unsigned short*)((char*)d_out + 26214400);
  kvsred_k<<<dim3(100, 4), 256, 0, stream>>>(KQb, Vb, (float*)d_out, ksum, 600);
  kvsfin_k<<<256, 256, 0, stream>>>((const float*)d_out, kvs, kvsT, 100);
  gemm128_k<0, 2><<<dim3(GB_E, 4), 256, 0, stream>>>(z0, 128, sg_Wq, 512, sg_bq, NE,
                                                     nullptr, KQb, 512, nullptr, ssq_q);
  sgapply_k<<<G64_E, 256, 0, stream>>>(KQb, Vb, kvsT, ksum, ssq_q, ssq_k, attnb, NE);
  ln_k<unsigned short, float><<<NE, 128, 0, stream>>>(attnb, z0, 0.5f, 0.5f, sg_ln1_g,
                                                      sg_ln1_b, z0, 0);
  ln_k<float, float><<<NE, 128, 0, stream>>>(h_e, z0, 0.9f, 0.1f, ln_ent_g, ln_ent_b,
                                             h_e, 0);
  gemm64_k<0, 1><<<G64_E, 256, 0, stream>>>(h_e, 128, proj_W1, 128, proj_b1, NE,
                                            z0, nullptr, 128, nullptr, nullptr);
  gemm64_k<0, 0><<<G64_E, 256, 0, stream>>>(z0, 128, proj_W2, 128, proj_b2, NE,
                                            (float*)d_out, nullptr, 128, nullptr, nullptr);
}

// Round 11
// 1824.828 us; speedup vs baseline: 1.1700x; 1.0856x over previous
//
#include <hip/hip_runtime.h>

// ---------------- constants ----------------
#define NE 60000
#define NA 30000
#define E_EE 150000
#define E_EA 75000
#define E_AE 75000
#define SCALE 0.17677669529663689f   // 1/sqrt(32)

typedef __attribute__((ext_vector_type(8))) short bf16x8;
typedef __attribute__((ext_vector_type(4))) float f32x4;

__device__ __forceinline__ float bf2f(unsigned short u) {
  return __uint_as_float(((unsigned)u) << 16);
}
__device__ __forceinline__ unsigned short f2bf(float f) {
  unsigned u = __float_as_uint(f);
  u = u + 0x7FFFu + ((u >> 16) & 1u);   // RNE
  return (unsigned short)(u >> 16);
}
__device__ __forceinline__ float ldc(const float* p) { return *p; }
__device__ __forceinline__ float ldc(const unsigned short* p) { return bf2f(*p); }
__device__ __forceinline__ float gelu_f(float x) {
  return 0.5f * x * (1.0f + erff(x * 0.7071067811865476f));
}

// ---------------- fused relation weights (all f32) ----------------
__global__ __launch_bounds__(256) void wrel_k(
    const float* __restrict__ Wk_e, const float* __restrict__ Wk_a,
    const float* __restrict__ bk_e, const float* __restrict__ bk_a,
    const float* __restrict__ a_rel, const float* __restrict__ m_rel,
    float* __restrict__ Wkt, float* __restrict__ Wvt,
    float* __restrict__ bkt, float* __restrict__ bvt) {
  int t = blockIdx.x;        // relation 0..2
  int part = blockIdx.y;     // 0: key (a_rel, cols 0..127), 1: value (m_rel, cols 256..)
  const float* W = (t < 2) ? Wk_e : Wk_a;
  const float* bb = (t < 2) ? bk_e : bk_a;
  const float* A = (part ? m_rel : a_rel) + t * 4096;
  int coff = part ? 256 : 0;
  float* Wo = (part ? Wvt : Wkt) + t * 16384;
  float* bo = (part ? bvt : bkt) + t * 128;
  __shared__ float As[4096];
  for (int u = threadIdx.x; u < 4096; u += 256) As[u] = A[u];
  __syncthreads();
  for (int u = threadIdx.x; u < 16384; u += 256) {
    int i = u >> 7, c = u & 127;
    int hh = c >> 5, e = c & 31;
    const float* wr = W + i * 384 + coff + hh * 32;
    const float* ar = As + hh * 1024 + e;
    float acc = 0.f;
#pragma unroll
    for (int d = 0; d < 32; ++d) acc = fmaf(wr[d], ar[d * 32], acc);
    Wo[u] = acc;
  }
  if (threadIdx.x < 128) {
    int c = threadIdx.x, hh = c >> 5, e = c & 31;
    const float* br = bb + coff + hh * 32;
    const float* ar = As + hh * 1024 + e;
    float acc = 0.f;
#pragma unroll
    for (int d = 0; d < 32; ++d) acc = fmaf(br[d], ar[d * 32], acc);
    bo[c] = acc;
  }
}

// ---------------- tiled GEMM (128-row), fp32 ----------------
template <int ACT, int EPI>
__global__ __launch_bounds__(256) void gemm128_k(
    const float* __restrict__ X, int ldx,
    const float* __restrict__ W, int ldw,
    const float* __restrict__ bias, int N,
    float* __restrict__ fout, unsigned short* __restrict__ bout, int ldo,
    const float* __restrict__ skipp, float* __restrict__ ssq) {
  __shared__ float Xs[128 * 32];
  __shared__ float Ws[32 * 128];
  const int tid = threadIdx.x;
  const int ti = tid >> 4;             // 0..15 -> rows ti*8..+7
  const int tj = tid & 15;             // cols {tj*4..+3} and {64+tj*4..+3}
  const int row0 = blockIdx.x * 128;
  const int cb = blockIdx.y * 128;
  const int c0 = cb + tj * 4;
  const int c1 = cb + 64 + tj * 4;

  float acc[8][8];
  {
    float bc[8] = {0.f, 0.f, 0.f, 0.f, 0.f, 0.f, 0.f, 0.f};
    if (bias) {
#pragma unroll
      for (int j = 0; j < 4; ++j) { bc[j] = bias[c0 + j]; bc[4 + j] = bias[c1 + j]; }
    }
#pragma unroll
    for (int i = 0; i < 8; ++i)
#pragma unroll
      for (int j = 0; j < 8; ++j) acc[i][j] = bc[j];
  }

  for (int ks = 0; ks < 128; ks += 32) {
    __syncthreads();
    for (int v = tid; v < 1024; v += 256) {
      int kq = v & 7, r = v >> 3;
      int rg = row0 + r; if (rg >= N) rg = N - 1;
      float4 x4 = *reinterpret_cast<const float4*>(X + (size_t)rg * ldx + ks + kq * 4);
      if (ACT == 1) {
        x4.x = gelu_f(x4.x); x4.y = gelu_f(x4.y);
        x4.z = gelu_f(x4.z); x4.w = gelu_f(x4.w);
      }
      *reinterpret_cast<float4*>(&Xs[r * 32 + ((kq ^ ((r >> 3) & 7)) << 2)]) = x4;
    }
    for (int v = tid; v < 1024; v += 256) {
      int cq = v & 31, k = v >> 5;
      *reinterpret_cast<float4*>(&Ws[k * 128 + cq * 4]) =
          *reinterpret_cast<const float4*>(W + (size_t)(ks + k) * ldw + cb + cq * 4);
    }
    __syncthreads();
#pragma unroll
    for (int k = 0; k < 32; k += 4) {
      float xr[8][4];
#pragma unroll
      for (int i = 0; i < 8; ++i)
        *reinterpret_cast<float4*>(xr[i]) = *reinterpret_cast<const float4*>(
            &Xs[(ti * 8 + i) * 32 + ((((k >> 2)) ^ (ti & 7)) << 2)]);
      float wr[4][8];
#pragma unroll
      for (int dk = 0; dk < 4; ++dk) {
        *reinterpret_cast<float4*>(&wr[dk][0]) =
            *reinterpret_cast<const float4*>(&Ws[(k + dk) * 128 + tj * 4]);
        *reinterpret_cast<float4*>(&wr[dk][4]) =
            *reinterpret_cast<const float4*>(&Ws[(k + dk) * 128 + 64 + tj * 4]);
      }
#pragma unroll
      for (int i = 0; i < 8; ++i)
#pragma unroll
        for (int dk = 0; dk < 4; ++dk)
#pragma unroll
          for (int j = 0; j < 8; ++j)
            acc[i][j] = fmaf(xr[i][dk], wr[dk][j], acc[i][j]);
    }
  }

  if (EPI == 0 || EPI == 1) {
#pragma unroll
    for (int i = 0; i < 8; ++i) {
      int rg = row0 + ti * 8 + i;
      if (rg < N) {
        float4 a = make_float4(acc[i][0], acc[i][1], acc[i][2], acc[i][3]);
        float4 b = make_float4(acc[i][4], acc[i][5], acc[i][6], acc[i][7]);
        if (EPI == 1) {
          a.x = fmaxf(a.x, 0.f); a.y = fmaxf(a.y, 0.f);
          a.z = fmaxf(a.z, 0.f); a.w = fmaxf(a.w, 0.f);
          b.x = fmaxf(b.x, 0.f); b.y = fmaxf(b.y, 0.f);
          b.z = fmaxf(b.z, 0.f); b.w = fmaxf(b.w, 0.f);
        }
        *reinterpret_cast<float4*>(fout + (size_t)rg * ldo + c0) = a;
        *reinterpret_cast<float4*>(fout + (size_t)rg * ldo + c1) = b;
      }
    }
  } else if (EPI == 2) {
    float loc = 0.f;
#pragma unroll
    for (int i = 0; i < 8; ++i) {
      int rg = row0 + ti * 8 + i;
      if (rg < N) {
        ushort4 s0, s1;
        s0.x = f2bf(acc[i][0]); s0.y = f2bf(acc[i][1]);
        s0.z = f2bf(acc[i][2]); s0.w = f2bf(acc[i][3]);
        s1.x = f2bf(acc[i][4]); s1.y = f2bf(acc[i][5]);
        s1.z = f2bf(acc[i][6]); s1.w = f2bf(acc[i][7]);
        *reinterpret_cast<ushort4*>(bout + (size_t)rg * ldo + c0) = s0;
        *reinterpret_cast<ushort4*>(bout + (size_t)rg * ldo + c1) = s1;
#pragma unroll
        for (int j = 0; j < 8; ++j) loc += acc[i][j] * acc[i][j];
      }
    }
    if (ssq) {
      __syncthreads();
      Xs[tid] = loc;
      __syncthreads();
      if (tid < 128) Xs[tid] += Xs[tid + 128];
      __syncthreads();
      if (tid < 64) {
        float v = Xs[tid] + Xs[tid + 64];
#pragma unroll
        for (int m = 32; m > 0; m >>= 1) v += __shfl_down(v, m, 64);
        if (tid == 0) atomicAdd(ssq, v);
      }
    }
  } else {  // EPI == 3
    float g = 1.f / (1.f + expf(-*skipp));
    float g1 = 1.f - g;
#pragma unroll
    for (int i = 0; i < 8; ++i) {
      int rg = row0 + ti * 8 + i;
      if (rg < N) {
        float4 o0 = *reinterpret_cast<const float4*>(fout + (size_t)rg * ldo + c0);
        float4 o1 = *reinterpret_cast<const float4*>(fout + (size_t)rg * ldo + c1);
        float4 a, b;
        a.x = gelu_f(g * acc[i][0] + g1 * o0.x);
        a.y = gelu_f(g * acc[i][1] + g1 * o0.y);
        a.z = gelu_f(g * acc[i][2] + g1 * o0.z);
        a.w = gelu_f(g * acc[i][3] + g1 * o0.w);
        b.x = gelu_f(g * acc[i][4] + g1 * o1.x);
        b.y = gelu_f(g * acc[i][5] + g1 * o1.y);
        b.z = gelu_f(g * acc[i][6] + g1 * o1.z);
        b.w = gelu_f(g * acc[i][7] + g1 * o1.w);
        *reinterpret_cast<float4*>(fout + (size_t)rg * ldo + c0) = a;
        *reinterpret_cast<float4*>(fout + (size_t)rg * ldo + c1) = b;
      }
    }
  }
}

// ---------------- tiled GEMM v6 (64-row), fp32 ----------------
template <int ACT, int EPI>
__global__ __launch_bounds__(256) void gemm64_k(
    const float* __restrict__ X, int ldx,
    const float* __restrict__ W, int ldw,
    const float* __restrict__ bias, int N,
    float* __restrict__ fout, unsigned short* __restrict__ bout, int ldo,
    const float* __restrict__ skipp, float* __restrict__ ssq) {
  __shared__ float Xs[64 * 32];
  __shared__ float Ws[32 * 128];
  const int tid = threadIdx.x;
  const int ti = tid >> 4;             // 0..15 -> rows ti*4..+3
  const int tj = tid & 15;             // cols {tj*4..+3} and {64+tj*4..+3}
  const int row0 = blockIdx.x * 64;
  const int cb = blockIdx.y * 128;
  const int c0 = cb + tj * 4;
  const int c1 = cb + 64 + tj * 4;

  float acc[4][8];
  {
    float bc[8] = {0.f, 0.f, 0.f, 0.f, 0.f, 0.f, 0.f, 0.f};
    if (bias) {
#pragma unroll
      for (int j = 0; j < 4; ++j) { bc[j] = bias[c0 + j]; bc[4 + j] = bias[c1 + j]; }
    }
#pragma unroll
    for (int i = 0; i < 4; ++i)
#pragma unroll
      for (int j = 0; j < 8; ++j) acc[i][j] = bc[j];
  }

  for (int ks = 0; ks < 128; ks += 32) {
    __syncthreads();
    for (int v = tid; v < 512; v += 256) {
      int kq = v & 7, r = v >> 3;
      int rg = row0 + r; if (rg >= N) rg = N - 1;
      float4 x4 = *reinterpret_cast<const float4*>(X + (size_t)rg * ldx + ks + kq * 4);
      if (ACT == 1) {
        x4.x = gelu_f(x4.x); x4.y = gelu_f(x4.y);
        x4.z = gelu_f(x4.z); x4.w = gelu_f(x4.w);
      }
      *reinterpret_cast<float4*>(&Xs[r * 32 + ((kq ^ ((r >> 3) & 7)) << 2)]) = x4;
    }
    for (int v = tid; v < 1024; v += 256) {
      int cq = v & 31, k = v >> 5;
      *reinterpret_cast<float4*>(&Ws[k * 128 + cq * 4]) =
          *reinterpret_cast<const float4*>(W + (size_t)(ks + k) * ldw + cb + cq * 4);
    }
    __syncthreads();
#pragma unroll
    for (int k = 0; k < 32; k += 4) {
      float xr[4][4];
#pragma unroll
      for (int i = 0; i < 4; ++i)
        *reinterpret_cast<float4*>(xr[i]) = *reinterpret_cast<const float4*>(
            &Xs[(ti * 4 + i) * 32 + ((((k >> 2)) ^ (ti >> 1)) << 2)]);
      float wr[4][8];
#pragma unroll
      for (int dk = 0; dk < 4; ++dk) {
        *reinterpret_cast<float4*>(&wr[dk][0]) =
            *reinterpret_cast<const float4*>(&Ws[(k + dk) * 128 + tj * 4]);
        *reinterpret_cast<float4*>(&wr[dk][4]) =
            *reinterpret_cast<const float4*>(&Ws[(k + dk) * 128 + 64 + tj * 4]);
      }
#pragma unroll
      for (int i = 0; i < 4; ++i)
#pragma unroll
        for (int dk = 0; dk < 4; ++dk)
#pragma unroll
          for (int j = 0; j < 8; ++j)
            acc[i][j] = fmaf(xr[i][dk], wr[dk][j], acc[i][j]);
    }
  }

  if (EPI == 0 || EPI == 1) {
#pragma unroll
    for (int i = 0; i < 4; ++i) {
      int rg = row0 + ti * 4 + i;
      if (rg < N) {
        float4 a = make_float4(acc[i][0], acc[i][1], acc[i][2], acc[i][3]);
        float4 b = make_float4(acc[i][4], acc[i][5], acc[i][6], acc[i][7]);
        if (EPI == 1) {
          a.x = fmaxf(a.x, 0.f); a.y = fmaxf(a.y, 0.f);
          a.z = fmaxf(a.z, 0.f); a.w = fmaxf(a.w, 0.f);
          b.x = fmaxf(b.x, 0.f); b.y = fmaxf(b.y, 0.f);
          b.z = fmaxf(b.z, 0.f); b.w = fmaxf(b.w, 0.f);
        }
        *reinterpret_cast<float4*>(fout + (size_t)rg * ldo + c0) = a;
        *reinterpret_cast<float4*>(fout + (size_t)rg * ldo + c1) = b;
      }
    }
  } else if (EPI == 2) {
    float loc = 0.f;
#pragma unroll
    for (int i = 0; i < 4; ++i) {
      int rg = row0 + ti * 4 + i;
      if (rg < N) {
        ushort4 s0, s1;
        s0.x = f2bf(acc[i][0]); s0.y = f2bf(acc[i][1]);
        s0.z = f2bf(acc[i][2]); s0.w = f2bf(acc[i][3]);
        s1.x = f2bf(acc[i][4]); s1.y = f2bf(acc[i][5]);
        s1.z = f2bf(acc[i][6]); s1.w = f2bf(acc[i][7]);
        *reinterpret_cast<ushort4*>(bout + (size_t)rg * ldo + c0) = s0;
        *reinterpret_cast<ushort4*>(bout + (size_t)rg * ldo + c1) = s1;
#pragma unroll
        for (int j = 0; j < 8; ++j) loc += acc[i][j] * acc[i][j];
      }
    }
    if (ssq) {
      __syncthreads();
      Xs[tid] = loc;
      __syncthreads();
      if (tid < 128) Xs[tid] += Xs[tid + 128];
      __syncthreads();
      if (tid < 64) {
        float v = Xs[tid] + Xs[tid + 64];
#pragma unroll
        for (int m = 32; m > 0; m >>= 1) v += __shfl_down(v, m, 64);
        if (tid == 0) atomicAdd(ssq, v);
      }
    }
  } else {  // EPI == 3
    float g = 1.f / (1.f + expf(-*skipp));
    float g1 = 1.f - g;
#pragma unroll
    for (int i = 0; i < 4; ++i) {
      int rg = row0 + ti * 4 + i;
      if (rg < N) {
        float4 o0 = *reinterpret_cast<const float4*>(fout + (size_t)rg * ldo + c0);
        float4 o1 = *reinterpret_cast<const float4*>(fout + (size_t)rg * ldo + c1);
        float4 a, b;
        a.x = gelu_f(g * acc[i][0] + g1 * o0.x);
        a.y = gelu_f(g * acc[i][1] + g1 * o0.y);
        a.z = gelu_f(g * acc[i][2] + g1 * o0.z);
        a.w = gelu_f(g * acc[i][3] + g1 * o0.w);
        b.x = gelu_f(g * acc[i][4] + g1 * o1.x);
        b.y = gelu_f(g * acc[i][5] + g1 * o1.y);
        b.z = gelu_f(g * acc[i][6] + g1 * o1.z);
        b.w = gelu_f(g * acc[i][7] + g1 * o1.w);
        *reinterpret_cast<float4*>(fout + (size_t)rg * ldo + c0) = a;
        *reinterpret_cast<float4*>(fout + (size_t)rg * ldo + c1) = b;
      }
    }
  }
}

// ---------------- MFMA GEMM (bf16 inputs): 64-row x 128-col block, 4 waves ----------
// Same fragment scheme as sgapply v5b (validated r10): A-frags direct from global
// (f32 -> bf16 in-register), W staged f32 -> bf16 into 2048 LDS fragment slots.
// Stage W: slot s=(dt*4+ks)*64+l holds W[k=(ks*32+(l>>4)*8+j)][c=cb+dt*16+(l&15)];
// 16-lane groups read 64B-contiguous W segments per j (coalesced; W slice L2-hot).
// EPI: 0 f32 store; 2 bf16 store (+ atomic ssq if ssq != null).
template <int EPI>
__global__ __launch_bounds__(256) void gemmMF_k(
    const float* __restrict__ X, int ldx,
    const float* __restrict__ W, int ldw,
    const float* __restrict__ bias, int N,
    float* __restrict__ fout, unsigned short* __restrict__ bout, int ldo,
    float* __restrict__ ssq) {
  __shared__ short Bs[16384];       // 2048 fragment slots x 8 bf16 = 32KB
  const int tid = threadIdx.x;
  const int lane = tid & 63;
  const int w = tid >> 6;           // wave 0..3 -> rows w*16..+15
  const int n0 = blockIdx.x * 64;
  const int cb = blockIdx.y * 128;

  // stage W fragments
  for (int s = tid; s < 2048; s += 256) {
    int l = s & 63, dtks = s >> 6;          // dt = dtks>>2, ks = dtks&3
    int c = cb + (dtks >> 2) * 16 + (l & 15);
    int kk = (dtks & 3) * 32 + (l >> 4) * 8;
    bf16x8 b;
#pragma unroll
    for (int j = 0; j < 8; ++j)
      b[j] = (short)f2bf(W[(size_t)(kk + j) * ldw + c]);
    *reinterpret_cast<bf16x8*>(&Bs[s * 8]) = b;
  }

  // A fragments: row = n0 + w*16 + (lane&15), k-offset (lane>>4)*8, 4 k-slabs
  int arow = n0 + w * 16 + (lane & 15);
  if (arow >= N) arow = N - 1;
  const int kofs = (lane >> 4) * 8;
  bf16x8 afr[4];
#pragma unroll
  for (int ks = 0; ks < 4; ++ks) {
    const float* xp = X + (size_t)arow * ldx + ks * 32 + kofs;
    float4 a0 = *reinterpret_cast<const float4*>(xp);
    float4 a1 = *reinterpret_cast<const float4*>(xp + 4);
    bf16x8 a;
    a[0] = (short)f2bf(a0.x); a[1] = (short)f2bf(a0.y);
    a[2] = (short)f2bf(a0.z); a[3] = (short)f2bf(a0.w);
    a[4] = (short)f2bf(a1.x); a[5] = (short)f2bf(a1.y);
    a[6] = (short)f2bf(a1.z); a[7] = (short)f2bf(a1.w);
    afr[ks] = a;
  }
  __syncthreads();

  float loc = 0.f;
#pragma unroll
  for (int dt = 0; dt < 8; ++dt) {
    f32x4 acc = {0.f, 0.f, 0.f, 0.f};
#pragma unroll
    for (int ks = 0; ks < 4; ++ks) {
      bf16x8 b = *reinterpret_cast<const bf16x8*>(&Bs[((dt * 4 + ks) * 64 + lane) * 8]);
      acc = __builtin_amdgcn_mfma_f32_16x16x32_bf16(afr[ks], b, acc, 0, 0, 0);
    }
    int dcol = dt * 16 + (lane & 15);
    float bv = bias ? bias[cb + dcol] : 0.f;
#pragma unroll
    for (int r = 0; r < 4; ++r) {
      int rg = n0 + w * 16 + (lane >> 4) * 4 + r;
      if (rg < N) {
        float val = acc[r] + bv;
        if (EPI == 0) {
          fout[(size_t)rg * ldo + cb + dcol] = val;
        } else {
          bout[(size_t)rg * ldo + cb + dcol] = f2bf(val);
          loc += val * val;
        }
      }
    }
  }
  if (EPI == 2 && ssq) {
    __syncthreads();                 // all waves done reading Bs
    float* red = (float*)Bs;
    red[tid] = loc;
    __syncthreads();
    if (tid < 128) red[tid] += red[tid + 128];
    __syncthreads();
    if (tid < 64) {
      float v = red[tid] + red[tid + 64];
#pragma unroll
      for (int m = 32; m > 0; m >>= 1) v += __shfl_down(v, m, 64);
      if (tid == 0) atomicAdd(ssq, v);
    }
  }
}

// ---------------- CSR build ----------------
__global__ __launch_bounds__(256) void deg_k(const int* __restrict__ ei, int E,
                                             int* __restrict__ deg) {
  int i = blockIdx.x * 256 + threadIdx.x;
  if (i < E) atomicAdd(&deg[ei[E + i]], 1);
}

// exclusive scan over deg_cursor[0..n), writing rowptr[0..n] and exclusive back
// into deg_cursor (becomes the fill cursor). Single block, 1024 threads.
__global__ __launch_bounds__(1024) void scan_k(int* __restrict__ deg_cursor,
                                               int* __restrict__ rowptr, int n) {
  __shared__ int sd[1024];
  __shared__ int carry;
  int tid = threadIdx.x;
  if (tid == 0) carry = 0;
  __syncthreads();
  for (int base = 0; base < n; base += 1024) {
    int v = (base + tid < n) ? deg_cursor[base + tid] : 0;
    sd[tid] = v;
    __syncthreads();
    for (int off = 1; off < 1024; off <<= 1) {
      int t = (tid >= off) ? sd[tid - off] : 0;
      __syncthreads();
      sd[tid] += t;
      __syncthreads();
    }
    int c0 = carry;
    if (base + tid < n) {
      int excl = c0 + sd[tid] - v;
      rowptr[base + tid] = excl;
      deg_cursor[base + tid] = excl;
    }
    __syncthreads();
    if (tid == 0) carry = c0 + sd[1023];
    __syncthreads();
  }
  if (tid == 0) rowptr[n] = carry;
}

__global__ __launch_bounds__(256) void fill_k(const int* __restrict__ ei, int E,
                                              int* __restrict__ cursor,
                                              int* __restrict__ entries,
                                              int srcoff, int tag) {
  int i = blockIdx.x * 256 + threadIdx.x;
  if (i < E) {
    int pos = atomicAdd(&cursor[ei[E + i]], 1);
    entries[pos] = (ei[i] + srcoff) | (tag << 30);
  }
}

// ---------------- HGT gather: one 32-lane group per (dst, head), no atomics --------
__global__ __launch_bounds__(256) void hgt_gather_k(
    const float* __restrict__ q, const unsigned short* __restrict__ ktbl,
    const unsigned short* __restrict__ vtbl, const int* __restrict__ rowptr,
    const int* __restrict__ entries, const float* __restrict__ pbase, int nd,
    float* __restrict__ out) {
  int g = blockIdx.x * 8 + (threadIdx.x >> 5);
  int dst = g >> 2, h = g & 3, c = threadIdx.x & 31;
  if (dst >= nd) return;
  int col = h * 32 + c;
  float qv = q[(size_t)dst * 128 + col];
  int i0 = rowptr[dst], i1 = rowptr[dst + 1];
  float sum = 0.f, acc = 0.f;
  for (int i = i0; i < i1; ++i) {
    int e = entries[i];
    int lin = e & 0x3FFFFFFF;
    int tag = (unsigned)e >> 30;
    float part = qv * bf2f(ktbl[(size_t)lin * 128 + col]);
#pragma unroll
    for (int m = 16; m > 0; m >>= 1) part += __shfl_xor(part, m);
    float w = expf(part * SCALE * pbase[tag * 8 + h]);
    sum += w;
    acc = fmaf(w, bf2f(vtbl[(size_t)lin * 128 + col]), acc);
  }
  out[(size_t)dst * 128 + col] = acc / (sum + 1e-16f);
}

// ---------------- LayerNorm (row=128): out = LN(alpha*A + beta*B)*g + b -------------
template <typename AT, typename BT>
__global__ __launch_bounds__(128) void ln_k(const AT* __restrict__ A,
                                            const BT* __restrict__ B, float alpha,
                                            float beta, const float* __restrict__ g,
                                            const float* __restrict__ b,
                                            float* __restrict__ out, int relu) {
  int row = blockIdx.x;
  int t = threadIdx.x;
  float v = alpha * ldc(A + (size_t)row * 128 + t);
  if (B) v += beta * ldc(B + (size_t)row * 128 + t);
  float s1 = v, s2 = v * v;
#pragma unroll
  for (int m = 32; m > 0; m >>= 1) {
    s1 += __shfl_xor(s1, m, 64);
    s2 += __shfl_xor(s2, m, 64);
  }
  __shared__ float r1[2], r2[2];
  int w = t >> 6;
  if ((t & 63) == 0) { r1[w] = s1; r2[w] = s2; }
  __syncthreads();
  float S1 = r1[0] + r1[1], S2 = r2[0] + r2[1];
  float mu = S1 * (1.f / 128.f);
  float var = S2 * (1.f / 128.f) - mu * mu;
  float rr = rsqrtf(fmaxf(var, 0.f) + 1e-5f);
  float o = (v - mu) * rr * g[t] + b[t];
  if (relu) o = fmaxf(o, 0.f);
  out[(size_t)row * 128 + t] = o;
}

// ---------------- kvs partial: part[g][h][128][128] = sum_{n in chunk g} K V^T ------
__global__ __launch_bounds__(256) void kvsred_k(const unsigned short* __restrict__ Kb,
                                                const unsigned short* __restrict__ Vb,
                                                float* __restrict__ part,
                                                float* __restrict__ ksum, int chunk) {
  const int h = blockIdx.y;
  const int n0 = blockIdx.x * chunk;
  const int iters = chunk >> 3;          // 75
  __shared__ float ks[8][132];
  __shared__ float vs[8][132];
  const int tid = threadIdx.x;
  const int ti = tid >> 4, tj = tid & 15;

  const int sw = tid >> 7;               // 0 = K, 1 = V
  const int sni = (tid >> 4) & 7;        // row within 8-row tile
  const int sc = (tid & 15) << 3;        // col base (8 bf16 per thread)
  const unsigned short* src =
      (sw ? Vb : Kb) + (size_t)(n0 + sni) * 512 + h * 128 + sc;
  float* dstrow = (sw ? &vs[0][0] : &ks[0][0]) + sni * 132 + sc;

  float acc[8][8];
#pragma unroll
  for (int i = 0; i < 8; ++i)
#pragma unroll
    for (int j = 0; j < 8; ++j) acc[i][j] = 0.f;
  float ksloc = 0.f;

  uint4 r = *reinterpret_cast<const uint4*>(src);
  for (int it = 0; it < iters; ++it) {
    __syncthreads();
    float4 lo, hi;
    lo.x = bf2f((unsigned short)(r.x & 0xffffu)); lo.y = bf2f((unsigned short)(r.x >> 16));
    lo.z = bf2f((unsigned short)(r.y & 0xffffu)); lo.w = bf2f((unsigned short)(r.y >> 16));
    hi.x = bf2f((unsigned short)(r.z & 0xffffu)); hi.y = bf2f((unsigned short)(r.z >> 16));
    hi.z = bf2f((unsigned short)(r.w & 0xffffu)); hi.w = bf2f((unsigned short)(r.w >> 16));
    *reinterpret_cast<float4*>(dstrow) = lo;
    *reinterpret_cast<float4*>(dstrow + 4) = hi;
    if (it + 1 < iters)
      r = *reinterpret_cast<const uint4*>(src + (size_t)(it + 1) * 8 * 512);
    __syncthreads();
#pragma unroll
    for (int ni = 0; ni < 8; ++ni) {
      float kk[8], vv[8];
      *reinterpret_cast<float4*>(kk) =
          *reinterpret_cast<const float4*>(&ks[ni][ti * 4]);
      *reinterpret_cast<float4*>(kk + 4) =
          *reinterpret_cast<const float4*>(&ks[ni][64 + ti * 4]);
      *reinterpret_cast<float4*>(vv) =
          *reinterpret_cast<const float4*>(&vs[ni][tj * 4]);
      *reinterpret_cast<float4*>(vv + 4) =
          *reinterpret_cast<const float4*>(&vs[ni][64 + tj * 4]);
#pragma unroll
      for (int i = 0; i < 8; ++i)
#pragma unroll
        for (int j = 0; j < 8; ++j) acc[i][j] = fmaf(kk[i], vv[j], acc[i][j]);
      if (tid < 128) ksloc += ks[ni][tid];
    }
  }
  float* pb = part + (size_t)(blockIdx.x * 4 + h) * 16384;
#pragma unroll
  for (int i = 0; i < 8; ++i) {
    int m = ti * 4 + (i & 3) + ((i >> 2) << 6);
    *reinterpret_cast<float4*>(pb + m * 128 + tj * 4) =
        make_float4(acc[i][0], acc[i][1], acc[i][2], acc[i][3]);
    *reinterpret_cast<float4*>(pb + m * 128 + 64 + tj * 4) =
        make_float4(acc[i][4], acc[i][5], acc[i][6], acc[i][7]);
  }
  if (tid < 128) atomicAdd(&ksum[h * 128 + tid], ksloc);
}

// ---------------- kvs final reduce: kvs[c]=sum_g part; also kvsT bf16 [h][d][k] -----
__global__ __launch_bounds__(256) void kvsfin_k(const float* __restrict__ part,
                                                float* __restrict__ kvs,
                                                unsigned short* __restrict__ kvsT,
                                                int G) {
  int c = blockIdx.x * 256 + threadIdx.x;   // c = h*16384 + m*128 + d (m = k index)
  int hh = c >> 14, md = c & 16383;
  int m = md >> 7, d = md & 127;
  const float* p = part + (size_t)hh * 16384 + md;
  float s = 0.f;
#pragma unroll 4
  for (int g = 0; g < G; ++g) s += p[(size_t)g * 65536];
  kvs[c] = s;
  kvsT[hh * 16384 + d * 128 + m] = f2bf(s);   // transposed bf16 for MFMA B-operand
}

// ---------------- SG attention apply v5b: MFMA (bf16), full 2048-slot B tile --------
__global__ __launch_bounds__(256) void sgapply_k(const unsigned short* __restrict__ Qb,
                                                 const unsigned short* __restrict__ Vb,
                                                 const unsigned short* __restrict__ kvsT,
                                                 const float* __restrict__ ksum,
                                                 const float* __restrict__ ssqq,
                                                 const float* __restrict__ ssqk,
                                                 unsigned short* __restrict__ attnb,
                                                 int N) {
  __shared__ short Bs[16384];       // 2048 fragment slots x 8 bf16 = 32KB
  __shared__ float den_s[64];
  __shared__ float fsh_s;
  const int tid = threadIdx.x;
  const int lane = tid & 63;
  const int w = tid >> 6;           // wave 0..3 -> rows w*16..+15
  const int n0 = blockIdx.x * 64;
  if (tid == 0) fsh_s = 1.0f / (sqrtf(*ssqq) * sqrtf(*ssqk));

  float out[8][4];
#pragma unroll
  for (int dt = 0; dt < 8; ++dt)
#pragma unroll
    for (int r = 0; r < 4; ++r) out[dt][r] = 0.f;

  int arow = n0 + w * 16 + (lane & 15);
  if (arow >= N) arow = N - 1;
  const int kofs = (lane >> 4) * 8;   // k offset within 32-slab

  for (int h = 0; h < 4; ++h) {
    __syncthreads();   // previous head's compute done; also fsh_s visible (h=0)
    for (int s = tid; s < 2048; s += 256) {
      int l = s & 63, dtks = s >> 6;        // dt = dtks>>2, kslab = dtks&3
      int d = (dtks >> 2) * 16 + (l & 15);
      int kk = (dtks & 3) * 32 + (l >> 4) * 8;
      *reinterpret_cast<bf16x8*>(&Bs[s * 8]) =
          *reinterpret_cast<const bf16x8*>(kvsT + h * 16384 + d * 128 + kk);
    }
    // den for the block's 64 rows: 4 threads per row, 32 k each
    {
      int r = tid >> 2, seg = tid & 3;
      int rg = n0 + r; if (rg >= N) rg = N - 1;
      const unsigned short* qp = Qb + (size_t)rg * 512 + h * 128 + seg * 32;
      const float* kp = ksum + h * 128 + seg * 32;
      float p = 0.f;
#pragma unroll
      for (int u = 0; u < 32; u += 8) {
        bf16x8 q8 = *reinterpret_cast<const bf16x8*>(qp + u);
#pragma unroll
        for (int j = 0; j < 8; ++j)
          p = fmaf(bf2f((unsigned short)q8[j]), kp[u + j], p);
      }
      p += __shfl_xor(p, 1);
      p += __shfl_xor(p, 2);
      if (seg == 0) den_s[r] = p * fsh_s + 60000.0f;
    }
    __syncthreads();
    bf16x8 afr[4];
    {
      const unsigned short* qrow = Qb + (size_t)arow * 512 + h * 128 + kofs;
#pragma unroll
      for (int ks = 0; ks < 4; ++ks)
        afr[ks] = *reinterpret_cast<const bf16x8*>(qrow + ks * 32);
    }
    float f = fsh_s;
#pragma unroll
    for (int dt = 0; dt < 8; ++dt) {
      f32x4 acc = {0.f, 0.f, 0.f, 0.f};
#pragma unroll
      for (int ks = 0; ks < 4; ++ks) {
        bf16x8 b = *reinterpret_cast<const bf16x8*>(&Bs[((dt * 4 + ks) * 64 + lane) * 8]);
        acc = __builtin_amdgcn_mfma_f32_16x16x32_bf16(afr[ks], b, acc, 0, 0, 0);
      }
      int dcol = dt * 16 + (lane & 15);
#pragma unroll
      for (int r = 0; r < 4; ++r) {
        int rl = w * 16 + (lane >> 4) * 4 + r;
        int rg = n0 + rl;
        if (rg < N) {
          float v = bf2f(Vb[(size_t)rg * 512 + h * 128 + dcol]);
          float rd = 1.0f / den_s[rl];
          out[dt][r] += (acc[r] * f + 60000.0f * v) * rd;
        }
      }
    }
  }
#pragma unroll
  for (int dt = 0; dt < 8; ++dt) {
    int dcol = dt * 16 + (lane & 15);
#pragma unroll
    for (int r = 0; r < 4; ++r) {
      int rg = n0 + w * 16 + (lane >> 4) * 4 + r;
      if (rg < N) attnb[(size_t)rg * 128 + dcol] = f2bf(0.25f * out[dt][r]);
    }
  }
}

// ---------------- host ----------------
extern "C" void kernel_launch(void* const* d_in, const int* in_sizes, int n_in,
                              void* d_out, int out_size, void* d_ws, size_t ws_size,
                              hipStream_t stream) {
  const float* x_ent = (const float*)d_in[0];
  const float* x_att = (const float*)d_in[1];
  const float* Wkqv_e = (const float*)d_in[2];
  const float* bkqv_e = (const float*)d_in[3];
  const float* Wkqv_a = (const float*)d_in[4];
  const float* bkqv_a = (const float*)d_in[5];
  const float* Wout_e = (const float*)d_in[6];
  const float* bout_e = (const float*)d_in[7];
  const float* Wout_a = (const float*)d_in[8];
  const float* bout_a = (const float*)d_in[9];
  const float* skip_e = (const float*)d_in[10];
  const float* skip_a = (const float*)d_in[11];
  const float* a_rel = (const float*)d_in[12];
  const float* m_rel = (const float*)d_in[13];
  const float* p_rel = (const float*)d_in[14];
  const float* ln_ent_g = (const float*)d_in[15];
  const float* ln_ent_b = (const float*)d_in[16];
  const float* sg_fc_W = (const float*)d_in[17];
  const float* sg_fc_b = (const float*)d_in[18];
  const float* sg_ln0_g = (const float*)d_in[19];
  const float* sg_ln0_b = (const float*)d_in[20];
  const float* sg_Wq = (const float*)d_in[21];
  const float* sg_bq = (const float*)d_in[22];
  const float* sg_Wk = (const float*)d_in[23];
  const float* sg_bk = (const float*)d_in[24];
  const float* sg_Wv = (const float*)d_in[25];
  const float* sg_bv = (const float*)d_in[26];
  const float* sg_ln1_g = (const float*)d_in[27];
  const float* sg_ln1_b = (const float*)d_in[28];
  const float* proj_W1 = (const float*)d_in[29];
  const float* proj_b1 = (const float*)d_in[30];
  const float* proj_W2 = (const float*)d_in[31];
  const float* proj_b2 = (const float*)d_in[32];
  const int* ei_ee = (const int*)d_in[33];
  const int* ei_ea = (const int*)d_in[34];
  const int* ei_ae = (const int*)d_in[35];

  char* ws = (char*)d_ws;
  // ---- fixed region ----
  const size_t O_HE = 0;                         // h_e f32 (30.72M)
  const size_t O_HA = 30720000;                  // h_a f32 (15.36M) | SG: attnb bf16
  const size_t O_Z0 = 46080000;                  // z0 f32 (30.72M)
  const size_t O_WKT = 76800000;                 // 3*16384 f32
  const size_t O_WVT = 76996608;
  const size_t O_BKT = 77193216;
  const size_t O_BVT = 77194752;
  const size_t O_KVS = 77196288;                 // kvs(262144)+ksum(2048)+ssq(64)
  // ---- CSR region ----
  const size_t O_RPE = 77460544;                 // rowptr_e (60001) -> 240064
  const size_t O_RPA = O_RPE + 240064;           // rowptr_a (30001) -> 120064
  const size_t O_CUE = O_RPA + 120064;           // cursor/deg_e -> 240000
  const size_t O_CUA = O_CUE + 240000;           // cursor/deg_a -> 120000
  const size_t O_ENE = O_CUA + 120000;           // entries_e (225000) -> 900000
  const size_t O_ENA = O_ENE + 900000;           // entries_a (75000) -> 300000
  const size_t O_UN = O_ENA + 300000;            // union; 79,380,672
  // HGT view of union:
  float* q_e = (float*)(ws + O_UN);                                 // 30.72M (also out_e)
  float* q_a = (float*)(ws + O_UN + 30720000);                      // 15.36M (also out_a)
  unsigned short* ktbl = (unsigned short*)(ws + O_UN + 46080000);   // 150000x128 bf16
  unsigned short* vtbl = (unsigned short*)(ws + O_UN + 84480000);   // 150000x128 bf16
  // SG view of union:
  float* tmpf = (float*)(ws + O_UN);                                // fc out f32
  unsigned short* Vb = (unsigned short*)(ws + O_UN);                // NE*512 bf16
  unsigned short* KQb = (unsigned short*)(ws + O_UN + 61440000);    // K then Q
  unsigned short* attnb = (unsigned short*)(ws + O_HA);             // NE*128 bf16

  float* h_e = (float*)(ws + O_HE);
  float* h_a = (float*)(ws + O_HA);
  float* z0 = (float*)(ws + O_Z0);
  float* Wkt = (float*)(ws + O_WKT);
  float* Wvt = (float*)(ws + O_WVT);
  float* bkt = (float*)(ws + O_BKT);
  float* bvt = (float*)(ws + O_BVT);
  float* kvs = (float*)(ws + O_KVS);
  float* ksum = (float*)(ws + O_KVS + 262144);
  float* ssq_q = (float*)(ws + O_KVS + 262144 + 2048);
  float* ssq_k = ssq_q + 1;
  int* rowptr_e = (int*)(ws + O_RPE);
  int* rowptr_a = (int*)(ws + O_RPA);
  int* cursor_e = (int*)(ws + O_CUE);
  int* cursor_a = (int*)(ws + O_CUA);
  int* entries_e = (int*)(ws + O_ENE);
  int* entries_a = (int*)(ws + O_ENA);

  const int GB_E = (NE + 127) / 128;    // 469
  const int G64_E = (NE + 63) / 64;     // 938
  const int G64_A = (NA + 63) / 64;     // 469

  hipMemcpyAsync(h_e, x_ent, (size_t)NE * 128 * 4, hipMemcpyDeviceToDevice, stream);
  hipMemcpyAsync(h_a, x_att, (size_t)NA * 128 * 4, hipMemcpyDeviceToDevice, stream);

  // ---- CSR build (graph identical across layers) ----
  hipMemsetAsync(ws + O_CUE, 0, 360000, stream);   // cursor_e + cursor_a
  deg_k<<<(E_EE + 255) / 256, 256, 0, stream>>>(ei_ee, E_EE, cursor_e);
  deg_k<<<(E_AE + 255) / 256, 256, 0, stream>>>(ei_ae, E_AE, cursor_e);
  deg_k<<<(E_EA + 255) / 256, 256, 0, stream>>>(ei_ea, E_EA, cursor_a);
  scan_k<<<1, 1024, 0, stream>>>(cursor_e, rowptr_e, NE);
  scan_k<<<1, 1024, 0, stream>>>(cursor_a, rowptr_a, NA);
  fill_k<<<(E_EE + 255) / 256, 256, 0, stream>>>(ei_ee, E_EE, cursor_e, entries_e, 0, 0);
  fill_k<<<(E_AE + 255) / 256, 256, 0, stream>>>(ei_ae, E_AE, cursor_e, entries_e, NE, 1);
  fill_k<<<(E_EA + 255) / 256, 256, 0, stream>>>(ei_ea, E_EA, cursor_a, entries_a, 0, 0);

  for (int l = 0; l < 2; ++l) {
    const float* Wke = Wkqv_e + (size_t)l * 49152;
    const float* Wka = Wkqv_a + (size_t)l * 49152;
    const float* bke = bkqv_e + (size_t)l * 384;
    const float* bka = bkqv_a + (size_t)l * 384;

    wrel_k<<<dim3(3, 2), 256, 0, stream>>>(Wke, Wka, bke, bka,
                                           a_rel + (size_t)l * 12288,
                                           m_rel + (size_t)l * 12288, Wkt, Wvt, bkt, bvt);
    // q projections (cols 128..255 of Wkqv)
    gemm64_k<0, 0><<<G64_E, 256, 0, stream>>>(h_e, 128, Wke + 128, 384, bke + 128, NE,
                                              q_e, nullptr, 128, nullptr, nullptr);
    gemm64_k<0, 0><<<G64_A, 256, 0, stream>>>(h_a, 128, Wka + 128, 384, bka + 128, NA,
                                              q_a, nullptr, 128, nullptr, nullptr);
    // kt/vt tables (bf16): rows [0,NE)=rel0(src e), [NE,NE+NA)=rel2(src a),
    //                      [90000,150000)=rel1(src e, dst a)
    gemm64_k<0, 2><<<G64_E, 256, 0, stream>>>(h_e, 128, Wkt, 128, bkt, NE,
                                              nullptr, ktbl, 128, nullptr, nullptr);
    gemm64_k<0, 2><<<G64_A, 256, 0, stream>>>(h_a, 128, Wkt + 2 * 16384, 128,
                                              bkt + 2 * 128, NA, nullptr,
                                              ktbl + (size_t)NE * 128, 128, nullptr, nullptr);
    gemm64_k<0, 2><<<G64_E, 256, 0, stream>>>(h_e, 128, Wkt + 1 * 16384, 128,
                                              bkt + 1 * 128, NE, nullptr,
                                              ktbl + (size_t)90000 * 128, 128, nullptr, nullptr);
    gemm64_k<0, 2><<<G64_E, 256, 0, stream>>>(h_e, 128, Wvt, 128, bvt, NE,
                                              nullptr, vtbl, 128, nullptr, nullptr);
    gemm64_k<0, 2><<<G64_A, 256, 0, stream>>>(h_a, 128, Wvt + 2 * 16384, 128,
                                              bvt + 2 * 128, NA, nullptr,
                                              vtbl + (size_t)NE * 128, 128, nullptr, nullptr);
    gemm64_k<0, 2><<<G64_E, 256, 0, stream>>>(h_e, 128, Wvt + 1 * 16384, 128,
                                              bvt + 1 * 128, NE, nullptr,
                                              vtbl + (size_t)90000 * 128, 128, nullptr, nullptr);
    // gather (writes message in-place over q buffers)
    hgt_gather_k<<<30000, 256, 0, stream>>>(q_e, ktbl, vtbl, rowptr_e, entries_e,
                                            p_rel + (size_t)l * 12, NE, q_e);
    hgt_gather_k<<<15000, 256, 0, stream>>>(q_a, ktbl + (size_t)90000 * 128,
                                            vtbl + (size_t)90000 * 128, rowptr_a,
                                            entries_a, p_rel + (size_t)l * 12 + 4, NA, q_a);
    // out proj (gelu on msg) + gated skip + inter-layer gelu, in-place on h
    gemm64_k<1, 3><<<G64_E, 256, 0, stream>>>(q_e, 128, Wout_e + (size_t)l * 16384, 128,
                                              bout_e + (size_t)l * 128, NE, h_e, nullptr,
                                              128, skip_e + l, nullptr);
    gemm64_k<1, 3><<<G64_A, 256, 0, stream>>>(q_a, 128, Wout_a + (size_t)l * 16384, 128,
                                              bout_a + (size_t)l * 128, NA, h_a, nullptr,
                                              128, skip_a + l, nullptr);
  }

  // -------- SGFormer --------
  // fc -> MFMA (bf16 inputs): SG branch is attenuated 0.5*0.1 into the output.
  gemmMF_k<0><<<dim3(G64_E, 1), 256, 0, stream>>>(h_e, 128, sg_fc_W, 128, sg_fc_b, NE,
                                                  tmpf, nullptr, 128, nullptr);
  ln_k<float, float><<<NE, 128, 0, stream>>>(tmpf, nullptr, 1.f, 0.f, sg_ln0_g,
                                             sg_ln0_b, z0, 1);
  hipMemsetAsync(ws + O_KVS, 0, 264256, stream);
  gemmMF_k<2><<<dim3(G64_E, 4), 256, 0, stream>>>(z0, 128, sg_Wv, 512, sg_bv, NE,
                                                  nullptr, Vb, 512, nullptr);
  gemmMF_k<2><<<dim3(G64_E, 4), 256, 0, stream>>>(z0, 128, sg_Wk, 512, sg_bk, NE,
                                                  nullptr, KQb, 512, ssq_k);
  // partials into d_out (dead until proj2): 400 slabs x 64KB = 25.6MB; kvsT bf16
  // (128KB) right after at +26,214,400 (out_size 30.72MB has room)
  unsigned short* kvsT = (unsigned short*)((char*)d_out + 26214400);
  kvsred_k<<<dim3(100, 4), 256, 0, stream>>>(KQb, Vb, (float*)d_out, ksum, 600);
  kvsfin_k<<<256, 256, 0, stream>>>((const float*)d_out, kvs, kvsT, 100);
  gemmMF_k<2><<<dim3(G64_E, 4), 256, 0, stream>>>(z0, 128, sg_Wq, 512, sg_bq, NE,
                                                  nullptr, KQb, 512, ssq_q);
  sgapply_k<<<G64_E, 256, 0, stream>>>(KQb, Vb, kvsT, ksum, ssq_q, ssq_k, attnb, NE);
  ln_k<unsigned short, float><<<NE, 128, 0, stream>>>(attnb, z0, 0.5f, 0.5f, sg_ln1_g,
                                                      sg_ln1_b, z0, 0);
  ln_k<float, float><<<NE, 128, 0, stream>>>(h_e, z0, 0.9f, 0.1f, ln_ent_g, ln_ent_b,
                                             h_e, 0);
  gemm64_k<0, 1><<<G64_E, 256, 0, stream>>>(h_e, 128, proj_W1, 128, proj_b1, NE,
                                            z0, nullptr, 128, nullptr, nullptr);
  gemm64_k<0, 0><<<G64_E, 256, 0, stream>>>(z0, 128, proj_W2, 128, proj_b2, NE,
                                            (float*)d_out, nullptr, 128, nullptr, nullptr);
}